// Round 8
// baseline (226.001 us; speedup 1.0000x reference)
//
#include <hip/hip_runtime.h>
#include <hip/hip_bf16.h>
#include <math.h>

#define BB   128
#define NN   512
#define DIN  64
#define HH   256
#define DOUT 64
#define BNR  (BB * NN)          // 65536 rows

typedef float  f32x4  __attribute__((ext_vector_type(4)));
typedef __bf16 bf16x8 __attribute__((ext_vector_type(8)));

#define GLP(p)  ((const __attribute__((address_space(1))) void*)(p))
#define LDSP(p) ((__attribute__((address_space(3))) void*)(p))

// Haar/db1 'zero' DWT patterns, levels 1..3, FULL_LEN=8
__constant__ float PAT[3][8] = {
    {0.70710678f, 0.70710678f, 0.f, 0.f, 0.f, 0.f, 0.f, 0.f},
    {0.5f,        0.70710678f, 0.f, 0.5f, 0.f, 0.f, 0.f, 0.f},
    {0.35355339f, 0.70710678f, 0.f, 0.f, 0.f, 0.5f, 0.f, 0.35355339f}
};

__device__ __forceinline__ unsigned short f2bfu(float x) {
    __hip_bfloat16 b = __float2bfloat16(x);
    unsigned short u;
    __builtin_memcpy(&u, &b, 2);
    return u;
}
__device__ __forceinline__ float bf2f(unsigned short u) {
    unsigned int v = ((unsigned int)u) << 16;
    float f;
    __builtin_memcpy(&f, &v, 4);
    return f;
}

// ---------------------------------------------------------------------------
// In-kernel th = sigmoid(mean diff): every block reduces the partial buffer.
// red = LDS scratch (>=256 floats), free at call time. Same tree order as the
// old diff_final_k -> bit-identical th. Trailing sync protects red reuse.
// ---------------------------------------------------------------------------
__device__ __forceinline__ float block_th(const float* __restrict__ partial, int np,
                                          float inv_n, float* red, int tid)
{
    float s = 0.f;
    for (int i = tid; i < np; i += 256) s += partial[i];
    red[tid] = s;
    __syncthreads();
    for (int o = 128; o > 0; o >>= 1) {
        if (tid < o) red[tid] += red[tid + o];
        __syncthreads();
    }
    float th = 1.f / (1.f + expf(-red[0] * inv_n));
    __syncthreads();
    return th;
}

// ---------------------------------------------------------------------------
// Coalesced bf16 tile write via LDS staging (verified round 4).
// ---------------------------------------------------------------------------
template<int BM, int BN, int FM, int FN>
__device__ __forceinline__ void write_tile(char* lds, f32x4 (&a)[FM][FN],
                                           __hip_bfloat16* __restrict__ C,
                                           long base, int N, int tid)
{
    const int wave = tid >> 6;
    const int lane = tid & 63;
    const int wm = wave >> 1, wn = wave & 1;
    const int lc = lane & 15;
    const int lr4 = (lane >> 4) << 2;
    __syncthreads();
    #pragma unroll
    for (int j = 0; j < FN; ++j) {
        int colb = (wn * (FN * 16) + j * 16 + lc) * 2;
        #pragma unroll
        for (int i = 0; i < FM; ++i) {
            int row0 = wm * (FM * 16) + i * 16 + lr4;
            #pragma unroll
            for (int r = 0; r < 4; ++r) {
                int row = row0 + r;
                *reinterpret_cast<unsigned short*>(
                    lds + row * (BN * 2) + (colb ^ (((row >> 2) & 3) << 5))) =
                    f2bfu(a[i][j][r]);
            }
        }
    }
    __syncthreads();
    const int TPR = BN / 8;
    const int RPP = 256 / TPR;
    #pragma unroll
    for (int p = 0; p < BM / RPP; ++p) {
        int row = p * RPP + tid / TPR;
        int cb = (tid % TPR) * 16;
        int pb = cb ^ (((row >> 2) & 3) << 5);
        uint4 v = *reinterpret_cast<const uint4*>(lds + row * (BN * 2) + pb);
        *reinterpret_cast<uint4*>(reinterpret_cast<char*>(C + base + (long)row * N) + cb) = v;
    }
}

// ---------------------------------------------------------------------------
// staging of one K=64 slab of A(BM rows) + B(BN rows) into swizzled LDS
// ---------------------------------------------------------------------------
template<int BM, int BN>
__device__ __forceinline__ void stage_tiles(const __hip_bfloat16* __restrict__ Ab,
                                            const __hip_bfloat16* __restrict__ Bb,
                                            char* AsB, char* BsB,
                                            int m0, int n0, int k0, int KA, int KB,
                                            int wave, int lane)
{
    const int NCH = (BM + BN) / 32;
    const int lr = lane >> 3;
    const int ls = lane & 7;
    #pragma unroll
    for (int cc = 0; cc < NCH; ++cc) {
        int c = wave * NCH + cc;
        const __hip_bfloat16* src;
        char* ldsb;
        if (c < BM / 8) {
            int r = c * 8 + lr;
            ldsb = AsB + c * 1024;
            src = Ab + ((long)(m0 + r) * KA + k0 + ((ls ^ (r & 7)) << 3));
        } else {
            int c2 = c - BM / 8;
            int r = c2 * 8 + lr;
            ldsb = BsB + c2 * 1024;
            src = Bb + ((long)(n0 + r) * KB + k0 + ((ls ^ (r & 7)) << 3));
        }
        __builtin_amdgcn_global_load_lds(GLP(src), LDSP(ldsb), 16, 0, 0);
    }
}

// compute 2 k-slices of MFMA from staged LDS into acc
template<int BM, int BN, int FM, int FN>
__device__ __forceinline__ void mfma_tiles(char* AsB, char* BsB,
                                           f32x4 (&acc)[FM][FN], int wave, int lane)
{
    const int wm = wave >> 1, wn = wave & 1;
    #pragma unroll
    for (int ksl = 0; ksl < 2; ++ksl) {
        bf16x8 af[FM], bfr[FN];
        #pragma unroll
        for (int i = 0; i < FM; ++i) {
            int row = wm * (FM * 16) + i * 16 + (lane & 15);
            int off = (ksl * 64 + ((lane >> 4) << 4)) ^ ((row & 7) << 4);
            af[i] = *reinterpret_cast<const bf16x8*>(AsB + row * 128 + off);
        }
        #pragma unroll
        for (int j = 0; j < FN; ++j) {
            int row = wn * (FN * 16) + j * 16 + (lane & 15);
            int off = (ksl * 64 + ((lane >> 4) << 4)) ^ ((row & 7) << 4);
            bfr[j] = *reinterpret_cast<const bf16x8*>(BsB + row * 128 + off);
        }
        #pragma unroll
        for (int i = 0; i < FM; ++i)
            #pragma unroll
            for (int j = 0; j < FN; ++j)
                acc[i][j] = __builtin_amdgcn_mfma_f32_16x16x32_bf16(
                    af[i], bfr[j], acc[i][j], 0, 0, 0);
    }
}

// ---------------------------------------------------------------------------
// fp32 -> bf16 convert
// ---------------------------------------------------------------------------
__global__ __launch_bounds__(256) void cvt_k(const float* __restrict__ in,
                                             unsigned short* __restrict__ out, long n4)
{
    long gid = (long)blockIdx.x * 256 + threadIdx.x;
    long stride = (long)gridDim.x * 256;
    for (long i = gid; i < n4; i += stride) {
        float4 v = reinterpret_cast<const float4*>(in)[i];
        ushort4 u;
        u.x = f2bfu(v.x); u.y = f2bfu(v.y); u.z = f2bfu(v.z); u.w = f2bfu(v.w);
        reinterpret_cast<ushort4*>(out)[i] = u;
    }
}

// ---------------------------------------------------------------------------
// transpose-convert fp32 (R,C) -> bf16 (C,R) with optional per-src-row scale
// ---------------------------------------------------------------------------
__device__ __forceinline__ void tcvt_body(const float* __restrict__ in,
                                          unsigned short* __restrict__ out,
                                          const float* __restrict__ cs,
                                          int R, int C, int r0, int c0)
{
    __shared__ float t[64][65];
    int tr = threadIdx.x >> 6;
    int tc = threadIdx.x & 63;
    #pragma unroll
    for (int i = 0; i < 16; ++i) {
        int r = i * 4 + tr;
        t[r][tc] = in[(long)(r0 + r) * C + c0 + tc];
    }
    __syncthreads();
    float sc = cs ? cs[r0 + tc] : 1.0f;
    #pragma unroll
    for (int i = 0; i < 16; ++i) {
        int r = i * 4 + tr;
        out[(long)(c0 + r) * R + r0 + tc] = f2bfu(t[tc][r] * sc);
    }
}

__global__ __launch_bounds__(256) void tcvt_k(const float* __restrict__ in,
                                              unsigned short* __restrict__ out,
                                              int R, int C, long sz)
{
    long base = (long)blockIdx.z * sz;
    tcvt_body(in + base, out + base, nullptr, R, C, blockIdx.y * 64, blockIdx.x * 64);
}

struct WTArgs {
    const float* src[8];
    unsigned short* dst[8];
    const float* cs[8];
    int R[8], C[8];
};
__global__ __launch_bounds__(256) void tcvt_w_k(WTArgs a)
{
    int wgt = blockIdx.y;
    int R = a.R[wgt], C = a.C[wgt];
    int tilesX = C >> 6;
    int tiles = (R >> 6) * tilesX;
    int t = blockIdx.x;
    if (t >= tiles) return;
    tcvt_body(a.src[wgt], a.dst[wgt], a.cs[wgt], R, C, (t / tilesX) * 64, (t % tilesX) * 64);
}

// ---------------------------------------------------------------------------
// wavelet coeff
// ---------------------------------------------------------------------------
__global__ void coeff_k(const float* __restrict__ logits, const float* __restrict__ gumb,
                        const float* __restrict__ Wnl, float* __restrict__ coeff)
{
    int f = threadIdx.x;
    float l0 = logits[0] + gumb[f * 3 + 0];
    float l1 = logits[1] + gumb[f * 3 + 1];
    float l2 = logits[2] + gumb[f * 3 + 2];
    int bl = 0;
    float bv = l0;
    if (l1 > bv) { bv = l1; bl = 1; }
    if (l2 > bv) { bv = l2; bl = 2; }
    float s = 0.f;
    #pragma unroll
    for (int t = 0; t < 8; ++t) s += Wnl[f * 8 + t] * PAT[bl][t];
    coeff[f] = s;
}

// ---------------------------------------------------------------------------
// batched vector folds: out[n] = (base? base[n]:0) + sum_k v[k]*(c?c[k]:1)*W[k,n]
// ---------------------------------------------------------------------------
struct FVArgs {
    const float* W[5];
    const float* c[5];
    const float* v[5];
    const float* base[5];
    float* out[5];
    int K[5], N[5];
};
__global__ __launch_bounds__(256) void foldvec_k(FVArgs a)
{
    int cs = blockIdx.y;
    int n = blockIdx.x;
    if (n >= a.N[cs]) return;
    int k = threadIdx.x;
    float s = 0.f;
    if (k < a.K[cs]) {
        float cc = a.c[cs] ? a.c[cs][k] : 1.0f;
        s = a.v[cs][k] * cc * a.W[cs][(long)k * a.N[cs] + n];
    }
    __shared__ float sm[256];
    sm[threadIdx.x] = s;
    __syncthreads();
    for (int o = 128; o > 0; o >>= 1) {
        if (threadIdx.x < o) sm[threadIdx.x] += sm[threadIdx.x + o];
        __syncthreads();
    }
    if (threadIdx.x == 0)
        a.out[cs][n] = (a.base[cs] ? a.base[cs][n] : 0.f) + sm[0];
}

// ---------------------------------------------------------------------------
// batched weight folds (transposed bf16 out, M=64 rows, K=256 fixed):
//   dstT[n,m] = (incl? Wsrc[m,n] : 0) + sum_k Wsrc[m,k]*c[k]*Wbig[k,n]
// ---------------------------------------------------------------------------
struct WFArgs {
    const float* Wsrc[3];
    const float* Wbig[3];
    const float* c[3];
    int incl[3], N[3];
    unsigned short* dst[3];
};
__global__ __launch_bounds__(256) void wfold_k(WFArgs a)
{
    int cs = blockIdx.y;
    int m = blockIdx.x;
    __shared__ float ws[256];
    ws[threadIdx.x] = a.Wsrc[cs][m * 256 + threadIdx.x] * a.c[cs][threadIdx.x];
    __syncthreads();
    int n = threadIdx.x;
    int N = a.N[cs];
    if (n >= N) return;
    float s = a.incl[cs] ? a.Wsrc[cs][m * 256 + n] : 0.f;
    const float* Wb = a.Wbig[cs];
    #pragma unroll 8
    for (int k = 0; k < 256; ++k)
        s += ws[k] * Wb[(long)k * N + n];
    a.dst[cs][n * 64 + m] = f2bfu(s);
}

// ---------------------------------------------------------------------------
// Single MFMA bf16 GEMM (bf16 out, coalesced epilogue)
// ---------------------------------------------------------------------------
template<int BM, int BN, int FM, int FN>
__global__ __launch_bounds__(256) void gemm_bt_k(
    const __hip_bfloat16* __restrict__ A, const __hip_bfloat16* __restrict__ Bt,
    const float* __restrict__ bias, __hip_bfloat16* __restrict__ Cb,
    int M, int N, int K, long sA, long sB, long sC)
{
    __shared__ __attribute__((aligned(128))) char lds[(BM + BN) * 128];
    char* AsB = lds;
    char* BsB = lds + BM * 128;

    const long bz = blockIdx.z;
    const __hip_bfloat16* Ab = A + bz * sA;
    const __hip_bfloat16* Bb = Bt + bz * sB;

    const int m0 = blockIdx.y * BM;
    const int n0 = blockIdx.x * BN;
    const int tid  = threadIdx.x;
    const int wave = tid >> 6;
    const int lane = tid & 63;
    const int wn = wave & 1;

    f32x4 acc[FM][FN];
    #pragma unroll
    for (int i = 0; i < FM; ++i)
        #pragma unroll
        for (int j = 0; j < FN; ++j)
            acc[i][j] = (f32x4){0.f, 0.f, 0.f, 0.f};

    for (int k0 = 0; k0 < K; k0 += 64) {
        stage_tiles<BM, BN>(Ab, Bb, AsB, BsB, m0, n0, k0, K, K, wave, lane);
        __syncthreads();
        mfma_tiles<BM, BN, FM, FN>(AsB, BsB, acc, wave, lane);
        __syncthreads();
    }

    const int lc = lane & 15;
    #pragma unroll
    for (int j = 0; j < FN; ++j) {
        int col = n0 + wn * (FN * 16) + j * 16 + lc;
        float bv = bias ? bias[col] : 0.0f;
        #pragma unroll
        for (int i = 0; i < FM; ++i)
            #pragma unroll
            for (int r = 0; r < 4; ++r)
                acc[i][j][r] += bv;
    }
    write_tile<BM, BN, FM, FN>(lds, acc, Cb, bz * sC + (long)m0 * N + n0, N, tid);
}

// ---------------------------------------------------------------------------
// Dual MFMA GEMM, partials-only (D0): diff = (A1@B1+b1) - (A2@B2+b2)
// ---------------------------------------------------------------------------
template<int BM, int BN, int FM, int FN>
__global__ __launch_bounds__(256) void dual_k(
    const __hip_bfloat16* __restrict__ A1, const __hip_bfloat16* __restrict__ B1t,
    const float* __restrict__ bias1,
    const __hip_bfloat16* __restrict__ A2, const __hip_bfloat16* __restrict__ B2t,
    const float* __restrict__ bias2,
    float* __restrict__ partial,
    int M, int N, int K1, int K2)
{
    __shared__ __attribute__((aligned(128))) char lds[(BM + BN) * 128];
    char* AsB = lds;
    char* BsB = lds + BM * 128;

    const int m0 = blockIdx.y * BM;
    const int n0 = blockIdx.x * BN;
    const int tid  = threadIdx.x;
    const int wave = tid >> 6;
    const int lane = tid & 63;
    const int wn = wave & 1;

    f32x4 acc[2][FM][FN];
    #pragma unroll
    for (int p = 0; p < 2; ++p)
        #pragma unroll
        for (int i = 0; i < FM; ++i)
            #pragma unroll
            for (int j = 0; j < FN; ++j)
                acc[p][i][j] = (f32x4){0.f, 0.f, 0.f, 0.f};

    #pragma unroll
    for (int ph = 0; ph < 2; ++ph) {
        const __hip_bfloat16* Ab = ph ? A2 : A1;
        const __hip_bfloat16* Bb = ph ? B2t : B1t;
        const int K = ph ? K2 : K1;
        for (int k0 = 0; k0 < K; k0 += 64) {
            stage_tiles<BM, BN>(Ab, Bb, AsB, BsB, m0, n0, k0, K, K, wave, lane);
            __syncthreads();
            mfma_tiles<BM, BN, FM, FN>(AsB, BsB, acc[ph], wave, lane);
            __syncthreads();
        }
    }

    const int lc  = lane & 15;
    float dsum = 0.f;
    #pragma unroll
    for (int j = 0; j < FN; ++j) {
        int col = n0 + wn * (FN * 16) + j * 16 + lc;
        float b1 = bias1 ? bias1[col] : 0.0f;
        float b2 = bias2 ? bias2[col] : 0.0f;
        #pragma unroll
        for (int i = 0; i < FM; ++i)
            #pragma unroll
            for (int r = 0; r < 4; ++r) {
                float d = (acc[0][i][j][r] + b1) - (acc[1][i][j][r] + b2);
                dsum += d * d;
            }
    }

    float* red = (float*)lds;
    red[tid] = dsum;
    __syncthreads();
    for (int o = 128; o > 0; o >>= 1) {
        if (tid < o) red[tid] += red[tid + o];
        __syncthreads();
    }
    if (tid == 0) partial[blockIdx.y * gridDim.x + blockIdx.x] = red[0];
}

// ---------------------------------------------------------------------------
// wave_k: 3-phase MFMA, th computed in-kernel from partial_in:
//   C1 = th*(P0 + b0) + om*(P1 + b1) + crow[col]
//   C2 = P2 + b2[col];  partial_out += (C1-C2)^2
// ---------------------------------------------------------------------------
template<int BM, int BN, int FM, int FN>
__global__ __launch_bounds__(256) void wave_k(
    const __hip_bfloat16* __restrict__ A0, const __hip_bfloat16* __restrict__ B0,
    int K0, const float* __restrict__ b0,
    const __hip_bfloat16* __restrict__ A1, const __hip_bfloat16* __restrict__ B1,
    int K1, const float* __restrict__ b1,
    const __hip_bfloat16* __restrict__ A2, const __hip_bfloat16* __restrict__ B2,
    int K2, const float* __restrict__ b2,
    const float* __restrict__ partial_in, int np_in, float inv_in,
    const float* __restrict__ crow,
    __hip_bfloat16* __restrict__ C1, __hip_bfloat16* __restrict__ C2,
    float* __restrict__ partial_out, int M, int N)
{
    __shared__ __attribute__((aligned(128))) char lds[(BM + BN) * 128];
    char* AsB = lds;
    char* BsB = lds + BM * 128;

    const int m0 = blockIdx.y * BM;
    const int n0 = blockIdx.x * BN;
    const int tid  = threadIdx.x;
    const int wave = tid >> 6;
    const int lane = tid & 63;
    const int wn = wave & 1;

    f32x4 acc[3][FM][FN];
    #pragma unroll
    for (int p = 0; p < 3; ++p)
        #pragma unroll
        for (int i = 0; i < FM; ++i)
            #pragma unroll
            for (int j = 0; j < FN; ++j)
                acc[p][i][j] = (f32x4){0.f, 0.f, 0.f, 0.f};

    #pragma unroll
    for (int ph = 0; ph < 3; ++ph) {
        const __hip_bfloat16* Ab = (ph == 0) ? A0 : (ph == 1 ? A1 : A2);
        const __hip_bfloat16* Bb = (ph == 0) ? B0 : (ph == 1 ? B1 : B2);
        const int K = (ph == 0) ? K0 : (ph == 1 ? K1 : K2);
        for (int k0 = 0; k0 < K; k0 += 64) {
            stage_tiles<BM, BN>(Ab, Bb, AsB, BsB, m0, n0, k0, K, K, wave, lane);
            __syncthreads();
            mfma_tiles<BM, BN, FM, FN>(AsB, BsB, acc[ph], wave, lane);
            __syncthreads();
        }
    }

    const float th = block_th(partial_in, np_in, inv_in, (float*)lds, tid);
    const float om = 1.f - th;

    const int lc = lane & 15;
    float dsum = 0.f;
    #pragma unroll
    for (int j = 0; j < FN; ++j) {
        int col = n0 + wn * (FN * 16) + j * 16 + lc;
        float bv0 = b0 ? b0[col] : 0.0f;
        float bv1 = b1 ? b1[col] : 0.0f;
        float bv2 = b2 ? b2[col] : 0.0f;
        float cr  = crow[col];
        #pragma unroll
        for (int i = 0; i < FM; ++i)
            #pragma unroll
            for (int r = 0; r < 4; ++r) {
                float v1 = th * (acc[0][i][j][r] + bv0) + om * (acc[1][i][j][r] + bv1) + cr;
                float v2 = acc[2][i][j][r] + bv2;
                acc[0][i][j][r] = v1;
                acc[2][i][j][r] = v2;
                float d = v1 - v2;
                dsum += d * d;
            }
    }

    float* red = (float*)lds;
    red[tid] = dsum;
    __syncthreads();
    for (int o = 128; o > 0; o >>= 1) {
        if (tid < o) red[tid] += red[tid + o];
        __syncthreads();
    }
    if (tid == 0) partial_out[blockIdx.y * gridDim.x + blockIdx.x] = red[0];

    write_tile<BM, BN, FM, FN>(lds, acc[0], C1, (long)m0 * N + n0, N, tid);
    write_tile<BM, BN, FM, FN>(lds, acc[2], C2, (long)m0 * N + n0, N, tid);
}

// ---------------------------------------------------------------------------
// gmix_k v2 (round 8): xg1 = P0 + b0 + th*mixG + om*(P2 + b2); rg1 = P1 + b1
// th from partial_in (in-kernel). mixG staged to LDS bf16 with the write_tile
// XOR swizzle (coalesced in, fragment-layout u16 out) -> diff fully in
// registers, no f32 round-trips, no bank conflicts. Writes only C1 + partials.
// ---------------------------------------------------------------------------
template<int BM, int BN, int FM, int FN>
__global__ __launch_bounds__(256) void gmix_k(
    const __hip_bfloat16* __restrict__ A0, const __hip_bfloat16* __restrict__ B0,
    int K0, const float* __restrict__ b0,
    const __hip_bfloat16* __restrict__ A1, const __hip_bfloat16* __restrict__ B1,
    int K1, const float* __restrict__ b1,
    const __hip_bfloat16* __restrict__ A2, const __hip_bfloat16* __restrict__ B2,
    int K2, const float* __restrict__ b2,
    const __hip_bfloat16* __restrict__ mixG,
    const float* __restrict__ partial_in, int np_in, float inv_in,
    __hip_bfloat16* __restrict__ C1, float* __restrict__ partial_out, int M, int N)
{
    __shared__ __attribute__((aligned(128))) char lds[(BM + BN) * 128];
    char* AsB = lds;
    char* BsB = lds + BM * 128;

    const int m0 = blockIdx.y * BM;
    const int n0 = blockIdx.x * BN;
    const int tid  = threadIdx.x;
    const int wave = tid >> 6;
    const int lane = tid & 63;
    const int wm = wave >> 1, wn = wave & 1;

    f32x4 acc[3][FM][FN];
    #pragma unroll
    for (int p = 0; p < 3; ++p)
        #pragma unroll
        for (int i = 0; i < FM; ++i)
            #pragma unroll
            for (int j = 0; j < FN; ++j)
                acc[p][i][j] = (f32x4){0.f, 0.f, 0.f, 0.f};

    #pragma unroll
    for (int ph = 0; ph < 3; ++ph) {
        const __hip_bfloat16* Ab = (ph == 0) ? A0 : (ph == 1 ? A1 : A2);
        const __hip_bfloat16* Bb = (ph == 0) ? B0 : (ph == 1 ? B1 : B2);
        const int K = (ph == 0) ? K0 : (ph == 1 ? K1 : K2);
        for (int k0 = 0; k0 < K; k0 += 64) {
            stage_tiles<BM, BN>(Ab, Bb, AsB, BsB, m0, n0, k0, K, K, wave, lane);
            __syncthreads();
            mfma_tiles<BM, BN, FM, FN>(AsB, BsB, acc[ph], wave, lane);
            __syncthreads();
        }
    }

    const float th = block_th(partial_in, np_in, inv_in, (float*)lds, tid);
    const float om = 1.f - th;

    // stage mixG tile into LDS (bf16, write_tile swizzle), coalesced uint4 in
    const int TPR = BN / 8;
    const int RPP = 256 / TPR;
    #pragma unroll
    for (int p = 0; p < BM / RPP; ++p) {
        int row = p * RPP + tid / TPR;
        int cb = (tid % TPR) * 16;
        int pb = cb ^ (((row >> 2) & 3) << 5);
        uint4 v = *reinterpret_cast<const uint4*>(
            reinterpret_cast<const char*>(mixG + (long)(m0 + row) * N + n0) + cb);
        *reinterpret_cast<uint4*>(lds + row * (BN * 2) + pb) = v;
    }
    __syncthreads();

    // fragment-layout combine + diff, all in registers
    const int lc  = lane & 15;
    const int lr4 = (lane >> 4) << 2;
    float dsum = 0.f;
    #pragma unroll
    for (int j = 0; j < FN; ++j) {
        int col = n0 + wn * (FN * 16) + j * 16 + lc;
        int colb = (wn * (FN * 16) + j * 16 + lc) * 2;
        float bv0 = b0 ? b0[col] : 0.0f;
        float bv1 = b1 ? b1[col] : 0.0f;
        float bv2 = b2 ? b2[col] : 0.0f;
        #pragma unroll
        for (int i = 0; i < FM; ++i) {
            int row0 = wm * (FM * 16) + i * 16 + lr4;
            #pragma unroll
            for (int r = 0; r < 4; ++r) {
                int row = row0 + r;
                unsigned short g = *reinterpret_cast<const unsigned short*>(
                    lds + row * (BN * 2) + (colb ^ (((row >> 2) & 3) << 5)));
                float v1 = acc[0][i][j][r] + bv0 + th * bf2f(g)
                         + om * (acc[2][i][j][r] + bv2);
                float v2 = acc[1][i][j][r] + bv1;
                acc[0][i][j][r] = v1;
                float d = v1 - v2;
                dsum += d * d;
            }
        }
    }
    __syncthreads();

    float* red = (float*)lds;
    red[tid] = dsum;
    __syncthreads();
    for (int o = 128; o > 0; o >>= 1) {
        if (tid < o) red[tid] += red[tid + o];
        __syncthreads();
    }
    if (tid == 0) partial_out[blockIdx.y * gridDim.x + blockIdx.x] = red[0];

    write_tile<BM, BN, FM, FN>(lds, acc[0], C1, (long)m0 * N + n0, N, tid);
}

// ---------------------------------------------------------------------------
// mix + batched transpose (th in-kernel), writes xwT (b,H,N), ushort4 I/O
// ---------------------------------------------------------------------------
__global__ __launch_bounds__(256) void mixT_k(
    const unsigned short* __restrict__ h, const unsigned short* __restrict__ r,
    const float* __restrict__ partial_in, int np_in, float inv_in,
    unsigned short* __restrict__ xwT)
{
    __shared__ float t[64][65];
    const float th = block_th(partial_in, np_in, inv_in, &t[0][0], (int)threadIdx.x);
    const float om = 1.f - th;
    const long base = (long)blockIdx.z * NN * HH;
    const int r0 = blockIdx.y * 64;
    const int c0 = blockIdx.x * 64;
    const int tr  = threadIdx.x >> 4;
    const int tc4 = (threadIdx.x & 15) * 4;
    #pragma unroll
    for (int i = 0; i < 4; ++i) {
        int rr = i * 16 + tr;
        long idx = base + (long)(r0 + rr) * HH + c0 + tc4;
        ushort4 hv = *reinterpret_cast<const ushort4*>(h + idx);
        ushort4 rv = *reinterpret_cast<const ushort4*>(r + idx);
        t[rr][tc4 + 0] = th * bf2f(hv.x) + om * bf2f(rv.x);
        t[rr][tc4 + 1] = th * bf2f(hv.y) + om * bf2f(rv.y);
        t[rr][tc4 + 2] = th * bf2f(hv.z) + om * bf2f(rv.z);
        t[rr][tc4 + 3] = th * bf2f(hv.w) + om * bf2f(rv.w);
    }
    __syncthreads();
    #pragma unroll
    for (int i = 0; i < 4; ++i) {
        int cc = i * 16 + tr;
        ushort4 v;
        v.x = f2bfu(t[tc4 + 0][cc]);
        v.y = f2bfu(t[tc4 + 1][cc]);
        v.z = f2bfu(t[tc4 + 2][cc]);
        v.w = f2bfu(t[tc4 + 3][cc]);
        *reinterpret_cast<ushort4*>(xwT + base + (long)(c0 + cc) * NN + r0 + tc4) = v;
    }
}

// ---------------------------------------------------------------------------
// final mix (th in-kernel): out = th*h + (1-th)*r, fp32 out
// ---------------------------------------------------------------------------
__global__ __launch_bounds__(256) void mixfinal_k(
    const unsigned short* __restrict__ h, const unsigned short* __restrict__ r,
    const float* __restrict__ partial_in, int np_in, float inv_in,
    float* __restrict__ out, long n4)
{
    __shared__ float sm[256];
    const float th = block_th(partial_in, np_in, inv_in, sm, (int)threadIdx.x);
    const float om = 1.f - th;
    long gid = (long)blockIdx.x * 256 + threadIdx.x;
    long stride = (long)gridDim.x * 256;
    for (long i = gid; i < n4; i += stride) {
        ushort4 hv = reinterpret_cast<const ushort4*>(h)[i];
        ushort4 rv = reinterpret_cast<const ushort4*>(r)[i];
        float4 o;
        o.x = th * bf2f(hv.x) + om * bf2f(rv.x);
        o.y = th * bf2f(hv.y) + om * bf2f(rv.y);
        o.z = th * bf2f(hv.z) + om * bf2f(rv.z);
        o.w = th * bf2f(hv.w) + om * bf2f(rv.w);
        reinterpret_cast<float4*>(out)[i] = o;
    }
}

// ---------------------------------------------------------------------------
extern "C" void kernel_launch(void* const* d_in, const int* in_sizes, int n_in,
                              void* d_out, int out_size, void* d_ws, size_t ws_size,
                              hipStream_t stream)
{
    const float* x       = (const float*)d_in[0];
    const float* adj     = (const float*)d_in[1];
    const float* Wres    = (const float*)d_in[2];
    const float* bres    = (const float*)d_in[3];
    const float* Wg0     = (const float*)d_in[4];
    const float* bg0     = (const float*)d_in[5];
    const float* Wrg0    = (const float*)d_in[6];
    const float* brg0    = (const float*)d_in[7];
    const float* logits0 = (const float*)d_in[8];
    const float* gumb0   = (const float*)d_in[9];
    const float* Wnl0    = (const float*)d_in[10];
    const float* bnl0    = (const float*)d_in[11];
    const float* Wwo0    = (const float*)d_in[12];
    const float* bwo0    = (const float*)d_in[13];
    const float* Wrw0    = (const float*)d_in[14];
    const float* brw0    = (const float*)d_in[15];
    const float* Wg1     = (const float*)d_in[16];
    const float* bg1     = (const float*)d_in[17];
    const float* Wrg1    = (const float*)d_in[18];
    const float* brg1    = (const float*)d_in[19];
    const float* logits1 = (const float*)d_in[20];
    const float* gumb1   = (const float*)d_in[21];
    const float* Wnl1    = (const float*)d_in[22];
    const float* bnl1    = (const float*)d_in[23];
    const float* Wwo1    = (const float*)d_in[24];
    const float* bwo1    = (const float*)d_in[25];
    const float* Wrw1    = (const float*)d_in[26];
    const float* brw1    = (const float*)d_in[27];

    float* out = (float*)d_out;

    // ---- workspace ----
    char* w = (char*)d_ws;
    auto alloc = [&](long bytes) { char* p = w; w += (bytes + 255) & ~255L; return p; };
    const long SLOT = (long)BNR * HH * 2;                 // 32 MB
    char* pool = alloc(5 * SLOT);                         // 160 MB
    __hip_bfloat16* Rbf  = (__hip_bfloat16*)alloc((long)BNR * DOUT * 2); // 8 MB
    __hip_bfloat16* adjb = (__hip_bfloat16*)alloc((long)NN * NN * 2);
    __hip_bfloat16* WT   = (__hip_bfloat16*)alloc(192512L * 2);
    float* partial0 = (float*)alloc(2048 * 4);
    float* partial1 = (float*)alloc(2048 * 4);
    float* partial2 = (float*)alloc(2048 * 4);
    float* partial3 = (float*)alloc(2048 * 4);
    float* c0      = (float*)alloc(256 * 4);
    float* c1      = (float*)alloc(256 * 4);
    float* bg0p    = (float*)alloc(256 * 4);
    float* brg0p   = (float*)alloc(256 * 4);
    float* crow0   = (float*)alloc(256 * 4);
    float* brgc1   = (float*)alloc(64 * 4);
    float* crow1   = (float*)alloc(64 * 4);

    auto S = [&](int i) { return pool + (long)i * SLOT; };
    __hip_bfloat16* xwr = (__hip_bfloat16*)S(0);
    __hip_bfloat16* rw0 = (__hip_bfloat16*)S(1);
    __hip_bfloat16* orw = (__hip_bfloat16*)S(1);                      // after rw0 dead
    __hip_bfloat16* rw1 = (__hip_bfloat16*)(S(1) + (long)BNR * DOUT * 2);
    __hip_bfloat16* xwT = (__hip_bfloat16*)S(2);
    __hip_bfloat16* xg1 = (__hip_bfloat16*)S(2);                      // after xwT dead
    __hip_bfloat16* T1  = (__hip_bfloat16*)S(3);
    __hip_bfloat16* xbf = (__hip_bfloat16*)S(4);
    __hip_bfloat16* xT  = (__hip_bfloat16*)(S(4) + (long)BNR * DIN * 2);
    __hip_bfloat16* T0  = (__hip_bfloat16*)(S(4) + 2L * BNR * DIN * 2);

    // transposed weights inside WT (element offsets)
    __hip_bfloat16* WresT  = WT;             // 64x64
    __hip_bfloat16* Wg0T   = WT + 4096;      // 256x64
    __hip_bfloat16* Wrg0T  = WT + 20480;     // 256x64
    __hip_bfloat16* Wrw0T  = WT + 36864;     // 256x64
    __hip_bfloat16* Wg1T   = WT + 53248;     // 256x256
    __hip_bfloat16* Wrg1T  = WT + 118784;    // 256x64
    __hip_bfloat16* Wc1T   = WT + 135168;    // 64x256 (c1-scaled Wwo1^T)
    __hip_bfloat16* Wrw1T  = WT + 151552;    // 64x64
    __hip_bfloat16* Wg0pT  = WT + 155648;    // 256x64 (Wg0@(I+Wc0))^T
    __hip_bfloat16* Wrg0pT = WT + 172032;    // 256x64 (Wrg0@(I+Wc0))^T
    __hip_bfloat16* Wrgc1T = WT + 188416;    // 64x64  (Wrg1@Wc1)^T

    const dim3 blk(256);
    const float invH = 1.0f / ((float)BNR * HH);
    const float invD = 1.0f / ((float)BNR * DOUT);

    // ---- prep ----
    hipLaunchKernelGGL(coeff_k, dim3(1), dim3(256), 0, stream, logits0, gumb0, Wnl0, c0);
    hipLaunchKernelGGL(coeff_k, dim3(1), dim3(256), 0, stream, logits1, gumb1, Wnl1, c1);
    hipLaunchKernelGGL(cvt_k, dim3(2048), blk, 0, stream, x, (unsigned short*)xbf, (long)BNR * DIN / 4);
    hipLaunchKernelGGL(cvt_k, dim3(256), blk, 0, stream, adj, (unsigned short*)adjb, (long)NN * NN / 4);
    hipLaunchKernelGGL(tcvt_k, dim3(1, 8, 128), blk, 0, stream, x, (unsigned short*)xT, NN, DIN, (long)NN * DIN);

    WTArgs wa;
    wa.src[0] = Wres; wa.dst[0] = (unsigned short*)WresT; wa.cs[0] = nullptr; wa.R[0] = 64;  wa.C[0] = 64;
    wa.src[1] = Wg0;  wa.dst[1] = (unsigned short*)Wg0T;  wa.cs[1] = nullptr; wa.R[1] = 64;  wa.C[1] = 256;
    wa.src[2] = Wrg0; wa.dst[2] = (unsigned short*)Wrg0T; wa.cs[2] = nullptr; wa.R[2] = 64;  wa.C[2] = 256;
    wa.src[3] = Wrw0; wa.dst[3] = (unsigned short*)Wrw0T; wa.cs[3] = nullptr; wa.R[3] = 64;  wa.C[3] = 256;
    wa.src[4] = Wg1;  wa.dst[4] = (unsigned short*)Wg1T;  wa.cs[4] = nullptr; wa.R[4] = 256; wa.C[4] = 256;
    wa.src[5] = Wrg1; wa.dst[5] = (unsigned short*)Wrg1T; wa.cs[5] = nullptr; wa.R[5] = 64;  wa.C[5] = 256;
    wa.src[6] = Wwo1; wa.dst[6] = (unsigned short*)Wc1T;  wa.cs[6] = c1;      wa.R[6] = 256; wa.C[6] = 64;
    wa.src[7] = Wrw1; wa.dst[7] = (unsigned short*)Wrw1T; wa.cs[7] = nullptr; wa.R[7] = 64;  wa.C[7] = 64;
    hipLaunchKernelGGL(tcvt_w_k, dim3(16, 8), blk, 0, stream, wa);

    WFArgs wf;
    wf.Wsrc[0] = Wg0;  wf.Wbig[0] = Wwo0; wf.c[0] = c0; wf.incl[0] = 1; wf.N[0] = 256;
    wf.dst[0] = (unsigned short*)Wg0pT;
    wf.Wsrc[1] = Wrg0; wf.Wbig[1] = Wwo0; wf.c[1] = c0; wf.incl[1] = 1; wf.N[1] = 256;
    wf.dst[1] = (unsigned short*)Wrg0pT;
    wf.Wsrc[2] = Wrg1; wf.Wbig[2] = Wwo1; wf.c[2] = c1; wf.incl[2] = 0; wf.N[2] = 64;
    wf.dst[2] = (unsigned short*)Wrgc1T;
    hipLaunchKernelGGL(wfold_k, dim3(64, 3), blk, 0, stream, wf);

    FVArgs fv;
    fv.W[0] = Wwo0; fv.c[0] = c0;      fv.v[0] = bg0;  fv.base[0] = bg0;  fv.out[0] = bg0p;  fv.K[0] = 256; fv.N[0] = 256;
    fv.W[1] = Wwo0; fv.c[1] = c0;      fv.v[1] = brg0; fv.base[1] = brg0; fv.out[1] = brg0p; fv.K[1] = 256; fv.N[1] = 256;
    fv.W[2] = Wwo0; fv.c[2] = nullptr; fv.v[2] = bnl0; fv.base[2] = bwo0; fv.out[2] = crow0; fv.K[2] = 256; fv.N[2] = 256;
    fv.W[3] = Wwo1; fv.c[3] = c1;      fv.v[3] = brg1; fv.base[3] = nullptr; fv.out[3] = brgc1; fv.K[3] = 256; fv.N[3] = 64;
    fv.W[4] = Wwo1; fv.c[4] = nullptr; fv.v[4] = bnl1; fv.base[4] = bwo1; fv.out[4] = crow1; fv.K[4] = 256; fv.N[4] = 64;
    hipLaunchKernelGGL(foldvec_k, dim3(256, 5), blk, 0, stream, fv);

    // res = x @ Wres + bres
    hipLaunchKernelGGL((gemm_bt_k<128, 64, 4, 2>), dim3(1, BNR / 128, 1), blk, 0, stream,
                       xbf, WresT, bres, Rbf, BNR, DOUT, DIN, 0, 0, 0);

    // T0 = adj @ x (batched)
    hipLaunchKernelGGL((gemm_bt_k<128, 64, 4, 2>), dim3(1, 4, BB), blk, 0, stream,
                       adjb, xT, nullptr, T0, NN, DIN, NN, 0, (long)DIN * NN, (long)NN * DIN);

    // D0: diff0 partials only (xg vs rg, never materialized)
    hipLaunchKernelGGL((dual_k<64, 128, 2, 4>), dim3(2, BNR / 64), blk, 0, stream,
                       T0, Wg0T, bg0, Rbf, Wrg0T, brg0, partial0, BNR, HH, DIN, DOUT);

    // W0: xwr = th0*(T0@Wg0p+bg0p)+om0*(Rbf@Wrg0p+brg0p)+crow0 ; rw0 = Rbf@Wrw0+brw0
    hipLaunchKernelGGL((wave_k<64, 128, 2, 4>), dim3(2, BNR / 64), blk, 0, stream,
                       T0, Wg0pT, DIN, bg0p,
                       Rbf, Wrg0pT, DOUT, brg0p,
                       Rbf, Wrw0T, DOUT, brw0,
                       partial0, 2048, invH, crow0, xwr, rw0, partial1, BNR, HH);

    // xwT = transpose(mix(xwr, rw0))  (th1 from partial1 in-kernel)
    hipLaunchKernelGGL(mixT_k, dim3(4, 8, BB), blk, 0, stream,
                       (const unsigned short*)xwr, (const unsigned short*)rw0,
                       partial1, 2048, invH, (unsigned short*)xwT);

    // T1 = adj @ xw (batched)
    hipLaunchKernelGGL((gemm_bt_k<128, 128, 4, 4>), dim3(2, 4, BB), blk, 0, stream,
                       adjb, xwT, nullptr, T1, NN, HH, NN, 0, (long)HH * NN, (long)NN * HH);

    // DM1: xg1 = T1@Wg1+bg1 + th1*xwr + om1*(Rbf@Wrw0+brw0); rg1 in-reg (diff only)
    hipLaunchKernelGGL((gmix_k<64, 128, 2, 4>), dim3(2, BNR / 64), blk, 0, stream,
                       T1, Wg1T, HH, bg1,
                       Rbf, Wrg1T, DOUT, brg1,
                       Rbf, Wrw0T, DOUT, brw0,
                       xwr, partial1, 2048, invH, xg1, partial2, BNR, HH);

    // F: orw = th2*(xg1@Wc1) + om2*(Rbf@Wrgc1+brgc1) + crow1 ; rw1 = Rbf@Wrw1+brw1
    hipLaunchKernelGGL((wave_k<64, 64, 2, 2>), dim3(1, BNR / 64), blk, 0, stream,
                       xg1, Wc1T, HH, (const float*)nullptr,
                       Rbf, Wrgc1T, DOUT, brgc1,
                       Rbf, Wrw1T, DIN, brw1,
                       partial2, 2048, invH, crow1, orw, rw1, partial3, BNR, DOUT);

    // final mix -> fp32 out (th3 from partial3 in-kernel)
    hipLaunchKernelGGL(mixfinal_k, dim3(2048), blk, 0, stream,
                       (const unsigned short*)orw, (const unsigned short*)rw1,
                       partial3, 1024, invD, out, (long)BNR * DOUT / 4);
}

// Round 9
// 204.583 us; speedup vs baseline: 1.1047x; 1.1047x over previous
//
#include <hip/hip_runtime.h>
#include <hip/hip_bf16.h>
#include <math.h>

#define BB   128
#define NN   512
#define DIN  64
#define HH   256
#define DOUT 64
#define BNR  (BB * NN)          // 65536 rows

typedef float  f32x4  __attribute__((ext_vector_type(4)));
typedef __bf16 bf16x8 __attribute__((ext_vector_type(8)));

#define GLP(p)  ((const __attribute__((address_space(1))) void*)(p))
#define LDSP(p) ((__attribute__((address_space(3))) void*)(p))

// Haar/db1 'zero' DWT patterns, levels 1..3, FULL_LEN=8
__constant__ float PAT[3][8] = {
    {0.70710678f, 0.70710678f, 0.f, 0.f, 0.f, 0.f, 0.f, 0.f},
    {0.5f,        0.70710678f, 0.f, 0.5f, 0.f, 0.f, 0.f, 0.f},
    {0.35355339f, 0.70710678f, 0.f, 0.f, 0.f, 0.5f, 0.f, 0.35355339f}
};

__device__ __forceinline__ unsigned short f2bfu(float x) {
    __hip_bfloat16 b = __float2bfloat16(x);
    unsigned short u;
    __builtin_memcpy(&u, &b, 2);
    return u;
}
__device__ __forceinline__ float bf2f(unsigned short u) {
    unsigned int v = ((unsigned int)u) << 16;
    float f;
    __builtin_memcpy(&f, &v, 4);
    return f;
}

// ---------------------------------------------------------------------------
// In-kernel th = sigmoid(mean diff) — same tree order everywhere.
// ---------------------------------------------------------------------------
__device__ __forceinline__ float block_th(const float* __restrict__ partial, int np,
                                          float inv_n, float* red, int tid)
{
    float s = 0.f;
    for (int i = tid; i < np; i += 256) s += partial[i];
    red[tid] = s;
    __syncthreads();
    for (int o = 128; o > 0; o >>= 1) {
        if (tid < o) red[tid] += red[tid + o];
        __syncthreads();
    }
    float th = 1.f / (1.f + expf(-red[0] * inv_n));
    __syncthreads();
    return th;
}

// ---------------------------------------------------------------------------
// Coalesced bf16 tile write via LDS staging (proven round 4).
// ---------------------------------------------------------------------------
template<int BM, int BN, int FM, int FN>
__device__ __forceinline__ void write_tile(char* lds, f32x4 (&a)[FM][FN],
                                           __hip_bfloat16* __restrict__ C,
                                           long base, int N, int tid)
{
    const int wave = tid >> 6;
    const int lane = tid & 63;
    const int wm = wave >> 1, wn = wave & 1;
    const int lc = lane & 15;
    const int lr4 = (lane >> 4) << 2;
    __syncthreads();
    #pragma unroll
    for (int j = 0; j < FN; ++j) {
        int colb = (wn * (FN * 16) + j * 16 + lc) * 2;
        #pragma unroll
        for (int i = 0; i < FM; ++i) {
            int row0 = wm * (FM * 16) + i * 16 + lr4;
            #pragma unroll
            for (int r = 0; r < 4; ++r) {
                int row = row0 + r;
                *reinterpret_cast<unsigned short*>(
                    lds + row * (BN * 2) + (colb ^ (((row >> 2) & 3) << 5))) =
                    f2bfu(a[i][j][r]);
            }
        }
    }
    __syncthreads();
    const int TPR = BN / 8;
    const int RPP = 256 / TPR;
    #pragma unroll
    for (int p = 0; p < BM / RPP; ++p) {
        int row = p * RPP + tid / TPR;
        int cb = (tid % TPR) * 16;
        int pb = cb ^ (((row >> 2) & 3) << 5);
        uint4 v = *reinterpret_cast<const uint4*>(lds + row * (BN * 2) + pb);
        *reinterpret_cast<uint4*>(reinterpret_cast<char*>(C + base + (long)row * N) + cb) = v;
    }
}

// ---------------------------------------------------------------------------
// staging of one K=64 slab of A(BM rows) + B(BN rows) into swizzled LDS
// ---------------------------------------------------------------------------
template<int BM, int BN>
__device__ __forceinline__ void stage_tiles(const __hip_bfloat16* __restrict__ Ab,
                                            const __hip_bfloat16* __restrict__ Bb,
                                            char* AsB, char* BsB,
                                            int m0, int n0, int k0, int KA, int KB,
                                            int wave, int lane)
{
    const int NCH = (BM + BN) / 32;
    const int lr = lane >> 3;
    const int ls = lane & 7;
    #pragma unroll
    for (int cc = 0; cc < NCH; ++cc) {
        int c = wave * NCH + cc;
        const __hip_bfloat16* src;
        char* ldsb;
        if (c < BM / 8) {
            int r = c * 8 + lr;
            ldsb = AsB + c * 1024;
            src = Ab + ((long)(m0 + r) * KA + k0 + ((ls ^ (r & 7)) << 3));
        } else {
            int c2 = c - BM / 8;
            int r = c2 * 8 + lr;
            ldsb = BsB + c2 * 1024;
            src = Bb + ((long)(n0 + r) * KB + k0 + ((ls ^ (r & 7)) << 3));
        }
        __builtin_amdgcn_global_load_lds(GLP(src), LDSP(ldsb), 16, 0, 0);
    }
}

template<int BM, int BN, int FM, int FN>
__device__ __forceinline__ void mfma_tiles(char* AsB, char* BsB,
                                           f32x4 (&acc)[FM][FN], int wave, int lane)
{
    const int wm = wave >> 1, wn = wave & 1;
    #pragma unroll
    for (int ksl = 0; ksl < 2; ++ksl) {
        bf16x8 af[FM], bfr[FN];
        #pragma unroll
        for (int i = 0; i < FM; ++i) {
            int row = wm * (FM * 16) + i * 16 + (lane & 15);
            int off = (ksl * 64 + ((lane >> 4) << 4)) ^ ((row & 7) << 4);
            af[i] = *reinterpret_cast<const bf16x8*>(AsB + row * 128 + off);
        }
        #pragma unroll
        for (int j = 0; j < FN; ++j) {
            int row = wn * (FN * 16) + j * 16 + (lane & 15);
            int off = (ksl * 64 + ((lane >> 4) << 4)) ^ ((row & 7) << 4);
            bfr[j] = *reinterpret_cast<const bf16x8*>(BsB + row * 128 + off);
        }
        #pragma unroll
        for (int i = 0; i < FM; ++i)
            #pragma unroll
            for (int j = 0; j < FN; ++j)
                acc[i][j] = __builtin_amdgcn_mfma_f32_16x16x32_bf16(
                    af[i], bfr[j], acc[i][j], 0, 0, 0);
    }
}

// ---------------------------------------------------------------------------
// fp32 -> bf16 convert
// ---------------------------------------------------------------------------
__global__ __launch_bounds__(256) void cvt_k(const float* __restrict__ in,
                                             unsigned short* __restrict__ out, long n4)
{
    long gid = (long)blockIdx.x * 256 + threadIdx.x;
    long stride = (long)gridDim.x * 256;
    for (long i = gid; i < n4; i += stride) {
        float4 v = reinterpret_cast<const float4*>(in)[i];
        ushort4 u;
        u.x = f2bfu(v.x); u.y = f2bfu(v.y); u.z = f2bfu(v.z); u.w = f2bfu(v.w);
        reinterpret_cast<ushort4*>(out)[i] = u;
    }
}

// ---------------------------------------------------------------------------
// transpose-convert fp32 (R,C) -> bf16 (C,R), optional per-src-row scale + sign
// ---------------------------------------------------------------------------
__device__ __forceinline__ void tcvt_body(const float* __restrict__ in,
                                          unsigned short* __restrict__ out,
                                          const float* __restrict__ cs, float us,
                                          int R, int C, int r0, int c0)
{
    __shared__ float t[64][65];
    int tr = threadIdx.x >> 6;
    int tc = threadIdx.x & 63;
    #pragma unroll
    for (int i = 0; i < 16; ++i) {
        int r = i * 4 + tr;
        t[r][tc] = in[(long)(r0 + r) * C + c0 + tc];
    }
    __syncthreads();
    float sc = (cs ? cs[r0 + tc] : 1.0f) * us;
    #pragma unroll
    for (int i = 0; i < 16; ++i) {
        int r = i * 4 + tr;
        out[(long)(c0 + r) * R + r0 + tc] = f2bfu(t[tc][r] * sc);
    }
}

__global__ __launch_bounds__(256) void tcvt_k(const float* __restrict__ in,
                                              unsigned short* __restrict__ out,
                                              int R, int C, long sz)
{
    long base = (long)blockIdx.z * sz;
    tcvt_body(in + base, out + base, nullptr, 1.0f, R, C, blockIdx.y * 64, blockIdx.x * 64);
}

struct WTArgs {
    const float* src[8];
    unsigned short* dst[8];
    const float* cs[8];
    float sgn[8];
    int R[8], C[8];
};
__global__ __launch_bounds__(256) void tcvt_w_k(WTArgs a)
{
    int wgt = blockIdx.y;
    int R = a.R[wgt], C = a.C[wgt];
    int tilesX = C >> 6;
    int tiles = (R >> 6) * tilesX;
    int t = blockIdx.x;
    if (t >= tiles) return;
    tcvt_body(a.src[wgt], a.dst[wgt], a.cs[wgt], a.sgn[wgt], R, C,
              (t / tilesX) * 64, (t % tilesX) * 64);
}

// ---------------------------------------------------------------------------
// wavelet coeff
// ---------------------------------------------------------------------------
__global__ void coeff_k(const float* __restrict__ logits, const float* __restrict__ gumb,
                        const float* __restrict__ Wnl, float* __restrict__ coeff)
{
    int f = threadIdx.x;
    float l0 = logits[0] + gumb[f * 3 + 0];
    float l1 = logits[1] + gumb[f * 3 + 1];
    float l2 = logits[2] + gumb[f * 3 + 2];
    int bl = 0;
    float bv = l0;
    if (l1 > bv) { bv = l1; bl = 1; }
    if (l2 > bv) { bv = l2; bl = 2; }
    float s = 0.f;
    #pragma unroll
    for (int t = 0; t < 8; ++t) s += Wnl[f * 8 + t] * PAT[bl][t];
    coeff[f] = s;
}

// ---------------------------------------------------------------------------
// batched vector folds: out[n] = (base? base[n]:0) + sum_k v[k]*(c?c[k]:1)*W[k,n]
// ---------------------------------------------------------------------------
struct FVArgs {
    const float* W[5];
    const float* c[5];
    const float* v[5];
    const float* base[5];
    float* out[5];
    int K[5], N[5];
};
__global__ __launch_bounds__(256) void foldvec_k(FVArgs a)
{
    int cs = blockIdx.y;
    int n = blockIdx.x;
    if (n >= a.N[cs]) return;
    int k = threadIdx.x;
    float s = 0.f;
    if (k < a.K[cs]) {
        float cc = a.c[cs] ? a.c[cs][k] : 1.0f;
        s = a.v[cs][k] * cc * a.W[cs][(long)k * a.N[cs] + n];
    }
    __shared__ float sm[256];
    sm[threadIdx.x] = s;
    __syncthreads();
    for (int o = 128; o > 0; o >>= 1) {
        if (threadIdx.x < o) sm[threadIdx.x] += sm[threadIdx.x + o];
        __syncthreads();
    }
    if (threadIdx.x == 0)
        a.out[cs][n] = (a.base[cs] ? a.base[cs][n] : 0.f) + sm[0];
}

// ---------------------------------------------------------------------------
// batched weight folds (transposed bf16 out, M=64 rows, K=256 fixed)
// ---------------------------------------------------------------------------
struct WFArgs {
    const float* Wsrc[3];
    const float* Wbig[3];
    const float* c[3];
    int incl[3], N[3];
    unsigned short* dst[3];
};
__global__ __launch_bounds__(256) void wfold_k(WFArgs a)
{
    int cs = blockIdx.y;
    int m = blockIdx.x;
    __shared__ float ws[256];
    ws[threadIdx.x] = a.Wsrc[cs][m * 256 + threadIdx.x] * a.c[cs][threadIdx.x];
    __syncthreads();
    int n = threadIdx.x;
    int N = a.N[cs];
    if (n >= N) return;
    float s = a.incl[cs] ? a.Wsrc[cs][m * 256 + n] : 0.f;
    const float* Wb = a.Wbig[cs];
    #pragma unroll 8
    for (int k = 0; k < 256; ++k)
        s += ws[k] * Wb[(long)k * N + n];
    a.dst[cs][n * 64 + m] = f2bfu(s);
}

// ---------------------------------------------------------------------------
// sc kernels: compute th from partials, scale folded weights in place,
// and fold the matching bias vectors. grid = 64 blocks x 256.
// ---------------------------------------------------------------------------
__global__ __launch_bounds__(256) void sc0_k(
    const float* __restrict__ partial, int np, float inv_n,
    unsigned short* __restrict__ Wa,   // 16384 *= th
    unsigned short* __restrict__ Wb,   // 16384 *= om
    const float* __restrict__ bg0p, const float* __restrict__ brg0p,
    const float* __restrict__ crow0, float* __restrict__ cv0)  // 256
{
    __shared__ float red[256];
    float th = block_th(partial, np, inv_n, red, threadIdx.x);
    float om = 1.f - th;
    int g = blockIdx.x * 256 + threadIdx.x;
    Wa[g] = f2bfu(th * bf2f(Wa[g]));
    Wb[g] = f2bfu(om * bf2f(Wb[g]));
    if (g < 256) cv0[g] = th * bg0p[g] + om * brg0p[g] + crow0[g];
}

__global__ __launch_bounds__(256) void sc1_k(
    const float* __restrict__ partial, int np, float inv_n,
    const unsigned short* __restrict__ Wrw0T, unsigned short* __restrict__ Wrw0sT,
    const float* __restrict__ bg1, const float* __restrict__ brw0,
    float* __restrict__ bv1g)
{
    __shared__ float red[256];
    float th = block_th(partial, np, inv_n, red, threadIdx.x);
    float om = 1.f - th;
    int g = blockIdx.x * 256 + threadIdx.x;
    Wrw0sT[g] = f2bfu(om * bf2f(Wrw0T[g]));
    if (g < 256) bv1g[g] = bg1[g] + om * brw0[g];
}

__global__ __launch_bounds__(256) void sc2_k(
    const float* __restrict__ partial, int np, float inv_n,
    unsigned short* __restrict__ Wc1T,    // 16384 *= th
    unsigned short* __restrict__ Wrgc1T,  // 4096  *= om
    const float* __restrict__ brgc1, const float* __restrict__ crow1,
    float* __restrict__ cv2)              // 64
{
    __shared__ float red[256];
    float th = block_th(partial, np, inv_n, red, threadIdx.x);
    float om = 1.f - th;
    int g = blockIdx.x * 256 + threadIdx.x;
    Wc1T[g] = f2bfu(th * bf2f(Wc1T[g]));
    if (g < 4096) Wrgc1T[g] = f2bfu(om * bf2f(Wrgc1T[g]));
    if (g < 64) cv2[g] = om * brgc1[g] + crow1[g];
}

// ---------------------------------------------------------------------------
// Single MFMA bf16 GEMM (bf16 out, coalesced epilogue)
// ---------------------------------------------------------------------------
template<int BM, int BN, int FM, int FN>
__global__ __launch_bounds__(256) void gemm_bt_k(
    const __hip_bfloat16* __restrict__ A, const __hip_bfloat16* __restrict__ Bt,
    const float* __restrict__ bias, __hip_bfloat16* __restrict__ Cb,
    int M, int N, int K, long sA, long sB, long sC)
{
    __shared__ __attribute__((aligned(128))) char lds[(BM + BN) * 128];
    char* AsB = lds;
    char* BsB = lds + BM * 128;

    const long bz = blockIdx.z;
    const __hip_bfloat16* Ab = A + bz * sA;
    const __hip_bfloat16* Bb = Bt + bz * sB;

    const int m0 = blockIdx.y * BM;
    const int n0 = blockIdx.x * BN;
    const int tid  = threadIdx.x;
    const int wave = tid >> 6;
    const int lane = tid & 63;
    const int wn = wave & 1;

    f32x4 acc[FM][FN];
    #pragma unroll
    for (int i = 0; i < FM; ++i)
        #pragma unroll
        for (int j = 0; j < FN; ++j)
            acc[i][j] = (f32x4){0.f, 0.f, 0.f, 0.f};

    for (int k0 = 0; k0 < K; k0 += 64) {
        stage_tiles<BM, BN>(Ab, Bb, AsB, BsB, m0, n0, k0, K, K, wave, lane);
        __syncthreads();
        mfma_tiles<BM, BN, FM, FN>(AsB, BsB, acc, wave, lane);
        __syncthreads();
    }

    const int lc = lane & 15;
    #pragma unroll
    for (int j = 0; j < FN; ++j) {
        int col = n0 + wn * (FN * 16) + j * 16 + lc;
        float bv = bias ? bias[col] : 0.0f;
        #pragma unroll
        for (int i = 0; i < FM; ++i)
            #pragma unroll
            for (int r = 0; r < 4; ++r)
                acc[i][j][r] += bv;
    }
    write_tile<BM, BN, FM, FN>(lds, acc, Cb, bz * sC + (long)m0 * N + n0, N, tid);
}

// ---------------------------------------------------------------------------
// dual1_k (D0): ONE accumulator. acc = A0@B0 + A1@B1 (B1 pre-negated).
// diff = acc + b1[col] - b2[col]; partials only.
// ---------------------------------------------------------------------------
template<int BM, int BN, int FM, int FN>
__global__ __launch_bounds__(256) void dual1_k(
    const __hip_bfloat16* __restrict__ A0, const __hip_bfloat16* __restrict__ B0, int K0,
    const __hip_bfloat16* __restrict__ A1, const __hip_bfloat16* __restrict__ B1, int K1,
    const float* __restrict__ b1, const float* __restrict__ b2,
    float* __restrict__ partial, int M, int N)
{
    __shared__ __attribute__((aligned(128))) char lds[(BM + BN) * 128];
    char* AsB = lds;
    char* BsB = lds + BM * 128;

    const int m0 = blockIdx.y * BM;
    const int n0 = blockIdx.x * BN;
    const int tid  = threadIdx.x;
    const int wave = tid >> 6;
    const int lane = tid & 63;
    const int wn = wave & 1;

    f32x4 acc[FM][FN];
    #pragma unroll
    for (int i = 0; i < FM; ++i)
        #pragma unroll
        for (int j = 0; j < FN; ++j)
            acc[i][j] = (f32x4){0.f, 0.f, 0.f, 0.f};

    #pragma unroll
    for (int ph = 0; ph < 2; ++ph) {
        const __hip_bfloat16* Ab = ph ? A1 : A0;
        const __hip_bfloat16* Bb = ph ? B1 : B0;
        const int K = ph ? K1 : K0;
        for (int k0 = 0; k0 < K; k0 += 64) {
            stage_tiles<BM, BN>(Ab, Bb, AsB, BsB, m0, n0, k0, K, K, wave, lane);
            __syncthreads();
            mfma_tiles<BM, BN, FM, FN>(AsB, BsB, acc, wave, lane);
            __syncthreads();
        }
    }

    const int lc = lane & 15;
    float dsum = 0.f;
    #pragma unroll
    for (int j = 0; j < FN; ++j) {
        int col = n0 + wn * (FN * 16) + j * 16 + lc;
        float bd = b1[col] - b2[col];
        #pragma unroll
        for (int i = 0; i < FM; ++i)
            #pragma unroll
            for (int r = 0; r < 4; ++r) {
                float d = acc[i][j][r] + bd;
                dsum += d * d;
            }
    }

    float* red = (float*)lds;
    red[tid] = dsum;
    __syncthreads();
    for (int o = 128; o > 0; o >>= 1) {
        if (tid < o) red[tid] += red[tid + o];
        __syncthreads();
    }
    if (tid == 0) partial[blockIdx.y * gridDim.x + blockIdx.x] = red[0];
}

// ---------------------------------------------------------------------------
// wave2_k (W0, F): TWO accumulators, weights pre-scaled by th/om on device:
//   acc0 = A0@B0 + A1@B1 ; acc1 = A2@B2
//   C1 = acc0 + cv[col] ; C2 = acc1 + b2v[col] ; partial_out += (C1-C2)^2
// ---------------------------------------------------------------------------
template<int BM, int BN, int FM, int FN>
__global__ __launch_bounds__(256) void wave2_k(
    const __hip_bfloat16* __restrict__ A0, const __hip_bfloat16* __restrict__ B0, int K0,
    const __hip_bfloat16* __restrict__ A1, const __hip_bfloat16* __restrict__ B1, int K1,
    const __hip_bfloat16* __restrict__ A2, const __hip_bfloat16* __restrict__ B2, int K2,
    const float* __restrict__ cv, const float* __restrict__ b2v,
    __hip_bfloat16* __restrict__ C1, __hip_bfloat16* __restrict__ C2,
    float* __restrict__ partial_out, int M, int N)
{
    __shared__ __attribute__((aligned(128))) char lds[(BM + BN) * 128];
    char* AsB = lds;
    char* BsB = lds + BM * 128;

    const int m0 = blockIdx.y * BM;
    const int n0 = blockIdx.x * BN;
    const int tid  = threadIdx.x;
    const int wave = tid >> 6;
    const int lane = tid & 63;
    const int wn = wave & 1;

    f32x4 acc0[FM][FN], acc1[FM][FN];
    #pragma unroll
    for (int i = 0; i < FM; ++i)
        #pragma unroll
        for (int j = 0; j < FN; ++j) {
            acc0[i][j] = (f32x4){0.f, 0.f, 0.f, 0.f};
            acc1[i][j] = (f32x4){0.f, 0.f, 0.f, 0.f};
        }

    #pragma unroll
    for (int ph = 0; ph < 3; ++ph) {
        const __hip_bfloat16* Ab = (ph == 0) ? A0 : (ph == 1 ? A1 : A2);
        const __hip_bfloat16* Bb = (ph == 0) ? B0 : (ph == 1 ? B1 : B2);
        const int K = (ph == 0) ? K0 : (ph == 1 ? K1 : K2);
        for (int k0 = 0; k0 < K; k0 += 64) {
            stage_tiles<BM, BN>(Ab, Bb, AsB, BsB, m0, n0, k0, K, K, wave, lane);
            __syncthreads();
            if (ph < 2) mfma_tiles<BM, BN, FM, FN>(AsB, BsB, acc0, wave, lane);
            else        mfma_tiles<BM, BN, FM, FN>(AsB, BsB, acc1, wave, lane);
            __syncthreads();
        }
    }

    const int lc = lane & 15;
    float dsum = 0.f;
    #pragma unroll
    for (int j = 0; j < FN; ++j) {
        int col = n0 + wn * (FN * 16) + j * 16 + lc;
        float c1 = cv[col];
        float c2 = b2v[col];
        #pragma unroll
        for (int i = 0; i < FM; ++i)
            #pragma unroll
            for (int r = 0; r < 4; ++r) {
                float v1 = acc0[i][j][r] + c1;
                float v2 = acc1[i][j][r] + c2;
                acc0[i][j][r] = v1;
                acc1[i][j][r] = v2;
                float d = v1 - v2;
                dsum += d * d;
            }
    }

    float* red = (float*)lds;
    red[tid] = dsum;
    __syncthreads();
    for (int o = 128; o > 0; o >>= 1) {
        if (tid < o) red[tid] += red[tid + o];
        __syncthreads();
    }
    if (tid == 0) partial_out[blockIdx.y * gridDim.x + blockIdx.x] = red[0];

    write_tile<BM, BN, FM, FN>(lds, acc0, C1, (long)m0 * N + n0, N, tid);
    write_tile<BM, BN, FM, FN>(lds, acc1, C2, (long)m0 * N + n0, N, tid);
}

// ---------------------------------------------------------------------------
// gmix2_k: acc0 = T1@Wg1 + Rbf@(om1*Wrw0) ; acc1 = Rbf@Wrg1
//   v1 = acc0 + bv1[col] + th*mixG ; v2 = acc1 + b2v[col]
// f32 LDS epilogue with write_tile-style XOR swizzle (2-way = free), split-
// column f32x4 reads + coalesced uint2 mixG/C1 global accesses.
// ---------------------------------------------------------------------------
template<int BM, int BN, int FM, int FN>
__global__ __launch_bounds__(256) void gmix2_k(
    const __hip_bfloat16* __restrict__ A0, const __hip_bfloat16* __restrict__ B0, int K0,
    const __hip_bfloat16* __restrict__ A1, const __hip_bfloat16* __restrict__ B1, int K1,
    const __hip_bfloat16* __restrict__ A2, const __hip_bfloat16* __restrict__ B2, int K2,
    const float* __restrict__ bv1, const float* __restrict__ b2v,
    const __hip_bfloat16* __restrict__ mixG,
    const float* __restrict__ partial_in, int np_in, float inv_in,
    __hip_bfloat16* __restrict__ C1, float* __restrict__ partial_out, int M, int N)
{
    __shared__ __attribute__((aligned(128))) char lds[BM * BN * 4];   // 32KB >= staging 24KB
    char* AsB = lds;
    char* BsB = lds + BM * 128;

    const int m0 = blockIdx.y * BM;
    const int n0 = blockIdx.x * BN;
    const int tid  = threadIdx.x;
    const int wave = tid >> 6;
    const int lane = tid & 63;
    const int wm = wave >> 1, wn = wave & 1;

    f32x4 acc0[FM][FN], acc1[FM][FN];
    #pragma unroll
    for (int i = 0; i < FM; ++i)
        #pragma unroll
        for (int j = 0; j < FN; ++j) {
            acc0[i][j] = (f32x4){0.f, 0.f, 0.f, 0.f};
            acc1[i][j] = (f32x4){0.f, 0.f, 0.f, 0.f};
        }

    #pragma unroll
    for (int ph = 0; ph < 3; ++ph) {
        const __hip_bfloat16* Ab = (ph == 0) ? A0 : (ph == 1 ? A1 : A2);
        const __hip_bfloat16* Bb = (ph == 0) ? B0 : (ph == 1 ? B1 : B2);
        const int K = (ph == 0) ? K0 : (ph == 1 ? K1 : K2);
        for (int k0 = 0; k0 < K; k0 += 64) {
            stage_tiles<BM, BN>(Ab, Bb, AsB, BsB, m0, n0, k0, K, K, wave, lane);
            __syncthreads();
            if (ph < 2) mfma_tiles<BM, BN, FM, FN>(AsB, BsB, acc0, wave, lane);
            else        mfma_tiles<BM, BN, FM, FN>(AsB, BsB, acc1, wave, lane);
            __syncthreads();
        }
    }

    const float th = block_th(partial_in, np_in, inv_in, (float*)lds, tid);

    const int lc  = lane & 15;
    const int lr4 = (lane >> 4) << 2;
    const int tl  = tid & 15;
    const int trow = tid >> 4;          // 0..15

    // ---- pass A: LDS <- acc0 + bv1 (swizzled f32) ----
    #pragma unroll
    for (int j = 0; j < FN; ++j) {
        int cl = wn * (FN * 16) + j * 16 + lc;
        float bv = bv1[n0 + cl];
        #pragma unroll
        for (int i = 0; i < FM; ++i) {
            int row0 = wm * (FM * 16) + i * 16 + lr4;
            #pragma unroll
            for (int r = 0; r < 4; ++r) {
                int row = row0 + r;
                *reinterpret_cast<float*>(
                    lds + row * (BN * 4) + ((cl * 4) ^ (((row >> 2) & 3) << 5))) =
                    acc0[i][j][r] + bv;
            }
        }
    }
    __syncthreads();

    float v1k[BM / 16][8];
    float dsum = 0.f;
    #pragma unroll
    for (int p = 0; p < BM / 16; ++p) {
        int row = p * 16 + trow;
        int swz = ((row >> 2) & 3) << 5;
        #pragma unroll
        for (int s = 0; s < 2; ++s) {
            int cl4 = s * (BN / 2) + tl * 4;
            f32x4 v = *reinterpret_cast<const f32x4*>(
                lds + row * (BN * 4) + ((cl4 * 4) ^ swz));
            long gidx = (long)(m0 + row) * N + n0 + cl4;
            uint2 g = *reinterpret_cast<const uint2*>(mixG + gidx);
            float o0 = v[0] + th * bf2f((unsigned short)(g.x & 0xffff));
            float o1 = v[1] + th * bf2f((unsigned short)(g.x >> 16));
            float o2 = v[2] + th * bf2f((unsigned short)(g.y & 0xffff));
            float o3 = v[3] + th * bf2f((unsigned short)(g.y >> 16));
            v1k[p][s * 4 + 0] = o0; v1k[p][s * 4 + 1] = o1;
            v1k[p][s * 4 + 2] = o2; v1k[p][s * 4 + 3] = o3;
            uint2 ow;
            ow.x = (unsigned int)f2bfu(o0) | ((unsigned int)f2bfu(o1) << 16);
            ow.y = (unsigned int)f2bfu(o2) | ((unsigned int)f2bfu(o3) << 16);
            *reinterpret_cast<uint2*>(C1 + gidx) = ow;
        }
    }
    __syncthreads();

    // ---- pass B: LDS <- acc1 + b2v ; diff vs kept v1 ----
    #pragma unroll
    for (int j = 0; j < FN; ++j) {
        int cl = wn * (FN * 16) + j * 16 + lc;
        float bv = b2v[n0 + cl];
        #pragma unroll
        for (int i = 0; i < FM; ++i) {
            int row0 = wm * (FM * 16) + i * 16 + lr4;
            #pragma unroll
            for (int r = 0; r < 4; ++r) {
                int row = row0 + r;
                *reinterpret_cast<float*>(
                    lds + row * (BN * 4) + ((cl * 4) ^ (((row >> 2) & 3) << 5))) =
                    acc1[i][j][r] + bv;
            }
        }
    }
    __syncthreads();

    #pragma unroll
    for (int p = 0; p < BM / 16; ++p) {
        int row = p * 16 + trow;
        int swz = ((row >> 2) & 3) << 5;
        #pragma unroll
        for (int s = 0; s < 2; ++s) {
            int cl4 = s * (BN / 2) + tl * 4;
            f32x4 v = *reinterpret_cast<const f32x4*>(
                lds + row * (BN * 4) + ((cl4 * 4) ^ swz));
            #pragma unroll
            for (int q = 0; q < 4; ++q) {
                float d = v1k[p][s * 4 + q] - v[q];
                dsum += d * d;
            }
        }
    }
    __syncthreads();

    float* red = (float*)lds;
    red[tid] = dsum;
    __syncthreads();
    for (int o = 128; o > 0; o >>= 1) {
        if (tid < o) red[tid] += red[tid + o];
        __syncthreads();
    }
    if (tid == 0) partial_out[blockIdx.y * gridDim.x + blockIdx.x] = red[0];
}

// ---------------------------------------------------------------------------
// mix + batched transpose (th in-kernel), writes xwT (b,H,N), ushort4 I/O
// ---------------------------------------------------------------------------
__global__ __launch_bounds__(256) void mixT_k(
    const unsigned short* __restrict__ h, const unsigned short* __restrict__ r,
    const float* __restrict__ partial_in, int np_in, float inv_in,
    unsigned short* __restrict__ xwT)
{
    __shared__ float t[64][65];
    const float th = block_th(partial_in, np_in, inv_in, &t[0][0], (int)threadIdx.x);
    const float om = 1.f - th;
    const long base = (long)blockIdx.z * NN * HH;
    const int r0 = blockIdx.y * 64;
    const int c0 = blockIdx.x * 64;
    const int tr  = threadIdx.x >> 4;
    const int tc4 = (threadIdx.x & 15) * 4;
    #pragma unroll
    for (int i = 0; i < 4; ++i) {
        int rr = i * 16 + tr;
        long idx = base + (long)(r0 + rr) * HH + c0 + tc4;
        ushort4 hv = *reinterpret_cast<const ushort4*>(h + idx);
        ushort4 rv = *reinterpret_cast<const ushort4*>(r + idx);
        t[rr][tc4 + 0] = th * bf2f(hv.x) + om * bf2f(rv.x);
        t[rr][tc4 + 1] = th * bf2f(hv.y) + om * bf2f(rv.y);
        t[rr][tc4 + 2] = th * bf2f(hv.z) + om * bf2f(rv.z);
        t[rr][tc4 + 3] = th * bf2f(hv.w) + om * bf2f(rv.w);
    }
    __syncthreads();
    #pragma unroll
    for (int i = 0; i < 4; ++i) {
        int cc = i * 16 + tr;
        ushort4 v;
        v.x = f2bfu(t[tc4 + 0][cc]);
        v.y = f2bfu(t[tc4 + 1][cc]);
        v.z = f2bfu(t[tc4 + 2][cc]);
        v.w = f2bfu(t[tc4 + 3][cc]);
        *reinterpret_cast<ushort4*>(xwT + base + (long)(c0 + cc) * NN + r0 + tc4) = v;
    }
}

// ---------------------------------------------------------------------------
// final mix (th in-kernel): out = th*h + (1-th)*r, fp32 out
// ---------------------------------------------------------------------------
__global__ __launch_bounds__(256) void mixfinal_k(
    const unsigned short* __restrict__ h, const unsigned short* __restrict__ r,
    const float* __restrict__ partial_in, int np_in, float inv_in,
    float* __restrict__ out, long n4)
{
    __shared__ float sm[256];
    const float th = block_th(partial_in, np_in, inv_in, sm, (int)threadIdx.x);
    const float om = 1.f - th;
    long gid = (long)blockIdx.x * 256 + threadIdx.x;
    long stride = (long)gridDim.x * 256;
    for (long i = gid; i < n4; i += stride) {
        ushort4 hv = reinterpret_cast<const ushort4*>(h)[i];
        ushort4 rv = reinterpret_cast<const ushort4*>(r)[i];
        float4 o;
        o.x = th * bf2f(hv.x) + om * bf2f(rv.x);
        o.y = th * bf2f(hv.y) + om * bf2f(rv.y);
        o.z = th * bf2f(hv.z) + om * bf2f(rv.z);
        o.w = th * bf2f(hv.w) + om * bf2f(rv.w);
        reinterpret_cast<float4*>(out)[i] = o;
    }
}

// ---------------------------------------------------------------------------
extern "C" void kernel_launch(void* const* d_in, const int* in_sizes, int n_in,
                              void* d_out, int out_size, void* d_ws, size_t ws_size,
                              hipStream_t stream)
{
    const float* x       = (const float*)d_in[0];
    const float* adj     = (const float*)d_in[1];
    const float* Wres    = (const float*)d_in[2];
    const float* bres    = (const float*)d_in[3];
    const float* Wg0     = (const float*)d_in[4];
    const float* bg0     = (const float*)d_in[5];
    const float* Wrg0    = (const float*)d_in[6];
    const float* brg0    = (const float*)d_in[7];
    const float* logits0 = (const float*)d_in[8];
    const float* gumb0   = (const float*)d_in[9];
    const float* Wnl0    = (const float*)d_in[10];
    const float* bnl0    = (const float*)d_in[11];
    const float* Wwo0    = (const float*)d_in[12];
    const float* bwo0    = (const float*)d_in[13];
    const float* Wrw0    = (const float*)d_in[14];
    const float* brw0    = (const float*)d_in[15];
    const float* Wg1     = (const float*)d_in[16];
    const float* bg1     = (const float*)d_in[17];
    const float* Wrg1    = (const float*)d_in[18];
    const float* brg1    = (const float*)d_in[19];
    const float* logits1 = (const float*)d_in[20];
    const float* gumb1   = (const float*)d_in[21];
    const float* Wnl1    = (const float*)d_in[22];
    const float* bnl1    = (const float*)d_in[23];
    const float* Wwo1    = (const float*)d_in[24];
    const float* bwo1    = (const float*)d_in[25];
    const float* Wrw1    = (const float*)d_in[26];
    const float* brw1    = (const float*)d_in[27];

    float* out = (float*)d_out;

    // ---- workspace ----
    char* w = (char*)d_ws;
    auto alloc = [&](long bytes) { char* p = w; w += (bytes + 255) & ~255L; return p; };
    const long SLOT = (long)BNR * HH * 2;                 // 32 MB
    char* pool = alloc(5 * SLOT);                         // 160 MB
    __hip_bfloat16* Rbf  = (__hip_bfloat16*)alloc((long)BNR * DOUT * 2); // 8 MB
    __hip_bfloat16* adjb = (__hip_bfloat16*)alloc((long)NN * NN * 2);
    __hip_bfloat16* WT   = (__hip_bfloat16*)alloc(208896L * 2);
    float* partial0 = (float*)alloc(2048 * 4);
    float* partial1 = (float*)alloc(2048 * 4);
    float* partial2 = (float*)alloc(2048 * 4);
    float* partial3 = (float*)alloc(2048 * 4);
    float* c0      = (float*)alloc(256 * 4);
    float* c1      = (float*)alloc(256 * 4);
    float* bg0p    = (float*)alloc(256 * 4);
    float* brg0p   = (float*)alloc(256 * 4);
    float* crow0   = (float*)alloc(256 * 4);
    float* brgc1   = (float*)alloc(64 * 4);
    float* crow1   = (float*)alloc(64 * 4);
    float* cv0     = (float*)alloc(256 * 4);
    float* bv1g    = (float*)alloc(256 * 4);
    float* cv2     = (float*)alloc(64 * 4);

    auto S = [&](int i) { return pool + (long)i * SLOT; };
    __hip_bfloat16* xwr = (__hip_bfloat16*)S(0);
    __hip_bfloat16* rw0 = (__hip_bfloat16*)S(1);
    __hip_bfloat16* orw = (__hip_bfloat16*)S(1);                      // after rw0 dead
    __hip_bfloat16* rw1 = (__hip_bfloat16*)(S(1) + (long)BNR * DOUT * 2);
    __hip_bfloat16* xwT = (__hip_bfloat16*)S(2);
    __hip_bfloat16* xg1 = (__hip_bfloat16*)S(2);                      // after xwT dead
    __hip_bfloat16* T1  = (__hip_bfloat16*)S(3);
    __hip_bfloat16* xbf = (__hip_bfloat16*)S(4);
    __hip_bfloat16* xT  = (__hip_bfloat16*)(S(4) + (long)BNR * DIN * 2);
    __hip_bfloat16* T0  = (__hip_bfloat16*)(S(4) + 2L * BNR * DIN * 2);

    // transposed weights inside WT (element offsets)
    __hip_bfloat16* WresT  = WT;             // 64x64
    __hip_bfloat16* Wg0T   = WT + 4096;      // 256x64
    __hip_bfloat16* Wrg0T  = WT + 20480;     // 256x64  (NEGATED at prep)
    __hip_bfloat16* Wrw0T  = WT + 36864;     // 256x64
    __hip_bfloat16* Wg1T   = WT + 53248;     // 256x256
    __hip_bfloat16* Wrg1T  = WT + 118784;    // 256x64
    __hip_bfloat16* Wc1T   = WT + 135168;    // 64x256 (c1-scaled Wwo1^T; th2-scaled by sc2)
    __hip_bfloat16* Wrw1T  = WT + 151552;    // 64x64
    __hip_bfloat16* Wg0pT  = WT + 155648;    // 256x64 (Wg0@(I+Wc0))^T; th0-scaled by sc0
    __hip_bfloat16* Wrg0pT = WT + 172032;    // 256x64 (Wrg0@(I+Wc0))^T; om0-scaled by sc0
    __hip_bfloat16* Wrgc1T = WT + 188416;    // 64x64  (Wrg1@Wc1)^T; om2-scaled by sc2
    __hip_bfloat16* Wrw0sT = WT + 192512;    // 256x64 (om1*Wrw0)^T by sc1

    const dim3 blk(256);
    const float invH = 1.0f / ((float)BNR * HH);
    const float invD = 1.0f / ((float)BNR * DOUT);

    // ---- prep ----
    hipLaunchKernelGGL(coeff_k, dim3(1), dim3(256), 0, stream, logits0, gumb0, Wnl0, c0);
    hipLaunchKernelGGL(coeff_k, dim3(1), dim3(256), 0, stream, logits1, gumb1, Wnl1, c1);
    hipLaunchKernelGGL(cvt_k, dim3(2048), blk, 0, stream, x, (unsigned short*)xbf, (long)BNR * DIN / 4);
    hipLaunchKernelGGL(cvt_k, dim3(256), blk, 0, stream, adj, (unsigned short*)adjb, (long)NN * NN / 4);
    hipLaunchKernelGGL(tcvt_k, dim3(1, 8, 128), blk, 0, stream, x, (unsigned short*)xT, NN, DIN, (long)NN * DIN);

    WTArgs wa;
    wa.src[0] = Wres; wa.dst[0] = (unsigned short*)WresT; wa.cs[0] = nullptr; wa.sgn[0] = 1.f;  wa.R[0] = 64;  wa.C[0] = 64;
    wa.src[1] = Wg0;  wa.dst[1] = (unsigned short*)Wg0T;  wa.cs[1] = nullptr; wa.sgn[1] = 1.f;  wa.R[1] = 64;  wa.C[1] = 256;
    wa.src[2] = Wrg0; wa.dst[2] = (unsigned short*)Wrg0T; wa.cs[2] = nullptr; wa.sgn[2] = -1.f; wa.R[2] = 64;  wa.C[2] = 256;
    wa.src[3] = Wrw0; wa.dst[3] = (unsigned short*)Wrw0T; wa.cs[3] = nullptr; wa.sgn[3] = 1.f;  wa.R[3] = 64;  wa.C[3] = 256;
    wa.src[4] = Wg1;  wa.dst[4] = (unsigned short*)Wg1T;  wa.cs[4] = nullptr; wa.sgn[4] = 1.f;  wa.R[4] = 256; wa.C[4] = 256;
    wa.src[5] = Wrg1; wa.dst[5] = (unsigned short*)Wrg1T; wa.cs[5] = nullptr; wa.sgn[5] = 1.f;  wa.R[5] = 64;  wa.C[5] = 256;
    wa.src[6] = Wwo1; wa.dst[6] = (unsigned short*)Wc1T;  wa.cs[6] = c1;      wa.sgn[6] = 1.f;  wa.R[6] = 256; wa.C[6] = 64;
    wa.src[7] = Wrw1; wa.dst[7] = (unsigned short*)Wrw1T; wa.cs[7] = nullptr; wa.sgn[7] = 1.f;  wa.R[7] = 64;  wa.C[7] = 64;
    hipLaunchKernelGGL(tcvt_w_k, dim3(16, 8), blk, 0, stream, wa);

    WFArgs wf;
    wf.Wsrc[0] = Wg0;  wf.Wbig[0] = Wwo0; wf.c[0] = c0; wf.incl[0] = 1; wf.N[0] = 256;
    wf.dst[0] = (unsigned short*)Wg0pT;
    wf.Wsrc[1] = Wrg0; wf.Wbig[1] = Wwo0; wf.c[1] = c0; wf.incl[1] = 1; wf.N[1] = 256;
    wf.dst[1] = (unsigned short*)Wrg0pT;
    wf.Wsrc[2] = Wrg1; wf.Wbig[2] = Wwo1; wf.c[2] = c1; wf.incl[2] = 0; wf.N[2] = 64;
    wf.dst[2] = (unsigned short*)Wrgc1T;
    hipLaunchKernelGGL(wfold_k, dim3(64, 3), blk, 0, stream, wf);

    FVArgs fv;
    fv.W[0] = Wwo0; fv.c[0] = c0;      fv.v[0] = bg0;  fv.base[0] = bg0;  fv.out[0] = bg0p;  fv.K[0] = 256; fv.N[0] = 256;
    fv.W[1] = Wwo0; fv.c[1] = c0;      fv.v[1] = brg0; fv.base[1] = brg0; fv.out[1] = brg0p; fv.K[1] = 256; fv.N[1] = 256;
    fv.W[2] = Wwo0; fv.c[2] = nullptr; fv.v[2] = bnl0; fv.base[2] = bwo0; fv.out[2] = crow0; fv.K[2] = 256; fv.N[2] = 256;
    fv.W[3] = Wwo1; fv.c[3] = c1;      fv.v[3] = brg1; fv.base[3] = nullptr; fv.out[3] = brgc1; fv.K[3] = 256; fv.N[3] = 64;
    fv.W[4] = Wwo1; fv.c[4] = nullptr; fv.v[4] = bnl1; fv.base[4] = bwo1; fv.out[4] = crow1; fv.K[4] = 256; fv.N[4] = 64;
    hipLaunchKernelGGL(foldvec_k, dim3(256, 5), blk, 0, stream, fv);

    // res = x @ Wres + bres
    hipLaunchKernelGGL((gemm_bt_k<128, 64, 4, 2>), dim3(1, BNR / 128, 1), blk, 0, stream,
                       xbf, WresT, bres, Rbf, BNR, DOUT, DIN, 0, 0, 0);

    // T0 = adj @ x (batched)
    hipLaunchKernelGGL((gemm_bt_k<128, 64, 4, 2>), dim3(1, 4, BB), blk, 0, stream,
                       adjb, xT, nullptr, T0, NN, DIN, NN, 0, (long)DIN * NN, (long)NN * DIN);

    // D0: diff0 partials only, single acc (Wrg0T pre-negated)
    hipLaunchKernelGGL((dual1_k<64, 128, 2, 4>), dim3(2, BNR / 64), blk, 0, stream,
                       T0, Wg0T, DIN, Rbf, Wrg0T, DOUT, bg0, brg0, partial0, BNR, HH);

    // sc0: th0-scale Wg0pT, om0-scale Wrg0pT, fold cv0
    hipLaunchKernelGGL(sc0_k, dim3(64), blk, 0, stream, partial0, 2048, invH,
                       (unsigned short*)Wg0pT, (unsigned short*)Wrg0pT,
                       bg0p, brg0p, crow0, cv0);

    // W0: acc0 = T0@(th0*Wg0p) + Rbf@(om0*Wrg0p); acc1 = Rbf@Wrw0
    hipLaunchKernelGGL((wave2_k<64, 128, 2, 4>), dim3(2, BNR / 64), blk, 0, stream,
                       T0, Wg0pT, DIN, Rbf, Wrg0pT, DOUT, Rbf, Wrw0T, DOUT,
                       cv0, brw0, xwr, rw0, partial1, BNR, HH);

    // sc1: Wrw0sT = om1*Wrw0T ; bv1g = bg1 + om1*brw0
    hipLaunchKernelGGL(sc1_k, dim3(64), blk, 0, stream, partial1, 2048, invH,
                       (const unsigned short*)Wrw0T, (unsigned short*)Wrw0sT,
                       bg1, brw0, bv1g);

    // xwT = transpose(mix(xwr, rw0))
    hipLaunchKernelGGL(mixT_k, dim3(4, 8, BB), blk, 0, stream,
                       (const unsigned short*)xwr, (const unsigned short*)rw0,
                       partial1, 2048, invH, (unsigned short*)xwT);

    // T1 = adj @ xw (batched)
    hipLaunchKernelGGL((gemm_bt_k<128, 128, 4, 4>), dim3(2, 4, BB), blk, 0, stream,
                       adjb, xwT, nullptr, T1, NN, HH, NN, 0, (long)HH * NN, (long)NN * HH);

    // gmix: xg1 = T1@Wg1 + Rbf@(om1*Wrw0) + bv1g + th1*xwr ; rg1 = Rbf@Wrg1 + brg1 (diff)
    hipLaunchKernelGGL((gmix2_k<64, 128, 2, 4>), dim3(2, BNR / 64), blk, 0, stream,
                       T1, Wg1T, HH, Rbf, Wrw0sT, DOUT, Rbf, Wrg1T, DOUT,
                       bv1g, brg1, xwr, partial1, 2048, invH, xg1, partial2, BNR, HH);

    // sc2: th2-scale Wc1T, om2-scale Wrgc1T, fold cv2
    hipLaunchKernelGGL(sc2_k, dim3(64), blk, 0, stream, partial2, 2048, invH,
                       (unsigned short*)Wc1T, (unsigned short*)Wrgc1T,
                       brgc1, crow1, cv2);

    // F: acc0 = xg1@(th2*Wc1) + Rbf@(om2*Wrgc1); acc1 = Rbf@Wrw1
    hipLaunchKernelGGL((wave2_k<64, 64, 2, 2>), dim3(1, BNR / 64), blk, 0, stream,
                       xg1, Wc1T, HH, Rbf, Wrgc1T, DOUT, Rbf, Wrw1T, DIN,
                       cv2, brw1, orw, rw1, partial3, BNR, DOUT);

    // final mix -> fp32 out
    hipLaunchKernelGGL(mixfinal_k, dim3(2048), blk, 0, stream,
                       (const unsigned short*)orw, (const unsigned short*)rw1,
                       partial3, 1024, invD, out, (long)BNR * DOUT / 4);
}

// Round 10
// 197.513 us; speedup vs baseline: 1.1442x; 1.0358x over previous
//
#include <hip/hip_runtime.h>
#include <hip/hip_bf16.h>
#include <math.h>

#define BB   128
#define NN   512
#define DIN  64
#define HH   256
#define DOUT 64
#define BNR  (BB * NN)          // 65536 rows

typedef float  f32x4  __attribute__((ext_vector_type(4)));
typedef __bf16 bf16x8 __attribute__((ext_vector_type(8)));

#define GLP(p)  ((const __attribute__((address_space(1))) void*)(p))
#define LDSP(p) ((__attribute__((address_space(3))) void*)(p))

// Haar/db1 'zero' DWT patterns, levels 1..3, FULL_LEN=8
__constant__ float PAT[3][8] = {
    {0.70710678f, 0.70710678f, 0.f, 0.f, 0.f, 0.f, 0.f, 0.f},
    {0.5f,        0.70710678f, 0.f, 0.5f, 0.f, 0.f, 0.f, 0.f},
    {0.35355339f, 0.70710678f, 0.f, 0.f, 0.f, 0.5f, 0.f, 0.35355339f}
};

__device__ __forceinline__ unsigned short f2bfu(float x) {
    __hip_bfloat16 b = __float2bfloat16(x);
    unsigned short u;
    __builtin_memcpy(&u, &b, 2);
    return u;
}
__device__ __forceinline__ float bf2f(unsigned short u) {
    unsigned int v = ((unsigned int)u) << 16;
    float f;
    __builtin_memcpy(&f, &v, 4);
    return f;
}

// ---------------------------------------------------------------------------
// In-kernel th = sigmoid(mean diff) — same tree order everywhere.
// ---------------------------------------------------------------------------
__device__ __forceinline__ float block_th(const float* __restrict__ partial, int np,
                                          float inv_n, float* red, int tid)
{
    float s = 0.f;
    for (int i = tid; i < np; i += 256) s += partial[i];
    red[tid] = s;
    __syncthreads();
    for (int o = 128; o > 0; o >>= 1) {
        if (tid < o) red[tid] += red[tid + o];
        __syncthreads();
    }
    float th = 1.f / (1.f + expf(-red[0] * inv_n));
    __syncthreads();
    return th;
}

// ---------------------------------------------------------------------------
// Coalesced bf16 tile write via LDS staging (proven round 4).
// ---------------------------------------------------------------------------
template<int BM, int BN, int FM, int FN>
__device__ __forceinline__ void write_tile(char* lds, f32x4 (&a)[FM][FN],
                                           __hip_bfloat16* __restrict__ C,
                                           long base, int N, int tid)
{
    const int wave = tid >> 6;
    const int lane = tid & 63;
    const int wm = wave >> 1, wn = wave & 1;
    const int lc = lane & 15;
    const int lr4 = (lane >> 4) << 2;
    __syncthreads();
    #pragma unroll
    for (int j = 0; j < FN; ++j) {
        int colb = (wn * (FN * 16) + j * 16 + lc) * 2;
        #pragma unroll
        for (int i = 0; i < FM; ++i) {
            int row0 = wm * (FM * 16) + i * 16 + lr4;
            #pragma unroll
            for (int r = 0; r < 4; ++r) {
                int row = row0 + r;
                *reinterpret_cast<unsigned short*>(
                    lds + row * (BN * 2) + (colb ^ (((row >> 2) & 3) << 5))) =
                    f2bfu(a[i][j][r]);
            }
        }
    }
    __syncthreads();
    const int TPR = BN / 8;
    const int RPP = 256 / TPR;
    #pragma unroll
    for (int p = 0; p < BM / RPP; ++p) {
        int row = p * RPP + tid / TPR;
        int cb = (tid % TPR) * 16;
        int pb = cb ^ (((row >> 2) & 3) << 5);
        uint4 v = *reinterpret_cast<const uint4*>(lds + row * (BN * 2) + pb);
        *reinterpret_cast<uint4*>(reinterpret_cast<char*>(C + base + (long)row * N) + cb) = v;
    }
}

// ---------------------------------------------------------------------------
// staging of one K=64 slab of A(BM rows) + B(BN rows) into swizzled LDS
// ---------------------------------------------------------------------------
template<int BM, int BN>
__device__ __forceinline__ void stage_tiles(const __hip_bfloat16* __restrict__ Ab,
                                            const __hip_bfloat16* __restrict__ Bb,
                                            char* AsB, char* BsB,
                                            int m0, int n0, int k0, int KA, int KB,
                                            int wave, int lane)
{
    const int NCH = (BM + BN) / 32;
    const int lr = lane >> 3;
    const int ls = lane & 7;
    #pragma unroll
    for (int cc = 0; cc < NCH; ++cc) {
        int c = wave * NCH + cc;
        const __hip_bfloat16* src;
        char* ldsb;
        if (c < BM / 8) {
            int r = c * 8 + lr;
            ldsb = AsB + c * 1024;
            src = Ab + ((long)(m0 + r) * KA + k0 + ((ls ^ (r & 7)) << 3));
        } else {
            int c2 = c - BM / 8;
            int r = c2 * 8 + lr;
            ldsb = BsB + c2 * 1024;
            src = Bb + ((long)(n0 + r) * KB + k0 + ((ls ^ (r & 7)) << 3));
        }
        __builtin_amdgcn_global_load_lds(GLP(src), LDSP(ldsb), 16, 0, 0);
    }
}

template<int BM, int BN, int FM, int FN>
__device__ __forceinline__ void mfma_tiles(char* AsB, char* BsB,
                                           f32x4 (&acc)[FM][FN], int wave, int lane)
{
    const int wm = wave >> 1, wn = wave & 1;
    #pragma unroll
    for (int ksl = 0; ksl < 2; ++ksl) {
        bf16x8 af[FM], bfr[FN];
        #pragma unroll
        for (int i = 0; i < FM; ++i) {
            int row = wm * (FM * 16) + i * 16 + (lane & 15);
            int off = (ksl * 64 + ((lane >> 4) << 4)) ^ ((row & 7) << 4);
            af[i] = *reinterpret_cast<const bf16x8*>(AsB + row * 128 + off);
        }
        #pragma unroll
        for (int j = 0; j < FN; ++j) {
            int row = wn * (FN * 16) + j * 16 + (lane & 15);
            int off = (ksl * 64 + ((lane >> 4) << 4)) ^ ((row & 7) << 4);
            bfr[j] = *reinterpret_cast<const bf16x8*>(BsB + row * 128 + off);
        }
        #pragma unroll
        for (int i = 0; i < FM; ++i)
            #pragma unroll
            for (int j = 0; j < FN; ++j)
                acc[i][j] = __builtin_amdgcn_mfma_f32_16x16x32_bf16(
                    af[i], bfr[j], acc[i][j], 0, 0, 0);
    }
}

// ---------------------------------------------------------------------------
// fp32 -> bf16 convert (adj)
// ---------------------------------------------------------------------------
__global__ __launch_bounds__(256) void cvt_k(const float* __restrict__ in,
                                             unsigned short* __restrict__ out, long n4)
{
    long gid = (long)blockIdx.x * 256 + threadIdx.x;
    long stride = (long)gridDim.x * 256;
    for (long i = gid; i < n4; i += stride) {
        float4 v = reinterpret_cast<const float4*>(in)[i];
        ushort4 u;
        u.x = f2bfu(v.x); u.y = f2bfu(v.y); u.z = f2bfu(v.z); u.w = f2bfu(v.w);
        reinterpret_cast<ushort4*>(out)[i] = u;
    }
}

// ---------------------------------------------------------------------------
// fused x conversion: one read of x -> xbf (row-major bf16) + xT (transposed)
// grid (1, NN/64, BB); tile 64x64 (DIN=64 = full width)
// ---------------------------------------------------------------------------
__global__ __launch_bounds__(256) void cvtx_k(const float* __restrict__ in,
                                              unsigned short* __restrict__ rm,
                                              unsigned short* __restrict__ tr)
{
    __shared__ float t[64][65];
    const long base = (long)blockIdx.z * NN * DIN;
    const int r0 = blockIdx.y * 64;
    const int tr4 = threadIdx.x >> 6;
    const int tc  = threadIdx.x & 63;
    #pragma unroll
    for (int i = 0; i < 16; ++i) {
        int r = i * 4 + tr4;
        float v = in[base + (long)(r0 + r) * DIN + tc];
        t[r][tc] = v;
        rm[base + (long)(r0 + r) * DIN + tc] = f2bfu(v);
    }
    __syncthreads();
    #pragma unroll
    for (int i = 0; i < 16; ++i) {
        int d = i * 4 + tr4;
        tr[base + (long)d * NN + r0 + tc] = f2bfu(t[tc][d]);
    }
}

// ---------------------------------------------------------------------------
// transpose-convert fp32 (R,C) -> bf16 (C,R), optional per-src-row scale + sign
// ---------------------------------------------------------------------------
__device__ __forceinline__ void tcvt_body(const float* __restrict__ in,
                                          unsigned short* __restrict__ out,
                                          const float* __restrict__ cs, float us,
                                          int R, int C, int r0, int c0)
{
    __shared__ float t[64][65];
    int tr = threadIdx.x >> 6;
    int tc = threadIdx.x & 63;
    #pragma unroll
    for (int i = 0; i < 16; ++i) {
        int r = i * 4 + tr;
        t[r][tc] = in[(long)(r0 + r) * C + c0 + tc];
    }
    __syncthreads();
    float sc = (cs ? cs[r0 + tc] : 1.0f) * us;
    #pragma unroll
    for (int i = 0; i < 16; ++i) {
        int r = i * 4 + tr;
        out[(long)(c0 + r) * R + r0 + tc] = f2bfu(t[tc][r] * sc);
    }
}

struct WTArgs {
    const float* src[8];
    unsigned short* dst[8];
    const float* cs[8];
    float sgn[8];
    int R[8], C[8];
};
__global__ __launch_bounds__(256) void tcvt_w_k(WTArgs a)
{
    int wgt = blockIdx.y;
    int R = a.R[wgt], C = a.C[wgt];
    int tilesX = C >> 6;
    int tiles = (R >> 6) * tilesX;
    int t = blockIdx.x;
    if (t >= tiles) return;
    tcvt_body(a.src[wgt], a.dst[wgt], a.cs[wgt], a.sgn[wgt], R, C,
              (t / tilesX) * 64, (t % tilesX) * 64);
}

// ---------------------------------------------------------------------------
// wavelet coeff
// ---------------------------------------------------------------------------
__global__ void coeff_k(const float* __restrict__ logits, const float* __restrict__ gumb,
                        const float* __restrict__ Wnl, float* __restrict__ coeff)
{
    int f = threadIdx.x;
    float l0 = logits[0] + gumb[f * 3 + 0];
    float l1 = logits[1] + gumb[f * 3 + 1];
    float l2 = logits[2] + gumb[f * 3 + 2];
    int bl = 0;
    float bv = l0;
    if (l1 > bv) { bv = l1; bl = 1; }
    if (l2 > bv) { bv = l2; bl = 2; }
    float s = 0.f;
    #pragma unroll
    for (int t = 0; t < 8; ++t) s += Wnl[f * 8 + t] * PAT[bl][t];
    coeff[f] = s;
}

// ---------------------------------------------------------------------------
// batched vector folds: out[n] = (base? base[n]:0) + sum_k v[k]*(c?c[k]:1)*W[k,n]
// ---------------------------------------------------------------------------
struct FVArgs {
    const float* W[5];
    const float* c[5];
    const float* v[5];
    const float* base[5];
    float* out[5];
    int K[5], N[5];
};
__global__ __launch_bounds__(256) void foldvec_k(FVArgs a)
{
    int cs = blockIdx.y;
    int n = blockIdx.x;
    if (n >= a.N[cs]) return;
    int k = threadIdx.x;
    float s = 0.f;
    if (k < a.K[cs]) {
        float cc = a.c[cs] ? a.c[cs][k] : 1.0f;
        s = a.v[cs][k] * cc * a.W[cs][(long)k * a.N[cs] + n];
    }
    __shared__ float sm[256];
    sm[threadIdx.x] = s;
    __syncthreads();
    for (int o = 128; o > 0; o >>= 1) {
        if (threadIdx.x < o) sm[threadIdx.x] += sm[threadIdx.x + o];
        __syncthreads();
    }
    if (threadIdx.x == 0)
        a.out[cs][n] = (a.base[cs] ? a.base[cs][n] : 0.f) + sm[0];
}

// ---------------------------------------------------------------------------
// batched weight folds (transposed bf16 out, M=64 rows, K=256 fixed)
// ---------------------------------------------------------------------------
struct WFArgs {
    const float* Wsrc[3];
    const float* Wbig[3];
    const float* c[3];
    int incl[3], N[3];
    unsigned short* dst[3];
};
__global__ __launch_bounds__(256) void wfold_k(WFArgs a)
{
    int cs = blockIdx.y;
    int m = blockIdx.x;
    __shared__ float ws[256];
    ws[threadIdx.x] = a.Wsrc[cs][m * 256 + threadIdx.x] * a.c[cs][threadIdx.x];
    __syncthreads();
    int n = threadIdx.x;
    int N = a.N[cs];
    if (n >= N) return;
    float s = a.incl[cs] ? a.Wsrc[cs][m * 256 + n] : 0.f;
    const float* Wb = a.Wbig[cs];
    #pragma unroll 8
    for (int k = 0; k < 256; ++k)
        s += ws[k] * Wb[(long)k * N + n];
    a.dst[cs][n * 64 + m] = f2bfu(s);
}

// ---------------------------------------------------------------------------
// sc kernels: compute th, scale folded weights in place, fold bias vectors.
// ---------------------------------------------------------------------------
__global__ __launch_bounds__(256) void sc0_k(
    const float* __restrict__ partial, int np, float inv_n,
    unsigned short* __restrict__ Wa,   // 16384 *= th0
    unsigned short* __restrict__ Wb,   // 16384 *= om0
    const float* __restrict__ bg0p, const float* __restrict__ brg0p,
    const float* __restrict__ crow0, float* __restrict__ cv0)
{
    __shared__ float red[256];
    float th = block_th(partial, np, inv_n, red, threadIdx.x);
    float om = 1.f - th;
    int g = blockIdx.x * 256 + threadIdx.x;
    Wa[g] = f2bfu(th * bf2f(Wa[g]));
    Wb[g] = f2bfu(om * bf2f(Wb[g]));
    if (g < 256) cv0[g] = th * bg0p[g] + om * brg0p[g] + crow0[g];
}

// sc1: after W0 consumed Wg0pT/Wrg0pT, rescale them in place by th1 (so gmix's
// T0/Rbf phases produce th1*xwr), produce om1-scaled Wrw0, and fold
// bv1g = bg1 + om1*brw0 + th1*cv0.
__global__ __launch_bounds__(256) void sc1_k(
    const float* __restrict__ partial, int np, float inv_n,
    const unsigned short* __restrict__ Wrw0T, unsigned short* __restrict__ Wrw0sT,
    unsigned short* __restrict__ Wg0pT, unsigned short* __restrict__ Wrg0pT,
    const float* __restrict__ bg1, const float* __restrict__ brw0,
    const float* __restrict__ cv0, float* __restrict__ bv1g)
{
    __shared__ float red[256];
    float th = block_th(partial, np, inv_n, red, threadIdx.x);
    float om = 1.f - th;
    int g = blockIdx.x * 256 + threadIdx.x;
    Wrw0sT[g] = f2bfu(om * bf2f(Wrw0T[g]));
    Wg0pT[g]  = f2bfu(th * bf2f(Wg0pT[g]));
    Wrg0pT[g] = f2bfu(th * bf2f(Wrg0pT[g]));
    if (g < 256) bv1g[g] = bg1[g] + om * brw0[g] + th * cv0[g];
}

__global__ __launch_bounds__(256) void sc2_k(
    const float* __restrict__ partial, int np, float inv_n,
    unsigned short* __restrict__ Wc1T,    // 16384 *= th2
    unsigned short* __restrict__ Wrgc1T,  // 4096  *= om2
    const float* __restrict__ brgc1, const float* __restrict__ crow1,
    float* __restrict__ cv2)
{
    __shared__ float red[256];
    float th = block_th(partial, np, inv_n, red, threadIdx.x);
    float om = 1.f - th;
    int g = blockIdx.x * 256 + threadIdx.x;
    Wc1T[g] = f2bfu(th * bf2f(Wc1T[g]));
    if (g < 4096) Wrgc1T[g] = f2bfu(om * bf2f(Wrgc1T[g]));
    if (g < 64) cv2[g] = om * brgc1[g] + crow1[g];
}

// ---------------------------------------------------------------------------
// Single MFMA bf16 GEMM (non-batched; used for Rbf)
// ---------------------------------------------------------------------------
template<int BM, int BN, int FM, int FN>
__global__ __launch_bounds__(256) void gemm_bt_k(
    const __hip_bfloat16* __restrict__ A, const __hip_bfloat16* __restrict__ Bt,
    const float* __restrict__ bias, __hip_bfloat16* __restrict__ Cb,
    int M, int N, int K)
{
    __shared__ __attribute__((aligned(128))) char lds[(BM + BN) * 128];
    char* AsB = lds;
    char* BsB = lds + BM * 128;

    const int m0 = blockIdx.y * BM;
    const int n0 = blockIdx.x * BN;
    const int tid  = threadIdx.x;
    const int wave = tid >> 6;
    const int lane = tid & 63;
    const int wn = wave & 1;

    f32x4 acc[FM][FN];
    #pragma unroll
    for (int i = 0; i < FM; ++i)
        #pragma unroll
        for (int j = 0; j < FN; ++j)
            acc[i][j] = (f32x4){0.f, 0.f, 0.f, 0.f};

    for (int k0 = 0; k0 < K; k0 += 64) {
        stage_tiles<BM, BN>(A, Bt, AsB, BsB, m0, n0, k0, K, K, wave, lane);
        __syncthreads();
        mfma_tiles<BM, BN, FM, FN>(AsB, BsB, acc, wave, lane);
        __syncthreads();
    }

    const int lc = lane & 15;
    #pragma unroll
    for (int j = 0; j < FN; ++j) {
        int col = n0 + wn * (FN * 16) + j * 16 + lc;
        float bv = bias ? bias[col] : 0.0f;
        #pragma unroll
        for (int i = 0; i < FM; ++i)
            #pragma unroll
            for (int r = 0; r < 4; ++r)
                acc[i][j][r] += bv;
    }
    write_tile<BM, BN, FM, FN>(lds, acc, Cb, (long)m0 * N + n0, N, tid);
}

// ---------------------------------------------------------------------------
// Batched MFMA GEMM with XCD-grouped block swizzle: all NB blocks of a batch
// get the same (dispatch_id % 8) -> same XCD -> shared B-panel is L2-hit.
// grid = 1D, NBAT*NB blocks; NBAT % 8 == 0. d = (b&7) + 8*(t + NB*(b>>3)).
// ---------------------------------------------------------------------------
template<int BM, int BN, int FM, int FN, int GX, int NB>
__global__ __launch_bounds__(256) void gemm_bt_swz_k(
    const __hip_bfloat16* __restrict__ A, const __hip_bfloat16* __restrict__ Bt,
    __hip_bfloat16* __restrict__ Cb,
    int M, int N, int K, long sA, long sB, long sC)
{
    __shared__ __attribute__((aligned(128))) char lds[(BM + BN) * 128];
    char* AsB = lds;
    char* BsB = lds + BM * 128;

    const int d   = blockIdx.x;
    const int xcd = d & 7;
    const int q   = d >> 3;
    const int t   = q % NB;
    const int bz  = xcd + ((q / NB) << 3);
    const int n0  = (t % GX) * BN;
    const int m0  = (t / GX) * BM;

    const __hip_bfloat16* Ab = A + (long)bz * sA;
    const __hip_bfloat16* Bb = Bt + (long)bz * sB;

    const int tid  = threadIdx.x;
    const int wave = tid >> 6;
    const int lane = tid & 63;
    const int wn = wave & 1;

    f32x4 acc[FM][FN];
    #pragma unroll
    for (int i = 0; i < FM; ++i)
        #pragma unroll
        for (int j = 0; j < FN; ++j)
            acc[i][j] = (f32x4){0.f, 0.f, 0.f, 0.f};

    for (int k0 = 0; k0 < K; k0 += 64) {
        stage_tiles<BM, BN>(Ab, Bb, AsB, BsB, m0, n0, k0, K, K, wave, lane);
        __syncthreads();
        mfma_tiles<BM, BN, FM, FN>(AsB, BsB, acc, wave, lane);
        __syncthreads();
    }

    write_tile<BM, BN, FM, FN>(lds, acc, Cb, (long)bz * sC + (long)m0 * N + n0, N, tid);
}

// ---------------------------------------------------------------------------
// dual1_k (D0): ONE accumulator, pair-swizzled 1D grid (2 n-tiles share A rows
// on the same XCD). acc = A0@B0 + A1@B1 (B1 pre-negated); partials only.
// ---------------------------------------------------------------------------
template<int BM, int BN, int FM, int FN>
__global__ __launch_bounds__(256) void dual1_k(
    const __hip_bfloat16* __restrict__ A0, const __hip_bfloat16* __restrict__ B0, int K0,
    const __hip_bfloat16* __restrict__ A1, const __hip_bfloat16* __restrict__ B1, int K1,
    const float* __restrict__ b1, const float* __restrict__ b2,
    float* __restrict__ partial, int M, int N)
{
    __shared__ __attribute__((aligned(128))) char lds[(BM + BN) * 128];
    char* AsB = lds;
    char* BsB = lds + BM * 128;

    const int d   = blockIdx.x;
    const int q   = d >> 3;
    const int nx  = q & 1;
    const int my  = (d & 7) + ((q >> 1) << 3);
    const int m0  = my * BM;
    const int n0  = nx * BN;

    const int tid  = threadIdx.x;
    const int wave = tid >> 6;
    const int lane = tid & 63;
    const int wn = wave & 1;

    f32x4 acc[FM][FN];
    #pragma unroll
    for (int i = 0; i < FM; ++i)
        #pragma unroll
        for (int j = 0; j < FN; ++j)
            acc[i][j] = (f32x4){0.f, 0.f, 0.f, 0.f};

    #pragma unroll
    for (int ph = 0; ph < 2; ++ph) {
        const __hip_bfloat16* Ab = ph ? A1 : A0;
        const __hip_bfloat16* Bb = ph ? B1 : B0;
        const int K = ph ? K1 : K0;
        for (int k0 = 0; k0 < K; k0 += 64) {
            stage_tiles<BM, BN>(Ab, Bb, AsB, BsB, m0, n0, k0, K, K, wave, lane);
            __syncthreads();
            mfma_tiles<BM, BN, FM, FN>(AsB, BsB, acc, wave, lane);
            __syncthreads();
        }
    }

    const int lc = lane & 15;
    float dsum = 0.f;
    #pragma unroll
    for (int j = 0; j < FN; ++j) {
        int col = n0 + wn * (FN * 16) + j * 16 + lc;
        float bd = b1[col] - b2[col];
        #pragma unroll
        for (int i = 0; i < FM; ++i)
            #pragma unroll
            for (int r = 0; r < 4; ++r) {
                float dd = acc[i][j][r] + bd;
                dsum += dd * dd;
            }
    }

    float* red = (float*)lds;
    red[tid] = dsum;
    __syncthreads();
    for (int o = 128; o > 0; o >>= 1) {
        if (tid < o) red[tid] += red[tid + o];
        __syncthreads();
    }
    if (tid == 0) partial[my * 2 + nx] = red[0];
}

// ---------------------------------------------------------------------------
// wave2_k (W0 pair-swizzled / F plain): TWO accumulators, pre-scaled weights:
//   acc0 = A0@B0 + A1@B1 ; acc1 = A2@B2
//   C1 = acc0 + cv[col] ; C2 = acc1 + b2v[col] ; partial_out += (C1-C2)^2
// ---------------------------------------------------------------------------
template<int BM, int BN, int FM, int FN, bool SWZ>
__global__ __launch_bounds__(256) void wave2_k(
    const __hip_bfloat16* __restrict__ A0, const __hip_bfloat16* __restrict__ B0, int K0,
    const __hip_bfloat16* __restrict__ A1, const __hip_bfloat16* __restrict__ B1, int K1,
    const __hip_bfloat16* __restrict__ A2, const __hip_bfloat16* __restrict__ B2, int K2,
    const float* __restrict__ cv, const float* __restrict__ b2v,
    __hip_bfloat16* __restrict__ C1, __hip_bfloat16* __restrict__ C2,
    float* __restrict__ partial_out, int M, int N)
{
    __shared__ __attribute__((aligned(128))) char lds[(BM + BN) * 128];
    char* AsB = lds;
    char* BsB = lds + BM * 128;

    int m0, n0, pidx;
    if constexpr (SWZ) {
        const int d = blockIdx.x;
        const int q = d >> 3;
        const int nx = q & 1;
        const int my = (d & 7) + ((q >> 1) << 3);
        m0 = my * BM; n0 = nx * BN; pidx = my * 2 + nx;
    } else {
        m0 = blockIdx.y * BM; n0 = blockIdx.x * BN;
        pidx = blockIdx.y * gridDim.x + blockIdx.x;
    }

    const int tid  = threadIdx.x;
    const int wave = tid >> 6;
    const int lane = tid & 63;
    const int wn = wave & 1;

    f32x4 acc0[FM][FN], acc1[FM][FN];
    #pragma unroll
    for (int i = 0; i < FM; ++i)
        #pragma unroll
        for (int j = 0; j < FN; ++j) {
            acc0[i][j] = (f32x4){0.f, 0.f, 0.f, 0.f};
            acc1[i][j] = (f32x4){0.f, 0.f, 0.f, 0.f};
        }

    #pragma unroll
    for (int ph = 0; ph < 3; ++ph) {
        const __hip_bfloat16* Ab = (ph == 0) ? A0 : (ph == 1 ? A1 : A2);
        const __hip_bfloat16* Bb = (ph == 0) ? B0 : (ph == 1 ? B1 : B2);
        const int K = (ph == 0) ? K0 : (ph == 1 ? K1 : K2);
        for (int k0 = 0; k0 < K; k0 += 64) {
            stage_tiles<BM, BN>(Ab, Bb, AsB, BsB, m0, n0, k0, K, K, wave, lane);
            __syncthreads();
            if (ph < 2) mfma_tiles<BM, BN, FM, FN>(AsB, BsB, acc0, wave, lane);
            else        mfma_tiles<BM, BN, FM, FN>(AsB, BsB, acc1, wave, lane);
            __syncthreads();
        }
    }

    const int lc = lane & 15;
    float dsum = 0.f;
    #pragma unroll
    for (int j = 0; j < FN; ++j) {
        int col = n0 + wn * (FN * 16) + j * 16 + lc;
        float c1 = cv[col];
        float c2 = b2v[col];
        #pragma unroll
        for (int i = 0; i < FM; ++i)
            #pragma unroll
            for (int r = 0; r < 4; ++r) {
                float v1 = acc0[i][j][r] + c1;
                float v2 = acc1[i][j][r] + c2;
                acc0[i][j][r] = v1;
                acc1[i][j][r] = v2;
                float dd = v1 - v2;
                dsum += dd * dd;
            }
    }

    float* red = (float*)lds;
    red[tid] = dsum;
    __syncthreads();
    for (int o = 128; o > 0; o >>= 1) {
        if (tid < o) red[tid] += red[tid + o];
        __syncthreads();
    }
    if (tid == 0) partial_out[pidx] = red[0];

    write_tile<BM, BN, FM, FN>(lds, acc0, C1, (long)m0 * N + n0, N, tid);
    write_tile<BM, BN, FM, FN>(lds, acc1, C2, (long)m0 * N + n0, N, tid);
}

// ---------------------------------------------------------------------------
// gmix3_k: pure-MFMA 5-phase (round-10). th1 is baked into weights by sc1:
//   acc0 = T1@Wg1 + Rbf@(om1*Wrw0) + T0@(th1*th0*Wg0p) + Rbf@(th1*om0*Wrg0p)
//   acc1 = Rbf@Wrg1
//   C1 = acc0 + bv1g[col] ; rg1 = acc1 + brg1[col] (diff only)
// Pair-swizzled 1D grid.
// ---------------------------------------------------------------------------
template<int BM, int BN, int FM, int FN>
__global__ __launch_bounds__(256) void gmix3_k(
    const __hip_bfloat16* __restrict__ A0, const __hip_bfloat16* __restrict__ B0, int K0,
    const __hip_bfloat16* __restrict__ A1, const __hip_bfloat16* __restrict__ B1, int K1,
    const __hip_bfloat16* __restrict__ A2, const __hip_bfloat16* __restrict__ B2, int K2,
    const __hip_bfloat16* __restrict__ A3, const __hip_bfloat16* __restrict__ B3, int K3,
    const __hip_bfloat16* __restrict__ A4, const __hip_bfloat16* __restrict__ B4, int K4,
    const float* __restrict__ bv1, const float* __restrict__ b2v,
    __hip_bfloat16* __restrict__ C1, float* __restrict__ partial_out, int M, int N)
{
    __shared__ __attribute__((aligned(128))) char lds[(BM + BN) * 128];
    char* AsB = lds;
    char* BsB = lds + BM * 128;

    const int d  = blockIdx.x;
    const int q  = d >> 3;
    const int nx = q & 1;
    const int my = (d & 7) + ((q >> 1) << 3);
    const int m0 = my * BM;
    const int n0 = nx * BN;

    const int tid  = threadIdx.x;
    const int wave = tid >> 6;
    const int lane = tid & 63;
    const int wn = wave & 1;

    f32x4 acc0[FM][FN], acc1[FM][FN];
    #pragma unroll
    for (int i = 0; i < FM; ++i)
        #pragma unroll
        for (int j = 0; j < FN; ++j) {
            acc0[i][j] = (f32x4){0.f, 0.f, 0.f, 0.f};
            acc1[i][j] = (f32x4){0.f, 0.f, 0.f, 0.f};
        }

    const __hip_bfloat16* As[5] = {A0, A1, A2, A3, A4};
    const __hip_bfloat16* Bs[5] = {B0, B1, B2, B3, B4};
    const int Ks[5] = {K0, K1, K2, K3, K4};

    #pragma unroll
    for (int ph = 0; ph < 5; ++ph) {
        const __hip_bfloat16* Ab = As[ph];
        const __hip_bfloat16* Bb = Bs[ph];
        const int K = Ks[ph];
        for (int k0 = 0; k0 < K; k0 += 64) {
            stage_tiles<BM, BN>(Ab, Bb, AsB, BsB, m0, n0, k0, K, K, wave, lane);
            __syncthreads();
            if (ph < 4) mfma_tiles<BM, BN, FM, FN>(AsB, BsB, acc0, wave, lane);
            else        mfma_tiles<BM, BN, FM, FN>(AsB, BsB, acc1, wave, lane);
            __syncthreads();
        }
    }

    const int lc = lane & 15;
    float dsum = 0.f;
    #pragma unroll
    for (int j = 0; j < FN; ++j) {
        int col = n0 + wn * (FN * 16) + j * 16 + lc;
        float c1 = bv1[col];
        float c2 = b2v[col];
        #pragma unroll
        for (int i = 0; i < FM; ++i)
            #pragma unroll
            for (int r = 0; r < 4; ++r) {
                float v1 = acc0[i][j][r] + c1;
                float v2 = acc1[i][j][r] + c2;
                acc0[i][j][r] = v1;
                float dd = v1 - v2;
                dsum += dd * dd;
            }
    }

    float* red = (float*)lds;
    red[tid] = dsum;
    __syncthreads();
    for (int o = 128; o > 0; o >>= 1) {
        if (tid < o) red[tid] += red[tid + o];
        __syncthreads();
    }
    if (tid == 0) partial_out[my * 2 + nx] = red[0];

    write_tile<BM, BN, FM, FN>(lds, acc0, C1, (long)m0 * N + n0, N, tid);
}

// ---------------------------------------------------------------------------
// mix + batched transpose (th in-kernel), writes xwT (b,H,N), ushort4 I/O
// ---------------------------------------------------------------------------
__global__ __launch_bounds__(256) void mixT_k(
    const unsigned short* __restrict__ h, const unsigned short* __restrict__ r,
    const float* __restrict__ partial_in, int np_in, float inv_in,
    unsigned short* __restrict__ xwT)
{
    __shared__ float t[64][65];
    const float th = block_th(partial_in, np_in, inv_in, &t[0][0], (int)threadIdx.x);
    const float om = 1.f - th;
    const long base = (long)blockIdx.z * NN * HH;
    const int r0 = blockIdx.y * 64;
    const int c0 = blockIdx.x * 64;
    const int tr  = threadIdx.x >> 4;
    const int tc4 = (threadIdx.x & 15) * 4;
    #pragma unroll
    for (int i = 0; i < 4; ++i) {
        int rr = i * 16 + tr;
        long idx = base + (long)(r0 + rr) * HH + c0 + tc4;
        ushort4 hv = *reinterpret_cast<const ushort4*>(h + idx);
        ushort4 rv = *reinterpret_cast<const ushort4*>(r + idx);
        t[rr][tc4 + 0] = th * bf2f(hv.x) + om * bf2f(rv.x);
        t[rr][tc4 + 1] = th * bf2f(hv.y) + om * bf2f(rv.y);
        t[rr][tc4 + 2] = th * bf2f(hv.z) + om * bf2f(rv.z);
        t[rr][tc4 + 3] = th * bf2f(hv.w) + om * bf2f(rv.w);
    }
    __syncthreads();
    #pragma unroll
    for (int i = 0; i < 4; ++i) {
        int cc = i * 16 + tr;
        ushort4 v;
        v.x = f2bfu(t[tc4 + 0][cc]);
        v.y = f2bfu(t[tc4 + 1][cc]);
        v.z = f2bfu(t[tc4 + 2][cc]);
        v.w = f2bfu(t[tc4 + 3][cc]);
        *reinterpret_cast<ushort4*>(xwT + base + (long)(c0 + cc) * NN + r0 + tc4) = v;
    }
}

// ---------------------------------------------------------------------------
// final mix (th in-kernel): out = th*h + (1-th)*r, fp32 out
// ---------------------------------------------------------------------------
__global__ __launch_bounds__(256) void mixfinal_k(
    const unsigned short* __restrict__ h, const unsigned short* __restrict__ r,
    const float* __restrict__ partial_in, int np_in, float inv_in,
    float* __restrict__ out, long n4)
{
    __shared__ float sm[256];
    const float th = block_th(partial_in, np_in, inv_in, sm, (int)threadIdx.x);
    const float om = 1.f - th;
    long gid = (long)blockIdx.x * 256 + threadIdx.x;
    long stride = (long)gridDim.x * 256;
    for (long i = gid; i < n4; i += stride) {
        ushort4 hv = reinterpret_cast<const ushort4*>(h)[i];
        ushort4 rv = reinterpret_cast<const ushort4*>(r)[i];
        float4 o;
        o.x = th * bf2f(hv.x) + om * bf2f(rv.x);
        o.y = th * bf2f(hv.y) + om * bf2f(rv.y);
        o.z = th * bf2f(hv.z) + om * bf2f(rv.z);
        o.w = th * bf2f(hv.w) + om * bf2f(rv.w);
        reinterpret_cast<float4*>(out)[i] = o;
    }
}

// ---------------------------------------------------------------------------
extern "C" void kernel_launch(void* const* d_in, const int* in_sizes, int n_in,
                              void* d_out, int out_size, void* d_ws, size_t ws_size,
                              hipStream_t stream)
{
    const float* x       = (const float*)d_in[0];
    const float* adj     = (const float*)d_in[1];
    const float* Wres    = (const float*)d_in[2];
    const float* bres    = (const float*)d_in[3];
    const float* Wg0     = (const float*)d_in[4];
    const float* bg0     = (const float*)d_in[5];
    const float* Wrg0    = (const float*)d_in[6];
    const float* brg0    = (const float*)d_in[7];
    const float* logits0 = (const float*)d_in[8];
    const float* gumb0   = (const float*)d_in[9];
    const float* Wnl0    = (const float*)d_in[10];
    const float* bnl0    = (const float*)d_in[11];
    const float* Wwo0    = (const float*)d_in[12];
    const float* bwo0    = (const float*)d_in[13];
    const float* Wrw0    = (const float*)d_in[14];
    const float* brw0    = (const float*)d_in[15];
    const float* Wg1     = (const float*)d_in[16];
    const float* bg1     = (const float*)d_in[17];
    const float* Wrg1    = (const float*)d_in[18];
    const float* brg1    = (const float*)d_in[19];
    const float* logits1 = (const float*)d_in[20];
    const float* gumb1   = (const float*)d_in[21];
    const float* Wnl1    = (const float*)d_in[22];
    const float* bnl1    = (const float*)d_in[23];
    const float* Wwo1    = (const float*)d_in[24];
    const float* bwo1    = (const float*)d_in[25];
    const float* Wrw1    = (const float*)d_in[26];
    const float* brw1    = (const float*)d_in[27];

    float* out = (float*)d_out;

    // ---- workspace ----
    char* w = (char*)d_ws;
    auto alloc = [&](long bytes) { char* p = w; w += (bytes + 255) & ~255L; return p; };
    const long SLOT = (long)BNR * HH * 2;                 // 32 MB
    char* pool = alloc(5 * SLOT);                         // 160 MB
    __hip_bfloat16* Rbf  = (__hip_bfloat16*)alloc((long)BNR * DOUT * 2); // 8 MB
    __hip_bfloat16* adjb = (__hip_bfloat16*)alloc((long)NN * NN * 2);
    __hip_bfloat16* WT   = (__hip_bfloat16*)alloc(208896L * 2);
    float* partial0 = (float*)alloc(2048 * 4);
    float* partial1 = (float*)alloc(2048 * 4);
    float* partial2 = (float*)alloc(2048 * 4);
    float* partial3 = (float*)alloc(2048 * 4);
    float* c0      = (float*)alloc(256 * 4);
    float* c1      = (float*)alloc(256 * 4);
    float* bg0p    = (float*)alloc(256 * 4);
    float* brg0p   = (float*)alloc(256 * 4);
    float* crow0   = (float*)alloc(256 * 4);
    float* brgc1   = (float*)alloc(64 * 4);
    float* crow1   = (float*)alloc(64 * 4);
    float* cv0     = (float*)alloc(256 * 4);
    float* bv1g    = (float*)alloc(256 * 4);
    float* cv2     = (float*)alloc(64 * 4);

    auto S = [&](int i) { return pool + (long)i * SLOT; };
    __hip_bfloat16* xwr = (__hip_bfloat16*)S(0);
    __hip_bfloat16* rw0 = (__hip_bfloat16*)S(1);
    __hip_bfloat16* orw = (__hip_bfloat16*)S(1);                      // after rw0 dead
    __hip_bfloat16* rw1 = (__hip_bfloat16*)(S(1) + (long)BNR * DOUT * 2);
    __hip_bfloat16* xwT = (__hip_bfloat16*)S(2);
    __hip_bfloat16* xg1 = (__hip_bfloat16*)S(2);                      // after xwT dead
    __hip_bfloat16* T1  = (__hip_bfloat16*)S(3);
    __hip_bfloat16* xbf = (__hip_bfloat16*)S(4);
    __hip_bfloat16* xT  = (__hip_bfloat16*)(S(4) + (long)BNR * DIN * 2);
    __hip_bfloat16* T0  = (__hip_bfloat16*)(S(4) + 2L * BNR * DIN * 2);

    // transposed weights inside WT (element offsets)
    __hip_bfloat16* WresT  = WT;             // 64x64
    __hip_bfloat16* Wg0T   = WT + 4096;      // 256x64
    __hip_bfloat16* Wrg0T  = WT + 20480;     // 256x64  (NEGATED at prep)
    __hip_bfloat16* Wrw0T  = WT + 36864;     // 256x64
    __hip_bfloat16* Wg1T   = WT + 53248;     // 256x256
    __hip_bfloat16* Wrg1T  = WT + 118784;    // 256x64
    __hip_bfloat16* Wc1T   = WT + 135168;    // 64x256 (c1-scaled Wwo1^T; th2 by sc2)
    __hip_bfloat16* Wrw1T  = WT + 151552;    // 64x64
    __hip_bfloat16* Wg0pT  = WT + 155648;    // 256x64 (Wg0@(I+Wc0))^T; th0 by sc0; th1 by sc1
    __hip_bfloat16* Wrg0pT = WT + 172032;    // 256x64 (Wrg0@(I+Wc0))^T; om0 by sc0; th1 by sc1
    __hip_bfloat16* Wrgc1T = WT + 188416;    // 64x64  (Wrg1@Wc1)^T; om2 by sc2
    __hip_bfloat16* Wrw0sT = WT + 192512;    // 256x64 (om1*Wrw0)^T by sc1

    const dim3 blk(256);
    const float invH = 1.0f / ((float)BNR * HH);
    const float invD = 1.0f / ((float)BNR * DOUT);

    // ---- prep ----
    hipLaunchKernelGGL(coeff_k, dim3(1), dim3(256), 0, stream, logits0, gumb0, Wnl0, c0);
    hipLaunchKernelGGL(coeff_k, dim3(1), dim3(256), 0, stream, logits1, gumb1, Wnl1, c1);
    hipLaunchKernelGGL(cvt_k, dim3(256), blk, 0, stream, adj, (unsigned short*)adjb, (long)NN * NN / 4);
    hipLaunchKernelGGL(cvtx_k, dim3(1, 8, BB), blk, 0, stream, x,
                       (unsigned short*)xbf, (unsigned short*)xT);

    WTArgs wa;
    wa.src[0] = Wres; wa.dst[0] = (unsigned short*)WresT; wa.cs[0] = nullptr; wa.sgn[0] = 1.f;  wa.R[0] = 64;  wa.C[0] = 64;
    wa.src[1] = Wg0;  wa.dst[1] = (unsigned short*)Wg0T;  wa.cs[1] = nullptr; wa.sgn[1] = 1.f;  wa.R[1] = 64;  wa.C[1] = 256;
    wa.src[2] = Wrg0; wa.dst[2] = (unsigned short*)Wrg0T; wa.cs[2] = nullptr; wa.sgn[2] = -1.f; wa.R[2] = 64;  wa.C[2] = 256;
    wa.src[3] = Wrw0; wa.dst[3] = (unsigned short*)Wrw0T; wa.cs[3] = nullptr; wa.sgn[3] = 1.f;  wa.R[3] = 64;  wa.C[3] = 256;
    wa.src[4] = Wg1;  wa.dst[4] = (unsigned short*)Wg1T;  wa.cs[4] = nullptr; wa.sgn[4] = 1.f;  wa.R[4] = 256; wa.C[4] = 256;
    wa.src[5] = Wrg1; wa.dst[5] = (unsigned short*)Wrg1T; wa.cs[5] = nullptr; wa.sgn[5] = 1.f;  wa.R[5] = 64;  wa.C[5] = 256;
    wa.src[6] = Wwo1; wa.dst[6] = (unsigned short*)Wc1T;  wa.cs[6] = c1;      wa.sgn[6] = 1.f;  wa.R[6] = 256; wa.C[6] = 64;
    wa.src[7] = Wrw1; wa.dst[7] = (unsigned short*)Wrw1T; wa.cs[7] = nullptr; wa.sgn[7] = 1.f;  wa.R[7] = 64;  wa.C[7] = 64;
    hipLaunchKernelGGL(tcvt_w_k, dim3(16, 8), blk, 0, stream, wa);

    WFArgs wf;
    wf.Wsrc[0] = Wg0;  wf.Wbig[0] = Wwo0; wf.c[0] = c0; wf.incl[0] = 1; wf.N[0] = 256;
    wf.dst[0] = (unsigned short*)Wg0pT;
    wf.Wsrc[1] = Wrg0; wf.Wbig[1] = Wwo0; wf.c[1] = c0; wf.incl[1] = 1; wf.N[1] = 256;
    wf.dst[1] = (unsigned short*)Wrg0pT;
    wf.Wsrc[2] = Wrg1; wf.Wbig[2] = Wwo1; wf.c[2] = c1; wf.incl[2] = 0; wf.N[2] = 64;
    wf.dst[2] = (unsigned short*)Wrgc1T;
    hipLaunchKernelGGL(wfold_k, dim3(64, 3), blk, 0, stream, wf);

    FVArgs fv;
    fv.W[0] = Wwo0; fv.c[0] = c0;      fv.v[0] = bg0;  fv.base[0] = bg0;  fv.out[0] = bg0p;  fv.K[0] = 256; fv.N[0] = 256;
    fv.W[1] = Wwo0; fv.c[1] = c0;      fv.v[1] = brg0; fv.base[1] = brg0; fv.out[1] = brg0p; fv.K[1] = 256; fv.N[1] = 256;
    fv.W[2] = Wwo0; fv.c[2] = nullptr; fv.v[2] = bnl0; fv.base[2] = bwo0; fv.out[2] = crow0; fv.K[2] = 256; fv.N[2] = 256;
    fv.W[3] = Wwo1; fv.c[3] = c1;      fv.v[3] = brg1; fv.base[3] = nullptr; fv.out[3] = brgc1; fv.K[3] = 256; fv.N[3] = 64;
    fv.W[4] = Wwo1; fv.c[4] = nullptr; fv.v[4] = bnl1; fv.base[4] = bwo1; fv.out[4] = crow1; fv.K[4] = 256; fv.N[4] = 64;
    hipLaunchKernelGGL(foldvec_k, dim3(256, 5), blk, 0, stream, fv);

    // res = x @ Wres + bres
    hipLaunchKernelGGL((gemm_bt_k<128, 64, 4, 2>), dim3(1, BNR / 128, 1), blk, 0, stream,
                       xbf, WresT, bres, Rbf, BNR, DOUT, DIN);

    // T0 = adj @ x (batched, XCD-grouped: 4 blocks/batch share the xT panel)
    hipLaunchKernelGGL((gemm_bt_swz_k<128, 64, 4, 2, 1, 4>), dim3(BB * 4), blk, 0, stream,
                       adjb, xT, T0, NN, DIN, NN, 0, (long)DIN * NN, (long)NN * DIN);

    // D0: diff0 partials only, single acc (Wrg0T pre-negated), pair-swizzled
    hipLaunchKernelGGL((dual1_k<64, 128, 2, 4>), dim3(2 * BNR / 64), blk, 0, stream,
                       T0, Wg0T, DIN, Rbf, Wrg0T, DOUT, bg0, brg0, partial0, BNR, HH);

    // sc0: th0-scale Wg0pT, om0-scale Wrg0pT, fold cv0
    hipLaunchKernelGGL(sc0_k, dim3(64), blk, 0, stream, partial0, 2048, invH,
                       (unsigned short*)Wg0pT, (unsigned short*)Wrg0pT,
                       bg0p, brg0p, crow0, cv0);

    // W0: acc0 = T0@(th0*Wg0p) + Rbf@(om0*Wrg0p); acc1 = Rbf@Wrw0 (pair-swizzled)
    hipLaunchKernelGGL((wave2_k<64, 128, 2, 4, true>), dim3(2 * BNR / 64), blk, 0, stream,
                       T0, Wg0pT, DIN, Rbf, Wrg0pT, DOUT, Rbf, Wrw0T, DOUT,
                       cv0, brw0, xwr, rw0, partial1, BNR, HH);

    // sc1: Wrw0sT = om1*Wrw0T ; Wg0pT/Wrg0pT *= th1 ; bv1g = bg1+om1*brw0+th1*cv0
    hipLaunchKernelGGL(sc1_k, dim3(64), blk, 0, stream, partial1, 2048, invH,
                       (const unsigned short*)Wrw0T, (unsigned short*)Wrw0sT,
                       (unsigned short*)Wg0pT, (unsigned short*)Wrg0pT,
                       bg1, brw0, cv0, bv1g);

    // xwT = transpose(mix(xwr, rw0))
    hipLaunchKernelGGL(mixT_k, dim3(4, 8, BB), blk, 0, stream,
                       (const unsigned short*)xwr, (const unsigned short*)rw0,
                       partial1, 2048, invH, (unsigned short*)xwT);

    // T1 = adj @ xw (batched, XCD-grouped: 8 blocks/batch share the xwT panel)
    hipLaunchKernelGGL((gemm_bt_swz_k<128, 128, 4, 4, 2, 8>), dim3(BB * 8), blk, 0, stream,
                       adjb, xwT, T1, NN, HH, NN, 0, (long)HH * NN, (long)NN * HH);

    // gmix3: acc0 = T1@Wg1 + Rbf@(om1*Wrw0) + T0@(th1*..Wg0p) + Rbf@(th1*..Wrg0p)
    //        acc1 = Rbf@Wrg1 ; xg1 = acc0+bv1g ; diff vs acc1+brg1
    hipLaunchKernelGGL((gmix3_k<64, 128, 2, 4>), dim3(2 * BNR / 64), blk, 0, stream,
                       T1, Wg1T, HH,
                       Rbf, Wrw0sT, DOUT,
                       T0, Wg0pT, DIN,
                       Rbf, Wrg0pT, DOUT,
                       Rbf, Wrg1T, DOUT,
                       bv1g, brg1, xg1, partial2, BNR, HH);

    // sc2: th2-scale Wc1T, om2-scale Wrgc1T, fold cv2
    hipLaunchKernelGGL(sc2_k, dim3(64), blk, 0, stream, partial2, 2048, invH,
                       (unsigned short*)Wc1T, (unsigned short*)Wrgc1T,
                       brgc1, crow1, cv2);

    // F: acc0 = xg1@(th2*Wc1) + Rbf@(om2*Wrgc1); acc1 = Rbf@Wrw1
    hipLaunchKernelGGL((wave2_k<64, 64, 2, 2, false>), dim3(1, BNR / 64), blk, 0, stream,
                       xg1, Wc1T, HH, Rbf, Wrgc1T, DOUT, Rbf, Wrw1T, DIN,
                       cv2, brw1, orw, rw1, partial3, BNR, DOUT);

    // final mix -> fp32 out
    hipLaunchKernelGGL(mixfinal_k, dim3(2048), blk, 0, stream,
                       (const unsigned short*)orw, (const unsigned short*)rw1,
                       partial3, 1024, invD, out, (long)BNR * DOUT / 4);
}

// Round 11
// 194.172 us; speedup vs baseline: 1.1639x; 1.0172x over previous
//
#include <hip/hip_runtime.h>
#include <hip/hip_bf16.h>
#include <math.h>

#define BB   128
#define NN   512
#define DIN  64
#define HH   256
#define DOUT 64
#define BNR  (BB * NN)          // 65536 rows

typedef float  f32x4  __attribute__((ext_vector_type(4)));
typedef __bf16 bf16x8 __attribute__((ext_vector_type(8)));

#define GLP(p)  ((const __attribute__((address_space(1))) void*)(p))
#define LDSP(p) ((__attribute__((address_space(3))) void*)(p))

// Haar/db1 'zero' DWT patterns, levels 1..3, FULL_LEN=8
__constant__ float PAT[3][8] = {
    {0.70710678f, 0.70710678f, 0.f, 0.f, 0.f, 0.f, 0.f, 0.f},
    {0.5f,        0.70710678f, 0.f, 0.5f, 0.f, 0.f, 0.f, 0.f},
    {0.35355339f, 0.70710678f, 0.f, 0.f, 0.f, 0.5f, 0.f, 0.35355339f}
};

__device__ __forceinline__ unsigned short f2bfu(float x) {
    __hip_bfloat16 b = __float2bfloat16(x);
    unsigned short u;
    __builtin_memcpy(&u, &b, 2);
    return u;
}
__device__ __forceinline__ float bf2f(unsigned short u) {
    unsigned int v = ((unsigned int)u) << 16;
    float f;
    __builtin_memcpy(&f, &v, 4);
    return f;
}

// ---------------------------------------------------------------------------
// In-kernel th = sigmoid(mean diff) — same tree order everywhere.
// ---------------------------------------------------------------------------
__device__ __forceinline__ float block_th(const float* __restrict__ partial, int np,
                                          float inv_n, float* red, int tid)
{
    float s = 0.f;
    for (int i = tid; i < np; i += 256) s += partial[i];
    red[tid] = s;
    __syncthreads();
    for (int o = 128; o > 0; o >>= 1) {
        if (tid < o) red[tid] += red[tid + o];
        __syncthreads();
    }
    float th = 1.f / (1.f + expf(-red[0] * inv_n));
    __syncthreads();
    return th;
}

// ---------------------------------------------------------------------------
// Coalesced bf16 tile write via LDS staging (proven round 4). Row-major.
// ---------------------------------------------------------------------------
template<int BM, int BN, int FM, int FN>
__device__ __forceinline__ void write_tile(char* lds, f32x4 (&a)[FM][FN],
                                           __hip_bfloat16* __restrict__ C,
                                           long base, int N, int tid)
{
    const int wave = tid >> 6;
    const int lane = tid & 63;
    const int wm = wave >> 1, wn = wave & 1;
    const int lc = lane & 15;
    const int lr4 = (lane >> 4) << 2;
    __syncthreads();
    #pragma unroll
    for (int j = 0; j < FN; ++j) {
        int colb = (wn * (FN * 16) + j * 16 + lc) * 2;
        #pragma unroll
        for (int i = 0; i < FM; ++i) {
            int row0 = wm * (FM * 16) + i * 16 + lr4;
            #pragma unroll
            for (int r = 0; r < 4; ++r) {
                int row = row0 + r;
                *reinterpret_cast<unsigned short*>(
                    lds + row * (BN * 2) + (colb ^ (((row >> 2) & 3) << 5))) =
                    f2bfu(a[i][j][r]);
            }
        }
    }
    __syncthreads();
    const int TPR = BN / 8;
    const int RPP = 256 / TPR;
    #pragma unroll
    for (int p = 0; p < BM / RPP; ++p) {
        int row = p * RPP + tid / TPR;
        int cb = (tid % TPR) * 16;
        int pb = cb ^ (((row >> 2) & 3) << 5);
        uint4 v = *reinterpret_cast<const uint4*>(lds + row * (BN * 2) + pb);
        *reinterpret_cast<uint4*>(reinterpret_cast<char*>(C + base + (long)row * N) + cb) = v;
    }
}

// ---------------------------------------------------------------------------
// Transposed tile write: fragment (m, c) stored at CT[baseT + c*ldT + m].
// LDS tile [BN rows = c][BM cols = m] bf16, same-style XOR swizzle on the m
// byte offset (4-way max on fragment store, epilogue-only).
// ---------------------------------------------------------------------------
template<int BM, int BN, int FM, int FN>
__device__ __forceinline__ void write_tileT(char* lds, f32x4 (&a)[FM][FN],
                                            __hip_bfloat16* __restrict__ CT,
                                            long baseT, int ldT, int tid)
{
    const int wave = tid >> 6;
    const int lane = tid & 63;
    const int wm = wave >> 1, wn = wave & 1;
    const int lc = lane & 15;
    const int lr4 = (lane >> 4) << 2;
    __syncthreads();
    #pragma unroll
    for (int j = 0; j < FN; ++j) {
        int c = wn * (FN * 16) + j * 16 + lc;
        int cbase = c * (BM * 2);
        int swz = ((c >> 2) & 3) << 5;
        #pragma unroll
        for (int i = 0; i < FM; ++i) {
            int m0 = wm * (FM * 16) + i * 16 + lr4;
            #pragma unroll
            for (int r = 0; r < 4; ++r) {
                int m = m0 + r;
                *reinterpret_cast<unsigned short*>(lds + cbase + ((m * 2) ^ swz)) =
                    f2bfu(a[i][j][r]);
            }
        }
    }
    __syncthreads();
    const int TPR = BM / 8;           // threads per c-row (16B each)
    const int RPP = 256 / TPR;
    #pragma unroll
    for (int p = 0; p < BN / RPP; ++p) {
        int c = p * RPP + tid / TPR;
        int tb = (tid % TPR) * 16;
        int pb = tb ^ (((c >> 2) & 3) << 5);
        uint4 v = *reinterpret_cast<const uint4*>(lds + c * (BM * 2) + pb);
        *reinterpret_cast<uint4*>(reinterpret_cast<char*>(CT + baseT + (long)c * ldT) + tb) = v;
    }
}

// ---------------------------------------------------------------------------
// staging of one K=64 slab of A(BM rows) + B(BN rows) into swizzled LDS
// ---------------------------------------------------------------------------
template<int BM, int BN>
__device__ __forceinline__ void stage_tiles(const __hip_bfloat16* __restrict__ Ab,
                                            const __hip_bfloat16* __restrict__ Bb,
                                            char* AsB, char* BsB,
                                            int m0, int n0, int k0, int KA, int KB,
                                            int wave, int lane)
{
    const int NCH = (BM + BN) / 32;
    const int lr = lane >> 3;
    const int ls = lane & 7;
    #pragma unroll
    for (int cc = 0; cc < NCH; ++cc) {
        int c = wave * NCH + cc;
        const __hip_bfloat16* src;
        char* ldsb;
        if (c < BM / 8) {
            int r = c * 8 + lr;
            ldsb = AsB + c * 1024;
            src = Ab + ((long)(m0 + r) * KA + k0 + ((ls ^ (r & 7)) << 3));
        } else {
            int c2 = c - BM / 8;
            int r = c2 * 8 + lr;
            ldsb = BsB + c2 * 1024;
            src = Bb + ((long)(n0 + r) * KB + k0 + ((ls ^ (r & 7)) << 3));
        }
        __builtin_amdgcn_global_load_lds(GLP(src), LDSP(ldsb), 16, 0, 0);
    }
}

template<int BM, int BN, int FM, int FN>
__device__ __forceinline__ void mfma_tiles(char* AsB, char* BsB,
                                           f32x4 (&acc)[FM][FN], int wave, int lane)
{
    const int wm = wave >> 1, wn = wave & 1;
    #pragma unroll
    for (int ksl = 0; ksl < 2; ++ksl) {
        bf16x8 af[FM], bfr[FN];
        #pragma unroll
        for (int i = 0; i < FM; ++i) {
            int row = wm * (FM * 16) + i * 16 + (lane & 15);
            int off = (ksl * 64 + ((lane >> 4) << 4)) ^ ((row & 7) << 4);
            af[i] = *reinterpret_cast<const bf16x8*>(AsB + row * 128 + off);
        }
        #pragma unroll
        for (int j = 0; j < FN; ++j) {
            int row = wn * (FN * 16) + j * 16 + (lane & 15);
            int off = (ksl * 64 + ((lane >> 4) << 4)) ^ ((row & 7) << 4);
            bfr[j] = *reinterpret_cast<const bf16x8*>(BsB + row * 128 + off);
        }
        #pragma unroll
        for (int i = 0; i < FM; ++i)
            #pragma unroll
            for (int j = 0; j < FN; ++j)
                acc[i][j] = __builtin_amdgcn_mfma_f32_16x16x32_bf16(
                    af[i], bfr[j], acc[i][j], 0, 0, 0);
    }
}

// ---------------------------------------------------------------------------
// adj: fp32 -> bf16 + row sums (one block per row)
// ---------------------------------------------------------------------------
__global__ __launch_bounds__(256) void cvta_k(const float* __restrict__ adj,
                                              unsigned int* __restrict__ adjb,
                                              float* __restrict__ ars)
{
    int n = blockIdx.x;
    int t = threadIdx.x;
    float2 v = reinterpret_cast<const float2*>(adj)[n * 256 + t];
    adjb[n * 256 + t] = (unsigned int)f2bfu(v.x) | ((unsigned int)f2bfu(v.y) << 16);
    __shared__ float sm[256];
    sm[t] = v.x + v.y;
    __syncthreads();
    for (int o = 128; o > 0; o >>= 1) {
        if (t < o) sm[t] += sm[t + o];
        __syncthreads();
    }
    if (t == 0) ars[n] = sm[0];
}

// ---------------------------------------------------------------------------
// fused x conversion: one read of x -> xbf (row-major bf16) + xT (transposed)
// ---------------------------------------------------------------------------
__global__ __launch_bounds__(256) void cvtx_k(const float* __restrict__ in,
                                              unsigned short* __restrict__ rm,
                                              unsigned short* __restrict__ tr)
{
    __shared__ float t[64][65];
    const long base = (long)blockIdx.z * NN * DIN;
    const int r0 = blockIdx.y * 64;
    const int tr4 = threadIdx.x >> 6;
    const int tc  = threadIdx.x & 63;
    #pragma unroll
    for (int i = 0; i < 16; ++i) {
        int r = i * 4 + tr4;
        float v = in[base + (long)(r0 + r) * DIN + tc];
        t[r][tc] = v;
        rm[base + (long)(r0 + r) * DIN + tc] = f2bfu(v);
    }
    __syncthreads();
    #pragma unroll
    for (int i = 0; i < 16; ++i) {
        int d = i * 4 + tr4;
        tr[base + (long)d * NN + r0 + tc] = f2bfu(t[tc][d]);
    }
}

// ---------------------------------------------------------------------------
// transpose-convert fp32 (R,C) -> bf16 (C,R), optional per-src-row scale + sign
// ---------------------------------------------------------------------------
__device__ __forceinline__ void tcvt_body(const float* __restrict__ in,
                                          unsigned short* __restrict__ out,
                                          const float* __restrict__ cs, float us,
                                          int R, int C, int r0, int c0)
{
    __shared__ float t[64][65];
    int tr = threadIdx.x >> 6;
    int tc = threadIdx.x & 63;
    #pragma unroll
    for (int i = 0; i < 16; ++i) {
        int r = i * 4 + tr;
        t[r][tc] = in[(long)(r0 + r) * C + c0 + tc];
    }
    __syncthreads();
    float sc = (cs ? cs[r0 + tc] : 1.0f) * us;
    #pragma unroll
    for (int i = 0; i < 16; ++i) {
        int r = i * 4 + tr;
        out[(long)(c0 + r) * R + r0 + tc] = f2bfu(t[tc][r] * sc);
    }
}

struct WTArgs {
    const float* src[8];
    unsigned short* dst[8];
    const float* cs[8];
    float sgn[8];
    int R[8], C[8];
};
__global__ __launch_bounds__(256) void tcvt_w_k(WTArgs a)
{
    int wgt = blockIdx.y;
    int R = a.R[wgt], C = a.C[wgt];
    int tilesX = C >> 6;
    int tiles = (R >> 6) * tilesX;
    int t = blockIdx.x;
    if (t >= tiles) return;
    tcvt_body(a.src[wgt], a.dst[wgt], a.cs[wgt], a.sgn[wgt], R, C,
              (t / tilesX) * 64, (t % tilesX) * 64);
}

// ---------------------------------------------------------------------------
// wavelet coeffs (both layers, one launch)
// ---------------------------------------------------------------------------
__global__ void coeff2_k(const float* __restrict__ logits0, const float* __restrict__ gumb0,
                         const float* __restrict__ Wnl0, float* __restrict__ c0,
                         const float* __restrict__ logits1, const float* __restrict__ gumb1,
                         const float* __restrict__ Wnl1, float* __restrict__ c1)
{
    const float* lg = blockIdx.x ? logits1 : logits0;
    const float* gb = blockIdx.x ? gumb1 : gumb0;
    const float* Wn = blockIdx.x ? Wnl1 : Wnl0;
    float* cc = blockIdx.x ? c1 : c0;
    int f = threadIdx.x;
    float l0 = lg[0] + gb[f * 3 + 0];
    float l1 = lg[1] + gb[f * 3 + 1];
    float l2 = lg[2] + gb[f * 3 + 2];
    int bl = 0;
    float bv = l0;
    if (l1 > bv) { bv = l1; bl = 1; }
    if (l2 > bv) { bv = l2; bl = 2; }
    float s = 0.f;
    #pragma unroll
    for (int t = 0; t < 8; ++t) s += Wn[f * 8 + t] * PAT[bl][t];
    cc[f] = s;
}

// ---------------------------------------------------------------------------
// batched vector folds: out[n] = (base? base[n]:0) + sum_k v[k]*(c?c[k]:1)*W[k,n]
// ---------------------------------------------------------------------------
struct FVArgs {
    const float* W[6];
    const float* c[6];
    const float* v[6];
    const float* base[6];
    float* out[6];
    int K[6], N[6];
};
__global__ __launch_bounds__(256) void foldvec_k(FVArgs a)
{
    int cs = blockIdx.y;
    int n = blockIdx.x;
    if (n >= a.N[cs]) return;
    int k = threadIdx.x;
    float s = 0.f;
    if (k < a.K[cs]) {
        float cc = a.c[cs] ? a.c[cs][k] : 1.0f;
        s = a.v[cs][k] * cc * a.W[cs][(long)k * a.N[cs] + n];
    }
    __shared__ float sm[256];
    sm[threadIdx.x] = s;
    __syncthreads();
    for (int o = 128; o > 0; o >>= 1) {
        if (threadIdx.x < o) sm[threadIdx.x] += sm[threadIdx.x + o];
        __syncthreads();
    }
    if (threadIdx.x == 0)
        a.out[cs][n] = (a.base[cs] ? a.base[cs][n] : 0.f) + sm[0];
}

// ---------------------------------------------------------------------------
// batched weight folds (transposed bf16 out, M=64 rows, K=256 fixed):
//   dstT[n,m] = (incl? Wsrc[m,n] : 0) + sum_k Wsrc[m,k]*(c?c[k]:1)*Wbig[k,n]
// ---------------------------------------------------------------------------
struct WFArgs {
    const float* Wsrc[4];
    const float* Wbig[4];
    const float* c[4];
    int incl[4], N[4];
    unsigned short* dst[4];
};
__global__ __launch_bounds__(256) void wfold_k(WFArgs a)
{
    int cs = blockIdx.y;
    int m = blockIdx.x;
    __shared__ float ws[256];
    const float* c = a.c[cs];
    ws[threadIdx.x] = a.Wsrc[cs][m * 256 + threadIdx.x] * (c ? c[threadIdx.x] : 1.0f);
    __syncthreads();
    int n = threadIdx.x;
    int N = a.N[cs];
    if (n >= N) return;
    float s = a.incl[cs] ? a.Wsrc[cs][m * 256 + n] : 0.f;
    const float* Wb = a.Wbig[cs];
    #pragma unroll 8
    for (int k = 0; k < 256; ++k)
        s += ws[k] * Wb[(long)k * N + n];
    a.dst[cs][n * 64 + m] = f2bfu(s);
}

// ---------------------------------------------------------------------------
// sc kernels: compute th, scale folded weights in place, fold bias vectors.
// ---------------------------------------------------------------------------
__global__ __launch_bounds__(256) void sc0_k(
    const float* __restrict__ partial, int np, float inv_n,
    unsigned short* __restrict__ Wa,   // 16384 *= th0
    unsigned short* __restrict__ Wb,   // 16384 *= om0
    const float* __restrict__ bg0p, const float* __restrict__ brg0p,
    const float* __restrict__ crow0, float* __restrict__ cv0)
{
    __shared__ float red[256];
    float th = block_th(partial, np, inv_n, red, threadIdx.x);
    float om = 1.f - th;
    int g = blockIdx.x * 256 + threadIdx.x;
    Wa[g] = f2bfu(th * bf2f(Wa[g]));
    Wb[g] = f2bfu(om * bf2f(Wb[g]));
    if (g < 256) cv0[g] = th * bg0p[g] + om * brg0p[g] + crow0[g];
}

// sc1 (grid 256): th1-scale Wg1T (65536) and Wg0pT/Wrg0pT; om1-scale Wrw0->Wrw0s
// and WrwWg1 (in place); fold bv1g = bg1 + om1*brw0 + th1*cv0, bw1s = om1*bw1v.
__global__ __launch_bounds__(256) void sc1_k(
    const float* __restrict__ partial, int np, float inv_n,
    unsigned short* __restrict__ Wg1T,
    const unsigned short* __restrict__ Wrw0T, unsigned short* __restrict__ Wrw0sT,
    unsigned short* __restrict__ Wg0pT, unsigned short* __restrict__ Wrg0pT,
    unsigned short* __restrict__ WrwWg1T,
    const float* __restrict__ bg1, const float* __restrict__ brw0,
    const float* __restrict__ cv0, const float* __restrict__ bw1v,
    float* __restrict__ bv1g, float* __restrict__ bw1s)
{
    __shared__ float red[256];
    float th = block_th(partial, np, inv_n, red, threadIdx.x);
    float om = 1.f - th;
    int g = blockIdx.x * 256 + threadIdx.x;
    Wg1T[g] = f2bfu(th * bf2f(Wg1T[g]));
    if (g < 16384) {
        Wrw0sT[g]  = f2bfu(om * bf2f(Wrw0T[g]));
        Wg0pT[g]   = f2bfu(th * bf2f(Wg0pT[g]));
        Wrg0pT[g]  = f2bfu(th * bf2f(Wrg0pT[g]));
        WrwWg1T[g] = f2bfu(om * bf2f(WrwWg1T[g]));
    }
    if (g < 256) {
        bv1g[g] = bg1[g] + om * brw0[g] + th * cv0[g];
        bw1s[g] = om * bw1v[g];
    }
}

__global__ __launch_bounds__(256) void sc2_k(
    const float* __restrict__ partial, int np, float inv_n,
    unsigned short* __restrict__ Wc1T,    // 16384 *= th2
    unsigned short* __restrict__ Wrgc1T,  // 4096  *= om2
    const float* __restrict__ brgc1, const float* __restrict__ crow1,
    float* __restrict__ cv2)
{
    __shared__ float red[256];
    float th = block_th(partial, np, inv_n, red, threadIdx.x);
    float om = 1.f - th;
    int g = blockIdx.x * 256 + threadIdx.x;
    Wc1T[g] = f2bfu(th * bf2f(Wc1T[g]));
    if (g < 4096) Wrgc1T[g] = f2bfu(om * bf2f(Wrgc1T[g]));
    if (g < 64) cv2[g] = om * brgc1[g] + crow1[g];
}

// ---------------------------------------------------------------------------
// Rbf producer: C = A@B + bias, written row-major AND per-batch transposed.
// ---------------------------------------------------------------------------
template<int BM, int BN, int FM, int FN>
__global__ __launch_bounds__(256) void gemm_res_k(
    const __hip_bfloat16* __restrict__ A, const __hip_bfloat16* __restrict__ Bt,
    const float* __restrict__ bias,
    __hip_bfloat16* __restrict__ Cb, __hip_bfloat16* __restrict__ CbT,
    int M, int N, int K)
{
    __shared__ __attribute__((aligned(128))) char lds[(BM + BN) * 128];
    char* AsB = lds;
    char* BsB = lds + BM * 128;

    const int m0 = blockIdx.y * BM;
    const int n0 = 0;
    const int tid  = threadIdx.x;
    const int wave = tid >> 6;
    const int lane = tid & 63;
    const int wn = wave & 1;

    f32x4 acc[FM][FN];
    #pragma unroll
    for (int i = 0; i < FM; ++i)
        #pragma unroll
        for (int j = 0; j < FN; ++j)
            acc[i][j] = (f32x4){0.f, 0.f, 0.f, 0.f};

    for (int k0 = 0; k0 < K; k0 += 64) {
        stage_tiles<BM, BN>(A, Bt, AsB, BsB, m0, n0, k0, K, K, wave, lane);
        __syncthreads();
        mfma_tiles<BM, BN, FM, FN>(AsB, BsB, acc, wave, lane);
        __syncthreads();
    }

    const int lc = lane & 15;
    #pragma unroll
    for (int j = 0; j < FN; ++j) {
        float bv = bias[n0 + wn * (FN * 16) + j * 16 + lc];
        #pragma unroll
        for (int i = 0; i < FM; ++i)
            #pragma unroll
            for (int r = 0; r < 4; ++r)
                acc[i][j][r] += bv;
    }
    write_tile<BM, BN, FM, FN>(lds, acc, Cb, (long)m0 * N + n0, N, tid);
    // transposed: CbT[b][c][node], b = m0/512, node0 = m0%512
    long baseT = (long)(m0 / NN) * ((long)N * NN) + (m0 % NN);
    write_tileT<BM, BN, FM, FN>(lds, acc, CbT, baseT, NN, tid);
}

// ---------------------------------------------------------------------------
// Batched MFMA GEMM with XCD-grouped block swizzle (proven round 10).
// ---------------------------------------------------------------------------
template<int BM, int BN, int FM, int FN, int GX, int NB>
__global__ __launch_bounds__(256) void gemm_bt_swz_k(
    const __hip_bfloat16* __restrict__ A, const __hip_bfloat16* __restrict__ Bt,
    __hip_bfloat16* __restrict__ Cb,
    int M, int N, int K, long sA, long sB, long sC)
{
    __shared__ __attribute__((aligned(128))) char lds[(BM + BN) * 128];
    char* AsB = lds;
    char* BsB = lds + BM * 128;

    const int d   = blockIdx.x;
    const int xcd = d & 7;
    const int q   = d >> 3;
    const int t   = q % NB;
    const int bz  = xcd + ((q / NB) << 3);
    const int n0  = (t % GX) * BN;
    const int m0  = (t / GX) * BM;

    const __hip_bfloat16* Ab = A + (long)bz * sA;
    const __hip_bfloat16* Bb = Bt + (long)bz * sB;

    const int tid  = threadIdx.x;
    const int wave = tid >> 6;
    const int lane = tid & 63;

    f32x4 acc[FM][FN];
    #pragma unroll
    for (int i = 0; i < FM; ++i)
        #pragma unroll
        for (int j = 0; j < FN; ++j)
            acc[i][j] = (f32x4){0.f, 0.f, 0.f, 0.f};

    for (int k0 = 0; k0 < K; k0 += 64) {
        stage_tiles<BM, BN>(Ab, Bb, AsB, BsB, m0, n0, k0, K, K, wave, lane);
        __syncthreads();
        mfma_tiles<BM, BN, FM, FN>(AsB, BsB, acc, wave, lane);
        __syncthreads();
    }

    write_tile<BM, BN, FM, FN>(lds, acc, Cb, (long)bz * sC + (long)m0 * N + n0, N, tid);
}

// ---------------------------------------------------------------------------
// dual1_k (D0): ONE accumulator, pair-swizzled. acc = A0@B0 + A1@B1 (B1
// pre-negated); diff = acc + b1 - b2; partials only.
// ---------------------------------------------------------------------------
template<int BM, int BN, int FM, int FN>
__global__ __launch_bounds__(256) void dual1_k(
    const __hip_bfloat16* __restrict__ A0, const __hip_bfloat16* __restrict__ B0, int K0,
    const __hip_bfloat16* __restrict__ A1, const __hip_bfloat16* __restrict__ B1, int K1,
    const float* __restrict__ b1, const float* __restrict__ b2,
    float* __restrict__ partial, int M, int N)
{
    __shared__ __attribute__((aligned(128))) char lds[(BM + BN) * 128];
    char* AsB = lds;
    char* BsB = lds + BM * 128;

    const int d   = blockIdx.x;
    const int q   = d >> 3;
    const int nx  = q & 1;
    const int my  = (d & 7) + ((q >> 1) << 3);
    const int m0  = my * BM;
    const int n0  = nx * BN;

    const int tid  = threadIdx.x;
    const int wave = tid >> 6;
    const int lane = tid & 63;
    const int wn = wave & 1;

    f32x4 acc[FM][FN];
    #pragma unroll
    for (int i = 0; i < FM; ++i)
        #pragma unroll
        for (int j = 0; j < FN; ++j)
            acc[i][j] = (f32x4){0.f, 0.f, 0.f, 0.f};

    #pragma unroll
    for (int ph = 0; ph < 2; ++ph) {
        const __hip_bfloat16* Ab = ph ? A1 : A0;
        const __hip_bfloat16* Bb = ph ? B1 : B0;
        const int K = ph ? K1 : K0;
        for (int k0 = 0; k0 < K; k0 += 64) {
            stage_tiles<BM, BN>(Ab, Bb, AsB, BsB, m0, n0, k0, K, K, wave, lane);
            __syncthreads();
            mfma_tiles<BM, BN, FM, FN>(AsB, BsB, acc, wave, lane);
            __syncthreads();
        }
    }

    const int lc = lane & 15;
    float dsum = 0.f;
    #pragma unroll
    for (int j = 0; j < FN; ++j) {
        int col = n0 + wn * (FN * 16) + j * 16 + lc;
        float bd = b1[col] - b2[col];
        #pragma unroll
        for (int i = 0; i < FM; ++i)
            #pragma unroll
            for (int r = 0; r < 4; ++r) {
                float dd = acc[i][j][r] + bd;
                dsum += dd * dd;
            }
    }

    float* red = (float*)lds;
    red[tid] = dsum;
    __syncthreads();
    for (int o = 128; o > 0; o >>= 1) {
        if (tid < o) red[tid] += red[tid + o];
        __syncthreads();
    }
    if (tid == 0) partial[my * 2 + nx] = red[0];
}

// ---------------------------------------------------------------------------
// wave2T_k (W0): TWO accumulators, pre-scaled weights; writes ONLY C1,
// TRANSPOSED (per-batch (H, N) layout) — feeds T1x = adj@xwr directly.
//   acc0 = A0@B0 + A1@B1 ; acc1 = A2@B2 (diff only)
// ---------------------------------------------------------------------------
template<int BM, int BN, int FM, int FN>
__global__ __launch_bounds__(256) void wave2T_k(
    const __hip_bfloat16* __restrict__ A0, const __hip_bfloat16* __restrict__ B0, int K0,
    const __hip_bfloat16* __restrict__ A1, const __hip_bfloat16* __restrict__ B1, int K1,
    const __hip_bfloat16* __restrict__ A2, const __hip_bfloat16* __restrict__ B2, int K2,
    const float* __restrict__ cv, const float* __restrict__ b2v,
    __hip_bfloat16* __restrict__ C1T, float* __restrict__ partial_out, int M, int N)
{
    __shared__ __attribute__((aligned(128))) char lds[(BM + BN) * 128];
    char* AsB = lds;
    char* BsB = lds + BM * 128;

    const int d   = blockIdx.x;
    const int q   = d >> 3;
    const int nx  = q & 1;
    const int my  = (d & 7) + ((q >> 1) << 3);
    const int m0  = my * BM;
    const int n0  = nx * BN;

    const int tid  = threadIdx.x;
    const int wave = tid >> 6;
    const int lane = tid & 63;
    const int wn = wave & 1;

    f32x4 acc0[FM][FN], acc1[FM][FN];
    #pragma unroll
    for (int i = 0; i < FM; ++i)
        #pragma unroll
        for (int j = 0; j < FN; ++j) {
            acc0[i][j] = (f32x4){0.f, 0.f, 0.f, 0.f};
            acc1[i][j] = (f32x4){0.f, 0.f, 0.f, 0.f};
        }

    #pragma unroll
    for (int ph = 0; ph < 3; ++ph) {
        const __hip_bfloat16* Ab = (ph == 0) ? A0 : (ph == 1 ? A1 : A2);
        const __hip_bfloat16* Bb = (ph == 0) ? B0 : (ph == 1 ? B1 : B2);
        const int K = (ph == 0) ? K0 : (ph == 1 ? K1 : K2);
        for (int k0 = 0; k0 < K; k0 += 64) {
            stage_tiles<BM, BN>(Ab, Bb, AsB, BsB, m0, n0, k0, K, K, wave, lane);
            __syncthreads();
            if (ph < 2) mfma_tiles<BM, BN, FM, FN>(AsB, BsB, acc0, wave, lane);
            else        mfma_tiles<BM, BN, FM, FN>(AsB, BsB, acc1, wave, lane);
            __syncthreads();
        }
    }

    const int lc = lane & 15;
    float dsum = 0.f;
    #pragma unroll
    for (int j = 0; j < FN; ++j) {
        int col = n0 + wn * (FN * 16) + j * 16 + lc;
        float c1 = cv[col];
        float c2 = b2v[col];
        #pragma unroll
        for (int i = 0; i < FM; ++i)
            #pragma unroll
            for (int r = 0; r < 4; ++r) {
                float v1 = acc0[i][j][r] + c1;
                float v2 = acc1[i][j][r] + c2;
                acc0[i][j][r] = v1;
                float dd = v1 - v2;
                dsum += dd * dd;
            }
    }

    float* red = (float*)lds;
    red[tid] = dsum;
    __syncthreads();
    for (int o = 128; o > 0; o >>= 1) {
        if (tid < o) red[tid] += red[tid + o];
        __syncthreads();
    }
    if (tid == 0) partial_out[my * 2 + nx] = red[0];

    // transposed write: C1T[b][n0+c][node0+m], b = m0/512
    long baseT = (long)(m0 / NN) * ((long)N * NN) + (long)n0 * NN + (m0 % NN);
    write_tileT<BM, BN, FM, FN>(lds, acc0, C1T, baseT, NN, tid);
}

// ---------------------------------------------------------------------------
// gmix4_k: pure-MFMA 6-phase with rank-1 epilogue term:
//   acc0 = T1x@(th1*Wg1) + Radj@(om1*WrwWg1) + T0@(th1*th0*Wg0p)
//        + Rbf@(th1*om0*Wrg0p) + Rbf@(om1*Wrw0)
//   acc1 = Rbf@Wrg1
//   xg1 = acc0 + bv1g[col] + ars[node]*bw1s[col] ; diff vs acc1 + brg1[col]
// ---------------------------------------------------------------------------
template<int BM, int BN, int FM, int FN>
__global__ __launch_bounds__(256) void gmix4_k(
    const __hip_bfloat16* __restrict__ A0, const __hip_bfloat16* __restrict__ B0, int K0,
    const __hip_bfloat16* __restrict__ A1, const __hip_bfloat16* __restrict__ B1, int K1,
    const __hip_bfloat16* __restrict__ A2, const __hip_bfloat16* __restrict__ B2, int K2,
    const __hip_bfloat16* __restrict__ A3, const __hip_bfloat16* __restrict__ B3, int K3,
    const __hip_bfloat16* __restrict__ A4, const __hip_bfloat16* __restrict__ B4, int K4,
    const __hip_bfloat16* __restrict__ A5, const __hip_bfloat16* __restrict__ B5, int K5,
    const float* __restrict__ bv1, const float* __restrict__ b2v,
    const float* __restrict__ ars, const float* __restrict__ bw1s,
    __hip_bfloat16* __restrict__ C1, float* __restrict__ partial_out, int M, int N)
{
    __shared__ __attribute__((aligned(128))) char lds[(BM + BN) * 128];
    char* AsB = lds;
    char* BsB = lds + BM * 128;

    const int d  = blockIdx.x;
    const int q  = d >> 3;
    const int nx = q & 1;
    const int my = (d & 7) + ((q >> 1) << 3);
    const int m0 = my * BM;
    const int n0 = nx * BN;

    const int tid  = threadIdx.x;
    const int wave = tid >> 6;
    const int lane = tid & 63;
    const int wm = wave >> 1, wn = wave & 1;

    f32x4 acc0[FM][FN], acc1[FM][FN];
    #pragma unroll
    for (int i = 0; i < FM; ++i)
        #pragma unroll
        for (int j = 0; j < FN; ++j) {
            acc0[i][j] = (f32x4){0.f, 0.f, 0.f, 0.f};
            acc1[i][j] = (f32x4){0.f, 0.f, 0.f, 0.f};
        }

    const __hip_bfloat16* As[6] = {A0, A1, A2, A3, A4, A5};
    const __hip_bfloat16* Bs[6] = {B0, B1, B2, B3, B4, B5};
    const int Ks[6] = {K0, K1, K2, K3, K4, K5};

    #pragma unroll
    for (int ph = 0; ph < 6; ++ph) {
        const __hip_bfloat16* Ab = As[ph];
        const __hip_bfloat16* Bb = Bs[ph];
        const int K = Ks[ph];
        for (int k0 = 0; k0 < K; k0 += 64) {
            stage_tiles<BM, BN>(Ab, Bb, AsB, BsB, m0, n0, k0, K, K, wave, lane);
            __syncthreads();
            if (ph < 5) mfma_tiles<BM, BN, FM, FN>(AsB, BsB, acc0, wave, lane);
            else        mfma_tiles<BM, BN, FM, FN>(AsB, BsB, acc1, wave, lane);
            __syncthreads();
        }
    }

    const int lc  = lane & 15;
    const int lr4 = (lane >> 4) << 2;
    const int node0 = m0 & (NN - 1);
    float dsum = 0.f;
    #pragma unroll
    for (int j = 0; j < FN; ++j) {
        int col = n0 + wn * (FN * 16) + j * 16 + lc;
        float c1 = bv1[col];
        float c2 = b2v[col];
        float bw = bw1s[col];
        #pragma unroll
        for (int i = 0; i < FM; ++i) {
            int rowl = wm * (FM * 16) + i * 16 + lr4;
            #pragma unroll
            for (int r = 0; r < 4; ++r) {
                float av = ars[node0 + rowl + r];
                float v1 = acc0[i][j][r] + c1 + av * bw;
                float v2 = acc1[i][j][r] + c2;
                acc0[i][j][r] = v1;
                float dd = v1 - v2;
                dsum += dd * dd;
            }
        }
    }

    float* red = (float*)lds;
    red[tid] = dsum;
    __syncthreads();
    for (int o = 128; o > 0; o >>= 1) {
        if (tid < o) red[tid] += red[tid + o];
        __syncthreads();
    }
    if (tid == 0) partial_out[my * 2 + nx] = red[0];

    write_tile<BM, BN, FM, FN>(lds, acc0, C1, (long)m0 * N + n0, N, tid);
}

// ---------------------------------------------------------------------------
// wave2_k (F, plain grid): as round 10.
// ---------------------------------------------------------------------------
template<int BM, int BN, int FM, int FN>
__global__ __launch_bounds__(256) void wave2_k(
    const __hip_bfloat16* __restrict__ A0, const __hip_bfloat16* __restrict__ B0, int K0,
    const __hip_bfloat16* __restrict__ A1, const __hip_bfloat16* __restrict__ B1, int K1,
    const __hip_bfloat16* __restrict__ A2, const __hip_bfloat16* __restrict__ B2, int K2,
    const float* __restrict__ cv, const float* __restrict__ b2v,
    __hip_bfloat16* __restrict__ C1, __hip_bfloat16* __restrict__ C2,
    float* __restrict__ partial_out, int M, int N)
{
    __shared__ __attribute__((aligned(128))) char lds[(BM + BN) * 128];
    char* AsB = lds;
    char* BsB = lds + BM * 128;

    const int m0 = blockIdx.y * BM;
    const int n0 = blockIdx.x * BN;
    const int pidx = blockIdx.y * gridDim.x + blockIdx.x;

    const int tid  = threadIdx.x;
    const int wave = tid >> 6;
    const int lane = tid & 63;
    const int wn = wave & 1;

    f32x4 acc0[FM][FN], acc1[FM][FN];
    #pragma unroll
    for (int i = 0; i < FM; ++i)
        #pragma unroll
        for (int j = 0; j < FN; ++j) {
            acc0[i][j] = (f32x4){0.f, 0.f, 0.f, 0.f};
            acc1[i][j] = (f32x4){0.f, 0.f, 0.f, 0.f};
        }

    #pragma unroll
    for (int ph = 0; ph < 3; ++ph) {
        const __hip_bfloat16* Ab = (ph == 0) ? A0 : (ph == 1 ? A1 : A2);
        const __hip_bfloat16* Bb = (ph == 0) ? B0 : (ph == 1 ? B1 : B2);
        const int K = (ph == 0) ? K0 : (ph == 1 ? K1 : K2);
        for (int k0 = 0; k0 < K; k0 += 64) {
            stage_tiles<BM, BN>(Ab, Bb, AsB, BsB, m0, n0, k0, K, K, wave, lane);
            __syncthreads();
            if (ph < 2) mfma_tiles<BM, BN, FM, FN>(AsB, BsB, acc0, wave, lane);
            else        mfma_tiles<BM, BN, FM, FN>(AsB, BsB, acc1, wave, lane);
            __syncthreads();
        }
    }

    const int lc = lane & 15;
    float dsum = 0.f;
    #pragma unroll
    for (int j = 0; j < FN; ++j) {
        int col = n0 + wn * (FN * 16) + j * 16 + lc;
        float c1 = cv[col];
        float c2 = b2v[col];
        #pragma unroll
        for (int i = 0; i < FM; ++i)
            #pragma unroll
            for (int r = 0; r < 4; ++r) {
                float v1 = acc0[i][j][r] + c1;
                float v2 = acc1[i][j][r] + c2;
                acc0[i][j][r] = v1;
                acc1[i][j][r] = v2;
                float dd = v1 - v2;
                dsum += dd * dd;
            }
    }

    float* red = (float*)lds;
    red[tid] = dsum;
    __syncthreads();
    for (int o = 128; o > 0; o >>= 1) {
        if (tid < o) red[tid] += red[tid + o];
        __syncthreads();
    }
    if (tid == 0) partial_out[pidx] = red[0];

    write_tile<BM, BN, FM, FN>(lds, acc0, C1, (long)m0 * N + n0, N, tid);
    write_tile<BM, BN, FM, FN>(lds, acc1, C2, (long)m0 * N + n0, N, tid);
}

// ---------------------------------------------------------------------------
// final mix (th in-kernel): out = th*h + (1-th)*r, fp32 out
// ---------------------------------------------------------------------------
__global__ __launch_bounds__(256) void mixfinal_k(
    const unsigned short* __restrict__ h, const unsigned short* __restrict__ r,
    const float* __restrict__ partial_in, int np_in, float inv_in,
    float* __restrict__ out, long n4)
{
    __shared__ float sm[256];
    const float th = block_th(partial_in, np_in, inv_in, sm, (int)threadIdx.x);
    const float om = 1.f - th;
    long gid = (long)blockIdx.x * 256 + threadIdx.x;
    long stride = (long)gridDim.x * 256;
    for (long i = gid; i < n4; i += stride) {
        ushort4 hv = reinterpret_cast<const ushort4*>(h)[i];
        ushort4 rv = reinterpret_cast<const ushort4*>(r)[i];
        float4 o;
        o.x = th * bf2f(hv.x) + om * bf2f(rv.x);
        o.y = th * bf2f(hv.y) + om * bf2f(rv.y);
        o.z = th * bf2f(hv.z) + om * bf2f(rv.z);
        o.w = th * bf2f(hv.w) + om * bf2f(rv.w);
        reinterpret_cast<float4*>(out)[i] = o;
    }
}

// ---------------------------------------------------------------------------
extern "C" void kernel_launch(void* const* d_in, const int* in_sizes, int n_in,
                              void* d_out, int out_size, void* d_ws, size_t ws_size,
                              hipStream_t stream)
{
    const float* x       = (const float*)d_in[0];
    const float* adj     = (const float*)d_in[1];
    const float* Wres    = (const float*)d_in[2];
    const float* bres    = (const float*)d_in[3];
    const float* Wg0     = (const float*)d_in[4];
    const float* bg0     = (const float*)d_in[5];
    const float* Wrg0    = (const float*)d_in[6];
    const float* brg0    = (const float*)d_in[7];
    const float* logits0 = (const float*)d_in[8];
    const float* gumb0   = (const float*)d_in[9];
    const float* Wnl0    = (const float*)d_in[10];
    const float* bnl0    = (const float*)d_in[11];
    const float* Wwo0    = (const float*)d_in[12];
    const float* bwo0    = (const float*)d_in[13];
    const float* Wrw0    = (const float*)d_in[14];
    const float* brw0    = (const float*)d_in[15];
    const float* Wg1     = (const float*)d_in[16];
    const float* bg1     = (const float*)d_in[17];
    const float* Wrg1    = (const float*)d_in[18];
    const float* brg1    = (const float*)d_in[19];
    const float* logits1 = (const float*)d_in[20];
    const float* gumb1   = (const float*)d_in[21];
    const float* Wnl1    = (const float*)d_in[22];
    const float* bnl1    = (const float*)d_in[23];
    const float* Wwo1    = (const float*)d_in[24];
    const float* bwo1    = (const float*)d_in[25];
    const float* Wrw1    = (const float*)d_in[26];
    const float* brw1    = (const float*)d_in[27];

    float* out = (float*)d_out;

    // ---- workspace ----
    char* w = (char*)d_ws;
    auto alloc = [&](long bytes) { char* p = w; w += (bytes + 255) & ~255L; return p; };
    const long SLOT = (long)BNR * HH * 2;                 // 32 MB
    char* pool = alloc(5 * SLOT);                         // 160 MB
    __hip_bfloat16* Rbf  = (__hip_bfloat16*)alloc((long)BNR * DOUT * 2); // 8 MB
    __hip_bfloat16* adjb = (__hip_bfloat16*)alloc((long)NN * NN * 2);
    __hip_bfloat16* WT   = (__hip_bfloat16*)alloc(225280L * 2);
    float* partial0 = (float*)alloc(2048 * 4);
    float* partial1 = (float*)alloc(2048 * 4);
    float* partial2 = (float*)alloc(2048 * 4);
    float* partial3 = (float*)alloc(2048 * 4);
    float* c0      = (float*)alloc(256 * 4);
    float* c1      = (float*)alloc(256 * 4);
    float* bg0p    = (float*)alloc(256 * 4);
    float* brg0p   = (float*)alloc(256 * 4);
    float* crow0   = (float*)alloc(256 * 4);
    float* brgc1   = (float*)alloc(64 * 4);
    float* crow1   = (float*)alloc(64 * 4);
    float* cv0     = (float*)alloc(256 * 4);
    float* bv1g    = (float*)alloc(256 * 4);
    float* cv2     = (float*)alloc(64 * 4);
    float* ars     = (float*)alloc(512 * 4);
    float* bw1v    = (float*)alloc(256 * 4);
    float* bw1s    = (float*)alloc(256 * 4);

    auto S = [&](int i) { return pool + (long)i * SLOT; };
    // S(0): xwrT (b,H,N) 32MB — W0 out, T1x B-operand
    // S(1): orw [0,8M), rw1 [8M,16M), Radj [16M,24M)
    // S(2): xg1 32MB
    // S(3): T1x 32MB
    // S(4): xbf | xT | T0 | RbfT (8MB each)
    __hip_bfloat16* xwrT = (__hip_bfloat16*)S(0);
    __hip_bfloat16* orw  = (__hip_bfloat16*)S(1);
    __hip_bfloat16* rw1  = (__hip_bfloat16*)(S(1) + (long)BNR * DOUT * 2);
    __hip_bfloat16* Radj = (__hip_bfloat16*)(S(1) + 2L * BNR * DOUT * 2);
    __hip_bfloat16* xg1  = (__hip_bfloat16*)S(2);
    __hip_bfloat16* T1x  = (__hip_bfloat16*)S(3);
    __hip_bfloat16* xbf  = (__hip_bfloat16*)S(4);
    __hip_bfloat16* xT   = (__hip_bfloat16*)(S(4) + (long)BNR * DIN * 2);
    __hip_bfloat16* T0   = (__hip_bfloat16*)(S(4) + 2L * BNR * DIN * 2);
    __hip_bfloat16* RbfT = (__hip_bfloat16*)(S(4) + 3L * BNR * DIN * 2);

    // transposed weights inside WT (element offsets)
    __hip_bfloat16* WresT   = WT;             // 64x64   (4096)
    __hip_bfloat16* Wg0T    = WT + 4096;      // 256x64  (16384)
    __hip_bfloat16* Wrg0T   = WT + 20480;     // 256x64  (NEGATED at prep)
    __hip_bfloat16* Wrw0T   = WT + 36864;     // 256x64
    __hip_bfloat16* Wg1T    = WT + 53248;     // 256x256 (65536; th1 by sc1)
    __hip_bfloat16* Wrg1T   = WT + 118784;    // 256x64
    __hip_bfloat16* Wc1T    = WT + 135168;    // 64x256 (c1-scaled Wwo1^T; th2 by sc2)
    __hip_bfloat16* Wrw1T   = WT + 151552;    // 64x64
    __hip_bfloat16* Wg0pT   = WT + 155648;    // 256x64 (Wg0@(I+Wc0))^T; th0 sc0; th1 sc1
    __hip_bfloat16* Wrg0pT  = WT + 172032;    // 256x64 (Wrg0@(I+Wc0))^T; om0 sc0; th1 sc1
    __hip_bfloat16* Wrgc1T  = WT + 188416;    // 64x64  (Wrg1@Wc1)^T; om2 sc2
    __hip_bfloat16* Wrw0sT  = WT + 192512;    // 256x64 (om1*Wrw0)^T by sc1
    __hip_bfloat16* WrwWg1T = WT + 208896;    // 256x64 (Wrw0@Wg1)^T; om1 by sc1

    const dim3 blk(256);
    const float invH = 1.0f / ((float)BNR * HH);
    const float invD = 1.0f / ((float)BNR * DOUT);

    // ---- prep ----
    hipLaunchKernelGGL(coeff2_k, dim3(2), dim3(256), 0, stream,
                       logits0, gumb0, Wnl0, c0, logits1, gumb1, Wnl1, c1);
    hipLaunchKernelGGL(cvta_k, dim3(NN), blk, 0, stream, adj, (unsigned int*)adjb, ars);
    hipLaunchKernelGGL(cvtx_k, dim3(1, 8, BB), blk, 0, stream, x,
                       (unsigned short*)xbf, (unsigned short*)xT);

    WTArgs wa;
    wa.src[0] = Wres; wa.dst[0] = (unsigned short*)WresT; wa.cs[0] = nullptr; wa.sgn[0] = 1.f;  wa.R[0] = 64;  wa.C[0] = 64;
    wa.src[1] = Wg0;  wa.dst[1] = (unsigned short*)Wg0T;  wa.cs[1] = nullptr; wa.sgn[1] = 1.f;  wa.R[1] = 64;  wa.C[1] = 256;
    wa.src[2] = Wrg0; wa.dst[2] = (unsigned short*)Wrg0T; wa.cs[2] = nullptr; wa.sgn[2] = -1.f; wa.R[2] = 64;  wa.C[2] = 256;
    wa.src[3] = Wrw0; wa.dst[3] = (unsigned short*)Wrw0T; wa.cs[3] = nullptr; wa.sgn[3] = 1.f;  wa.R[3] = 64;  wa.C[3] = 256;
    wa.src[4] = Wg1;  wa.dst[4] = (unsigned short*)Wg1T;  wa.cs[4] = nullptr; wa.sgn[4] = 1.f;  wa.R[4] = 256; wa.C[4] = 256;
    wa.src[5] = Wrg1; wa.dst[5] = (unsigned short*)Wrg1T; wa.cs[5] = nullptr; wa.sgn[5] = 1.f;  wa.R[5] = 64;  wa.C[5] = 256;
    wa.src[6] = Wwo1; wa.dst[6] = (unsigned short*)Wc1T;  wa.cs[6] = c1;      wa.sgn[6] = 1.f;  wa.R[6] = 256; wa.C[6] = 64;
    wa.src[7] = Wrw1; wa.dst[7] = (unsigned short*)Wrw1T; wa.cs[7] = nullptr; wa.sgn[7] = 1.f;  wa.R[7] = 64;  wa.C[7] = 64;
    hipLaunchKernelGGL(tcvt_w_k, dim3(16, 8), blk, 0, stream, wa);

    WFArgs wf;
    wf.Wsrc[0] = Wg0;  wf.Wbig[0] = Wwo0; wf.c[0] = c0;      wf.incl[0] = 1; wf.N[0] = 256;
    wf.dst[0] = (unsigned short*)Wg0pT;
    wf.Wsrc[1] = Wrg0; wf.Wbig[1] = Wwo0; wf.c[1] = c0;      wf.incl[1] = 1; wf.N[1] = 256;
    wf.dst[1] = (unsigned short*)Wrg0pT;
    wf.Wsrc[2] = Wrg1; wf.Wbig[2] = Wwo1; wf.c[2] = c1;      wf.incl[2] = 0; wf.N[2] = 64;
    wf.dst[2] = (unsigned short*)Wrgc1T;
    wf.Wsrc[3] = Wrw0; wf.Wbig[3] = Wg1;  wf.c[3] = nullptr; wf.incl[3] = 0; wf.N[3] = 256;
    wf.dst[3] = (unsigned short*)WrwWg1T;
    hipLaunchKernelGGL(wfold_k, dim3(64, 4), blk, 0, stream, wf);

    FVArgs fv;
    fv.W[0] = Wwo0; fv.c[0] = c0;      fv.v[0] = bg0;  fv.base[0] = bg0;     fv.out[0] = bg0p;  fv.K[0] = 256; fv.N[0] = 256;
    fv.W[1] = Wwo0; fv.c[1] = c0;      fv.v[1] = brg0; fv.base[1] = brg0;    fv.out[1] = brg0p; fv.K[1] = 256; fv.N[1] = 256;
    fv.W[2] = Wwo0; fv.c[2] = nullptr; fv.v[2] = bnl0; fv.base[2] = bwo0;    fv.out[2] = crow0; fv.K[2] = 256; fv.N[2] = 256;
    fv.W[3] = Wwo1; fv.c[3] = c1;      fv.v[3] = brg1; fv.base[3] = nullptr; fv.out[3] = brgc1; fv.K[3] = 256; fv.N[3] = 64;
    fv.W[4] = Wwo1; fv.c[4] = nullptr; fv.v[4] = bnl1; fv.base[4] = bwo1;    fv.out[4] = crow1; fv.K[4] = 256; fv.N[4] = 64;
    fv.W[5] = Wg1;  fv.c[5] = nullptr; fv.v[5] = brw0; fv.base[5] = nullptr; fv.out[5] = bw1v;  fv.K[5] = 256; fv.N[5] = 256;
    hipLaunchKernelGGL(foldvec_k, dim3(256, 6), blk, 0, stream, fv);

    // res = x @ Wres + bres -> Rbf (row-major) + RbfT (per-batch transposed)
    hipLaunchKernelGGL((gemm_res_k<128, 64, 4, 2>), dim3(1, BNR / 128, 1), blk, 0, stream,
                       xbf, WresT, bres, Rbf, RbfT, BNR, DOUT, DIN);

    // T0 = adj @ x (batched, XCD-grouped)
    hipLaunchKernelGGL((gemm_bt_swz_k<128, 64, 4, 2, 1, 4>), dim3(BB * 4), blk, 0, stream,
                       adjb, xT, T0, NN, DIN, NN, 0, (long)DIN * NN, (long)NN * DIN);

    // Radj = adj @ Rbf (batched, XCD-grouped; B = RbfT)
    hipLaunchKernelGGL((gemm_bt_swz_k<128, 64, 4, 2, 1, 4>), dim3(BB * 4), blk, 0, stream,
                       adjb, RbfT, Radj, NN, DOUT, NN, 0, (long)DOUT * NN, (long)NN * DOUT);

    // D0: diff0 partials only
    hipLaunchKernelGGL((dual1_k<64, 128, 2, 4>), dim3(2 * BNR / 64), blk, 0, stream,
                       T0, Wg0T, DIN, Rbf, Wrg0T, DOUT, bg0, brg0, partial0, BNR, HH);

    // sc0
    hipLaunchKernelGGL(sc0_k, dim3(64), blk, 0, stream, partial0, 2048, invH,
                       (unsigned short*)Wg0pT, (unsigned short*)Wrg0pT,
                       bg0p, brg0p, crow0, cv0);

    // W0: xwrT = [T0@(th0*Wg0p) + Rbf@(om0*Wrg0p) + cv0]^T ; diff vs Rbf@Wrw0+brw0
    hipLaunchKernelGGL((wave2T_k<64, 128, 2, 4>), dim3(2 * BNR / 64), blk, 0, stream,
                       T0, Wg0pT, DIN, Rbf, Wrg0pT, DOUT, Rbf, Wrw0T, DOUT,
                       cv0, brw0, xwrT, partial1, BNR, HH);

    // sc1
    hipLaunchKernelGGL(sc1_k, dim3(256), blk, 0, stream, partial1, 2048, invH,
                       (unsigned short*)Wg1T,
                       (const unsigned short*)Wrw0T, (unsigned short*)Wrw0sT,
                       (unsigned short*)Wg0pT, (unsigned short*)Wrg0pT,
                       (unsigned short*)WrwWg1T,
                       bg1, brw0, cv0, bw1v, bv1g, bw1s);

    // T1x = adj @ xwr (batched, XCD-grouped; B = xwrT)
    hipLaunchKernelGGL((gemm_bt_swz_k<128, 128, 4, 4, 2, 8>), dim3(BB * 8), blk, 0, stream,
                       adjb, xwrT, T1x, NN, HH, NN, 0, (long)HH * NN, (long)NN * HH);

    // gmix4: xg1 (6 MFMA phases + rank-1), diff2 partials
    hipLaunchKernelGGL((gmix4_k<64, 128, 2, 4>), dim3(2 * BNR / 64), blk, 0, stream,
                       T1x, Wg1T, HH,
                       Radj, WrwWg1T, DOUT,
                       T0, Wg0pT, DIN,
                       Rbf, Wrg0pT, DOUT,
                       Rbf, Wrw0sT, DOUT,
                       Rbf, Wrg1T, DOUT,
                       bv1g, brg1, ars, bw1s, xg1, partial2, BNR, HH);

    // sc2
    hipLaunchKernelGGL(sc2_k, dim3(64), blk, 0, stream, partial2, 2048, invH,
                       (unsigned short*)Wc1T, (unsigned short*)Wrgc1T,
                       brgc1, crow1, cv2);

    // F: orw = xg1@(th2*Wc1) + Rbf@(om2*Wrgc1) + cv2 ; rw1 = Rbf@Wrw1 + brw1
    hipLaunchKernelGGL((wave2_k<64, 64, 2, 2>), dim3(1, BNR / 64), blk, 0, stream,
                       xg1, Wc1T, HH, Rbf, Wrgc1T, DOUT, Rbf, Wrw1T, DIN,
                       cv2, brw1, orw, rw1, partial3, BNR, DOUT);

    // final mix -> fp32 out
    hipLaunchKernelGGL(mixfinal_k, dim3(2048), blk, 0, stream,
                       (const unsigned short*)orw, (const unsigned short*)rw1,
                       partial3, 1024, invD, out, (long)BNR * DOUT / 4);
}

// Round 13
// 178.218 us; speedup vs baseline: 1.2681x; 1.0895x over previous
//
#include <hip/hip_runtime.h>
#include <hip/hip_bf16.h>
#include <math.h>

#define BB   128
#define NN   512
#define DIN  64
#define HH   256
#define DOUT 64
#define BNR  (BB * NN)          // 65536 rows

typedef float  f32x4  __attribute__((ext_vector_type(4)));
typedef __bf16 bf16x8 __attribute__((ext_vector_type(8)));

#define GLP(p)  ((const __attribute__((address_space(1))) void*)(p))
#define LDSP(p) ((__attribute__((address_space(3))) void*)(p))

// Haar/db1 'zero' DWT patterns, levels 1..3, FULL_LEN=8
__constant__ float PAT[3][8] = {
    {0.70710678f, 0.70710678f, 0.f, 0.f, 0.f, 0.f, 0.f, 0.f},
    {0.5f,        0.70710678f, 0.f, 0.5f, 0.f, 0.f, 0.f, 0.f},
    {0.35355339f, 0.70710678f, 0.f, 0.f, 0.f, 0.5f, 0.f, 0.35355339f}
};

__device__ __forceinline__ unsigned short f2bfu(float x) {
    __hip_bfloat16 b = __float2bfloat16(x);
    unsigned short u;
    __builtin_memcpy(&u, &b, 2);
    return u;
}
__device__ __forceinline__ float bf2f(unsigned short u) {
    unsigned int v = ((unsigned int)u) << 16;
    float f;
    __builtin_memcpy(&f, &v, 4);
    return f;
}

// ---------------------------------------------------------------------------
// In-kernel th = sigmoid(mean diff) — same tree order everywhere.
// ---------------------------------------------------------------------------
__device__ __forceinline__ float block_th(const float* __restrict__ partial, int np,
                                          float inv_n, float* red, int tid)
{
    float s = 0.f;
    for (int i = tid; i < np; i += 256) s += partial[i];
    red[tid] = s;
    __syncthreads();
    for (int o = 128; o > 0; o >>= 1) {
        if (tid < o) red[tid] += red[tid + o];
        __syncthreads();
    }
    float th = 1.f / (1.f + expf(-red[0] * inv_n));
    __syncthreads();
    return th;
}

// ---------------------------------------------------------------------------
// Coalesced bf16 tile write via LDS staging (proven round 4). Row-major.
// ---------------------------------------------------------------------------
template<int BM, int BN, int FM, int FN>
__device__ __forceinline__ void write_tile(char* lds, f32x4 (&a)[FM][FN],
                                           __hip_bfloat16* __restrict__ C,
                                           long base, int N, int tid)
{
    const int wave = tid >> 6;
    const int lane = tid & 63;
    const int wm = wave >> 1, wn = wave & 1;
    const int lc = lane & 15;
    const int lr4 = (lane >> 4) << 2;
    __syncthreads();
    #pragma unroll
    for (int j = 0; j < FN; ++j) {
        int colb = (wn * (FN * 16) + j * 16 + lc) * 2;
        #pragma unroll
        for (int i = 0; i < FM; ++i) {
            int row0 = wm * (FM * 16) + i * 16 + lr4;
            #pragma unroll
            for (int r = 0; r < 4; ++r) {
                int row = row0 + r;
                *reinterpret_cast<unsigned short*>(
                    lds + row * (BN * 2) + (colb ^ (((row >> 2) & 3) << 5))) =
                    f2bfu(a[i][j][r]);
            }
        }
    }
    __syncthreads();
    const int TPR = BN / 8;
    const int RPP = 256 / TPR;
    #pragma unroll
    for (int p = 0; p < BM / RPP; ++p) {
        int row = p * RPP + tid / TPR;
        int cb = (tid % TPR) * 16;
        int pb = cb ^ (((row >> 2) & 3) << 5);
        uint4 v = *reinterpret_cast<const uint4*>(lds + row * (BN * 2) + pb);
        *reinterpret_cast<uint4*>(reinterpret_cast<char*>(C + base + (long)row * N) + cb) = v;
    }
}

// ---------------------------------------------------------------------------
// Transposed tile write (proven round 11).
// ---------------------------------------------------------------------------
template<int BM, int BN, int FM, int FN>
__device__ __forceinline__ void write_tileT(char* lds, f32x4 (&a)[FM][FN],
                                            __hip_bfloat16* __restrict__ CT,
                                            long baseT, int ldT, int tid)
{
    const int wave = tid >> 6;
    const int lane = tid & 63;
    const int wm = wave >> 1, wn = wave & 1;
    const int lc = lane & 15;
    const int lr4 = (lane >> 4) << 2;
    __syncthreads();
    #pragma unroll
    for (int j = 0; j < FN; ++j) {
        int c = wn * (FN * 16) + j * 16 + lc;
        int cbase = c * (BM * 2);
        int swz = ((c >> 2) & 3) << 5;
        #pragma unroll
        for (int i = 0; i < FM; ++i) {
            int m0 = wm * (FM * 16) + i * 16 + lr4;
            #pragma unroll
            for (int r = 0; r < 4; ++r) {
                int m = m0 + r;
                *reinterpret_cast<unsigned short*>(lds + cbase + ((m * 2) ^ swz)) =
                    f2bfu(a[i][j][r]);
            }
        }
    }
    __syncthreads();
    const int TPR = BM / 8;
    const int RPP = 256 / TPR;
    #pragma unroll
    for (int p = 0; p < BN / RPP; ++p) {
        int c = p * RPP + tid / TPR;
        int tb = (tid % TPR) * 16;
        int pb = tb ^ (((c >> 2) & 3) << 5);
        uint4 v = *reinterpret_cast<const uint4*>(lds + c * (BM * 2) + pb);
        *reinterpret_cast<uint4*>(reinterpret_cast<char*>(CT + baseT + (long)c * ldT) + tb) = v;
    }
}

// ---------------------------------------------------------------------------
// staging of one K=64 slab of A(BM rows) + B(BN rows) into swizzled LDS
// ---------------------------------------------------------------------------
template<int BM, int BN>
__device__ __forceinline__ void stage_tiles(const __hip_bfloat16* __restrict__ Ab,
                                            const __hip_bfloat16* __restrict__ Bb,
                                            char* AsB, char* BsB,
                                            int m0, int n0, int k0, int KA, int KB,
                                            int wave, int lane)
{
    const int NCH = (BM + BN) / 32;
    const int lr = lane >> 3;
    const int ls = lane & 7;
    #pragma unroll
    for (int cc = 0; cc < NCH; ++cc) {
        int c = wave * NCH + cc;
        const __hip_bfloat16* src;
        char* ldsb;
        if (c < BM / 8) {
            int r = c * 8 + lr;
            ldsb = AsB + c * 1024;
            src = Ab + ((long)(m0 + r) * KA + k0 + ((ls ^ (r & 7)) << 3));
        } else {
            int c2 = c - BM / 8;
            int r = c2 * 8 + lr;
            ldsb = BsB + c2 * 1024;
            src = Bb + ((long)(n0 + r) * KB + k0 + ((ls ^ (r & 7)) << 3));
        }
        __builtin_amdgcn_global_load_lds(GLP(src), LDSP(ldsb), 16, 0, 0);
    }
}

template<int BM, int BN, int FM, int FN>
__device__ __forceinline__ void mfma_tiles(char* AsB, char* BsB,
                                           f32x4 (&acc)[FM][FN], int wave, int lane)
{
    const int wm = wave >> 1, wn = wave & 1;
    #pragma unroll
    for (int ksl = 0; ksl < 2; ++ksl) {
        bf16x8 af[FM], bfr[FN];
        #pragma unroll
        for (int i = 0; i < FM; ++i) {
            int row = wm * (FM * 16) + i * 16 + (lane & 15);
            int off = (ksl * 64 + ((lane >> 4) << 4)) ^ ((row & 7) << 4);
            af[i] = *reinterpret_cast<const bf16x8*>(AsB + row * 128 + off);
        }
        #pragma unroll
        for (int j = 0; j < FN; ++j) {
            int row = wn * (FN * 16) + j * 16 + (lane & 15);
            int off = (ksl * 64 + ((lane >> 4) << 4)) ^ ((row & 7) << 4);
            bfr[j] = *reinterpret_cast<const bf16x8*>(BsB + row * 128 + off);
        }
        #pragma unroll
        for (int i = 0; i < FM; ++i)
            #pragma unroll
            for (int j = 0; j < FN; ++j)
                acc[i][j] = __builtin_amdgcn_mfma_f32_16x16x32_bf16(
                    af[i], bfr[j], acc[i][j], 0, 0, 0);
    }
}

// ---------------------------------------------------------------------------
// Pipelined multi-step runner — guide's verified minimum-2-phase recipe with
// __syncthreads ONLY (no inline asm): per step {issue STAGE(t+1) -> compute(t)
// -> __syncthreads}. compute(t)'s buffer was drained by the PREVIOUS
// __syncthreads (vmcnt(0)+barrier, exact compiler semantics); the buffer being
// staged was last read before that same barrier. Stage-(t+1) latency hides
// under compute(t). Steps 0..NA-1 -> acc0, NA.. -> acc1.
// ---------------------------------------------------------------------------
template<int BM, int BN, int FM, int FN, int NS, int NA>
__device__ __forceinline__ void pipe_run(
    const __hip_bfloat16* const (&sA)[NS], const __hip_bfloat16* const (&sB)[NS],
    const int (&sK)[NS], const int (&sk0)[NS],
    char* buf0, char* buf1,
    f32x4 (&acc0)[FM][FN], f32x4 (&acc1)[FM][FN],
    int m0, int n0, int wave, int lane)
{
    constexpr int BOFF = BM * 128;
    stage_tiles<BM, BN>(sA[0], sB[0], buf0, buf0 + BOFF, m0, n0, sk0[0],
                        sK[0], sK[0], wave, lane);
    __syncthreads();
    #pragma unroll
    for (int t = 0; t < NS; ++t) {
        char* bc = (t & 1) ? buf1 : buf0;
        if (t + 1 < NS) {
            char* bn = (t & 1) ? buf0 : buf1;
            stage_tiles<BM, BN>(sA[t + 1], sB[t + 1], bn, bn + BOFF, m0, n0,
                                sk0[t + 1], sK[t + 1], sK[t + 1], wave, lane);
        }
        if (t < NA) mfma_tiles<BM, BN, FM, FN>(bc, bc + BOFF, acc0, wave, lane);
        else        mfma_tiles<BM, BN, FM, FN>(bc, bc + BOFF, acc1, wave, lane);
        __syncthreads();
    }
}

// ---------------------------------------------------------------------------
// adj: fp32 -> bf16 + row sums (one block per row)
// ---------------------------------------------------------------------------
__global__ __launch_bounds__(256) void cvta_k(const float* __restrict__ adj,
                                              unsigned int* __restrict__ adjb,
                                              float* __restrict__ ars)
{
    int n = blockIdx.x;
    int t = threadIdx.x;
    float2 v = reinterpret_cast<const float2*>(adj)[n * 256 + t];
    adjb[n * 256 + t] = (unsigned int)f2bfu(v.x) | ((unsigned int)f2bfu(v.y) << 16);
    __shared__ float sm[256];
    sm[t] = v.x + v.y;
    __syncthreads();
    for (int o = 128; o > 0; o >>= 1) {
        if (t < o) sm[t] += sm[t + o];
        __syncthreads();
    }
    if (t == 0) ars[n] = sm[0];
}

// ---------------------------------------------------------------------------
// fused x conversion: one read of x -> xbf (row-major bf16) + xT (transposed)
// ---------------------------------------------------------------------------
__global__ __launch_bounds__(256) void cvtx_k(const float* __restrict__ in,
                                              unsigned short* __restrict__ rm,
                                              unsigned short* __restrict__ tr)
{
    __shared__ float t[64][65];
    const long base = (long)blockIdx.z * NN * DIN;
    const int r0 = blockIdx.y * 64;
    const int tr4 = threadIdx.x >> 6;
    const int tc  = threadIdx.x & 63;
    #pragma unroll
    for (int i = 0; i < 16; ++i) {
        int r = i * 4 + tr4;
        float v = in[base + (long)(r0 + r) * DIN + tc];
        t[r][tc] = v;
        rm[base + (long)(r0 + r) * DIN + tc] = f2bfu(v);
    }
    __syncthreads();
    #pragma unroll
    for (int i = 0; i < 16; ++i) {
        int d = i * 4 + tr4;
        tr[base + (long)d * NN + r0 + tc] = f2bfu(t[tc][d]);
    }
}

// ---------------------------------------------------------------------------
// transpose-convert fp32 (R,C) -> bf16 (C,R), optional per-src-row scale + sign
// ---------------------------------------------------------------------------
__device__ __forceinline__ void tcvt_body(const float* __restrict__ in,
                                          unsigned short* __restrict__ out,
                                          const float* __restrict__ cs, float us,
                                          int R, int C, int r0, int c0)
{
    __shared__ float t[64][65];
    int tr = threadIdx.x >> 6;
    int tc = threadIdx.x & 63;
    #pragma unroll
    for (int i = 0; i < 16; ++i) {
        int r = i * 4 + tr;
        t[r][tc] = in[(long)(r0 + r) * C + c0 + tc];
    }
    __syncthreads();
    float sc = (cs ? cs[r0 + tc] : 1.0f) * us;
    #pragma unroll
    for (int i = 0; i < 16; ++i) {
        int r = i * 4 + tr;
        out[(long)(c0 + r) * R + r0 + tc] = f2bfu(t[tc][r] * sc);
    }
}

struct WTArgs {
    const float* src[8];
    unsigned short* dst[8];
    const float* cs[8];
    float sgn[8];
    int R[8], C[8];
};
__global__ __launch_bounds__(256) void tcvt_w_k(WTArgs a)
{
    int wgt = blockIdx.y;
    int R = a.R[wgt], C = a.C[wgt];
    int tilesX = C >> 6;
    int tiles = (R >> 6) * tilesX;
    int t = blockIdx.x;
    if (t >= tiles) return;
    tcvt_body(a.src[wgt], a.dst[wgt], a.cs[wgt], a.sgn[wgt], R, C,
              (t / tilesX) * 64, (t % tilesX) * 64);
}

// ---------------------------------------------------------------------------
// wavelet coeffs (both layers, one launch)
// ---------------------------------------------------------------------------
__global__ void coeff2_k(const float* __restrict__ logits0, const float* __restrict__ gumb0,
                         const float* __restrict__ Wnl0, float* __restrict__ c0,
                         const float* __restrict__ logits1, const float* __restrict__ gumb1,
                         const float* __restrict__ Wnl1, float* __restrict__ c1)
{
    const float* lg = blockIdx.x ? logits1 : logits0;
    const float* gb = blockIdx.x ? gumb1 : gumb0;
    const float* Wn = blockIdx.x ? Wnl1 : Wnl0;
    float* cc = blockIdx.x ? c1 : c0;
    int f = threadIdx.x;
    float l0 = lg[0] + gb[f * 3 + 0];
    float l1 = lg[1] + gb[f * 3 + 1];
    float l2 = lg[2] + gb[f * 3 + 2];
    int bl = 0;
    float bv = l0;
    if (l1 > bv) { bv = l1; bl = 1; }
    if (l2 > bv) { bv = l2; bl = 2; }
    float s = 0.f;
    #pragma unroll
    for (int t = 0; t < 8; ++t) s += Wn[f * 8 + t] * PAT[bl][t];
    cc[f] = s;
}

// ---------------------------------------------------------------------------
// batched vector folds
// ---------------------------------------------------------------------------
struct FVArgs {
    const float* W[6];
    const float* c[6];
    const float* v[6];
    const float* base[6];
    float* out[6];
    int K[6], N[6];
};
__global__ __launch_bounds__(256) void foldvec_k(FVArgs a)
{
    int cs = blockIdx.y;
    int n = blockIdx.x;
    if (n >= a.N[cs]) return;
    int k = threadIdx.x;
    float s = 0.f;
    if (k < a.K[cs]) {
        float cc = a.c[cs] ? a.c[cs][k] : 1.0f;
        s = a.v[cs][k] * cc * a.W[cs][(long)k * a.N[cs] + n];
    }
    __shared__ float sm[256];
    sm[threadIdx.x] = s;
    __syncthreads();
    for (int o = 128; o > 0; o >>= 1) {
        if (threadIdx.x < o) sm[threadIdx.x] += sm[threadIdx.x + o];
        __syncthreads();
    }
    if (threadIdx.x == 0)
        a.out[cs][n] = (a.base[cs] ? a.base[cs][n] : 0.f) + sm[0];
}

// ---------------------------------------------------------------------------
// batched weight folds (transposed bf16 out, M=64 rows, K=256 fixed)
// ---------------------------------------------------------------------------
struct WFArgs {
    const float* Wsrc[4];
    const float* Wbig[4];
    const float* c[4];
    int incl[4], N[4];
    unsigned short* dst[4];
};
__global__ __launch_bounds__(256) void wfold_k(WFArgs a)
{
    int cs = blockIdx.y;
    int m = blockIdx.x;
    __shared__ float ws[256];
    const float* c = a.c[cs];
    ws[threadIdx.x] = a.Wsrc[cs][m * 256 + threadIdx.x] * (c ? c[threadIdx.x] : 1.0f);
    __syncthreads();
    int n = threadIdx.x;
    int N = a.N[cs];
    if (n >= N) return;
    float s = a.incl[cs] ? a.Wsrc[cs][m * 256 + n] : 0.f;
    const float* Wb = a.Wbig[cs];
    #pragma unroll 8
    for (int k = 0; k < 256; ++k)
        s += ws[k] * Wb[(long)k * N + n];
    a.dst[cs][n * 64 + m] = f2bfu(s);
}

// ---------------------------------------------------------------------------
// sc kernels
// ---------------------------------------------------------------------------
__global__ __launch_bounds__(256) void sc0_k(
    const float* __restrict__ partial, int np, float inv_n,
    unsigned short* __restrict__ Wa,   // 16384 *= th0
    unsigned short* __restrict__ Wb,   // 16384 *= om0
    const float* __restrict__ bg0p, const float* __restrict__ brg0p,
    const float* __restrict__ crow0, float* __restrict__ cv0)
{
    __shared__ float red[256];
    float th = block_th(partial, np, inv_n, red, threadIdx.x);
    float om = 1.f - th;
    int g = blockIdx.x * 256 + threadIdx.x;
    Wa[g] = f2bfu(th * bf2f(Wa[g]));
    Wb[g] = f2bfu(om * bf2f(Wb[g]));
    if (g < 256) cv0[g] = th * bg0p[g] + om * brg0p[g] + crow0[g];
}

// sc1 (grid 256): th1-scale Wg1T (65536) and Wg0pT; build Wcomb = th1*Wrg0p(om0)
// + om1*Wrw0; om1-scale WrwWg1 in place; fold bv1g, bw1s.
__global__ __launch_bounds__(256) void sc1_k(
    const float* __restrict__ partial, int np, float inv_n,
    unsigned short* __restrict__ Wg1T,
    const unsigned short* __restrict__ Wrw0T, const unsigned short* __restrict__ Wrg0pT,
    unsigned short* __restrict__ WcombT,
    unsigned short* __restrict__ Wg0pT,
    unsigned short* __restrict__ WrwWg1T,
    const float* __restrict__ bg1, const float* __restrict__ brw0,
    const float* __restrict__ cv0, const float* __restrict__ bw1v,
    float* __restrict__ bv1g, float* __restrict__ bw1s)
{
    __shared__ float red[256];
    float th = block_th(partial, np, inv_n, red, threadIdx.x);
    float om = 1.f - th;
    int g = blockIdx.x * 256 + threadIdx.x;
    Wg1T[g] = f2bfu(th * bf2f(Wg1T[g]));
    if (g < 16384) {
        WcombT[g]  = f2bfu(th * bf2f(Wrg0pT[g]) + om * bf2f(Wrw0T[g]));
        Wg0pT[g]   = f2bfu(th * bf2f(Wg0pT[g]));
        WrwWg1T[g] = f2bfu(om * bf2f(WrwWg1T[g]));
    }
    if (g < 256) {
        bv1g[g] = bg1[g] + om * brw0[g] + th * cv0[g];
        bw1s[g] = om * bw1v[g];
    }
}

__global__ __launch_bounds__(256) void sc2_k(
    const float* __restrict__ partial, int np, float inv_n,
    unsigned short* __restrict__ Wc1T,    // 16384 *= th2
    unsigned short* __restrict__ Wrgc1T,  // 4096  *= om2
    const float* __restrict__ brgc1, const float* __restrict__ crow1,
    float* __restrict__ cv2)
{
    __shared__ float red[256];
    float th = block_th(partial, np, inv_n, red, threadIdx.x);
    float om = 1.f - th;
    int g = blockIdx.x * 256 + threadIdx.x;
    Wc1T[g] = f2bfu(th * bf2f(Wc1T[g]));
    if (g < 4096) Wrgc1T[g] = f2bfu(om * bf2f(Wrgc1T[g]));
    if (g < 64) cv2[g] = om * brgc1[g] + crow1[g];
}

// ---------------------------------------------------------------------------
// Rbf producer: C = A@B + bias, row-major AND per-batch transposed (1 K-step).
// ---------------------------------------------------------------------------
template<int BM, int BN, int FM, int FN>
__global__ __launch_bounds__(256) void gemm_res_k(
    const __hip_bfloat16* __restrict__ A, const __hip_bfloat16* __restrict__ Bt,
    const float* __restrict__ bias,
    __hip_bfloat16* __restrict__ Cb, __hip_bfloat16* __restrict__ CbT,
    int M, int N, int K)
{
    __shared__ __attribute__((aligned(128))) char lds[(BM + BN) * 128];
    char* AsB = lds;
    char* BsB = lds + BM * 128;

    const int m0 = blockIdx.y * BM;
    const int tid  = threadIdx.x;
    const int wave = tid >> 6;
    const int lane = tid & 63;
    const int wn = wave & 1;

    f32x4 acc[FM][FN];
    #pragma unroll
    for (int i = 0; i < FM; ++i)
        #pragma unroll
        for (int j = 0; j < FN; ++j)
            acc[i][j] = (f32x4){0.f, 0.f, 0.f, 0.f};

    for (int k0 = 0; k0 < K; k0 += 64) {
        stage_tiles<BM, BN>(A, Bt, AsB, BsB, m0, 0, k0, K, K, wave, lane);
        __syncthreads();
        mfma_tiles<BM, BN, FM, FN>(AsB, BsB, acc, wave, lane);
        __syncthreads();
    }

    const int lc = lane & 15;
    #pragma unroll
    for (int j = 0; j < FN; ++j) {
        float bv = bias[wn * (FN * 16) + j * 16 + lc];
        #pragma unroll
        for (int i = 0; i < FM; ++i)
            #pragma unroll
            for (int r = 0; r < 4; ++r)
                acc[i][j][r] += bv;
    }
    write_tile<BM, BN, FM, FN>(lds, acc, Cb, (long)m0 * N, N, tid);
    long baseT = (long)(m0 / NN) * ((long)N * NN) + (m0 % NN);
    write_tileT<BM, BN, FM, FN>(lds, acc, CbT, baseT, NN, tid);
}

// ---------------------------------------------------------------------------
// Batched pipelined GEMM with XCD-grouped block swizzle.
// ---------------------------------------------------------------------------
template<int BM, int BN, int FM, int FN, int GX, int NB, int NS>
__global__ __launch_bounds__(256) void gemm_bt_swz_k(
    const __hip_bfloat16* __restrict__ A, const __hip_bfloat16* __restrict__ Bt,
    __hip_bfloat16* __restrict__ Cb,
    int M, int N, int K, long sA, long sB, long sC)
{
    __shared__ __attribute__((aligned(128))) char lds[2 * (BM + BN) * 128];

    const int d   = blockIdx.x;
    const int xcd = d & 7;
    const int q   = d >> 3;
    const int t   = q % NB;
    const int bz  = xcd + ((q / NB) << 3);
    const int n0  = (t % GX) * BN;
    const int m0  = (t / GX) * BM;

    const __hip_bfloat16* Ab = A + (long)bz * sA;
    const __hip_bfloat16* Bb = Bt + (long)bz * sB;

    const int tid  = threadIdx.x;
    const int wave = tid >> 6;
    const int lane = tid & 63;

    f32x4 acc[FM][FN];
    #pragma unroll
    for (int i = 0; i < FM; ++i)
        #pragma unroll
        for (int j = 0; j < FN; ++j)
            acc[i][j] = (f32x4){0.f, 0.f, 0.f, 0.f};

    const __hip_bfloat16* pA[NS];
    const __hip_bfloat16* pB[NS];
    int pK[NS], pk0[NS];
    #pragma unroll
    for (int s = 0; s < NS; ++s) { pA[s] = Ab; pB[s] = Bb; pK[s] = K; pk0[s] = s * 64; }

    pipe_run<BM, BN, FM, FN, NS, NS>(pA, pB, pK, pk0,
                                     lds, lds + (BM + BN) * 128,
                                     acc, acc, m0, n0, wave, lane);

    write_tile<BM, BN, FM, FN>(lds, acc, Cb, (long)bz * sC + (long)m0 * N + n0, N, tid);
}

// ---------------------------------------------------------------------------
// dual1_k (D0): ONE accumulator, pair-swizzled, pipelined (2 steps).
// ---------------------------------------------------------------------------
template<int BM, int BN, int FM, int FN>
__global__ __launch_bounds__(256) void dual1_k(
    const __hip_bfloat16* __restrict__ A0, const __hip_bfloat16* __restrict__ B0, int K0,
    const __hip_bfloat16* __restrict__ A1, const __hip_bfloat16* __restrict__ B1, int K1,
    const float* __restrict__ b1, const float* __restrict__ b2,
    float* __restrict__ partial, int M, int N)
{
    __shared__ __attribute__((aligned(128))) char lds[2 * (BM + BN) * 128];

    const int d   = blockIdx.x;
    const int q   = d >> 3;
    const int nx  = q & 1;
    const int my  = (d & 7) + ((q >> 1) << 3);
    const int m0  = my * BM;
    const int n0  = nx * BN;

    const int tid  = threadIdx.x;
    const int wave = tid >> 6;
    const int lane = tid & 63;
    const int wn = wave & 1;

    f32x4 acc[FM][FN];
    #pragma unroll
    for (int i = 0; i < FM; ++i)
        #pragma unroll
        for (int j = 0; j < FN; ++j)
            acc[i][j] = (f32x4){0.f, 0.f, 0.f, 0.f};

    const __hip_bfloat16* pA[2] = {A0, A1};
    const __hip_bfloat16* pB[2] = {B0, B1};
    int pK[2] = {K0, K1};
    int pk0[2] = {0, 0};
    pipe_run<BM, BN, FM, FN, 2, 2>(pA, pB, pK, pk0,
                                   lds, lds + (BM + BN) * 128,
                                   acc, acc, m0, n0, wave, lane);

    const int lc = lane & 15;
    float dsum = 0.f;
    #pragma unroll
    for (int j = 0; j < FN; ++j) {
        int col = n0 + wn * (FN * 16) + j * 16 + lc;
        float bd = b1[col] - b2[col];
        #pragma unroll
        for (int i = 0; i < FM; ++i)
            #pragma unroll
            for (int r = 0; r < 4; ++r) {
                float dd = acc[i][j][r] + bd;
                dsum += dd * dd;
            }
    }

    float* red = (float*)lds;
    red[tid] = dsum;
    __syncthreads();
    for (int o = 128; o > 0; o >>= 1) {
        if (tid < o) red[tid] += red[tid + o];
        __syncthreads();
    }
    if (tid == 0) partial[my * 2 + nx] = red[0];
}

// ---------------------------------------------------------------------------
// wave2T_k (W0): 3 pipelined steps {acc0,acc0,acc1}; writes C1 transposed.
// ---------------------------------------------------------------------------
template<int BM, int BN, int FM, int FN>
__global__ __launch_bounds__(256) void wave2T_k(
    const __hip_bfloat16* __restrict__ A0, const __hip_bfloat16* __restrict__ B0, int K0,
    const __hip_bfloat16* __restrict__ A1, const __hip_bfloat16* __restrict__ B1, int K1,
    const __hip_bfloat16* __restrict__ A2, const __hip_bfloat16* __restrict__ B2, int K2,
    const float* __restrict__ cv, const float* __restrict__ b2v,
    __hip_bfloat16* __restrict__ C1T, float* __restrict__ partial_out, int M, int N)
{
    __shared__ __attribute__((aligned(128))) char lds[2 * (BM + BN) * 128];

    const int d   = blockIdx.x;
    const int q   = d >> 3;
    const int nx  = q & 1;
    const int my  = (d & 7) + ((q >> 1) << 3);
    const int m0  = my * BM;
    const int n0  = nx * BN;

    const int tid  = threadIdx.x;
    const int wave = tid >> 6;
    const int lane = tid & 63;
    const int wn = wave & 1;

    f32x4 acc0[FM][FN], acc1[FM][FN];
    #pragma unroll
    for (int i = 0; i < FM; ++i)
        #pragma unroll
        for (int j = 0; j < FN; ++j) {
            acc0[i][j] = (f32x4){0.f, 0.f, 0.f, 0.f};
            acc1[i][j] = (f32x4){0.f, 0.f, 0.f, 0.f};
        }

    const __hip_bfloat16* pA[3] = {A0, A1, A2};
    const __hip_bfloat16* pB[3] = {B0, B1, B2};
    int pK[3] = {K0, K1, K2};
    int pk0[3] = {0, 0, 0};
    pipe_run<BM, BN, FM, FN, 3, 2>(pA, pB, pK, pk0,
                                   lds, lds + (BM + BN) * 128,
                                   acc0, acc1, m0, n0, wave, lane);

    const int lc = lane & 15;
    float dsum = 0.f;
    #pragma unroll
    for (int j = 0; j < FN; ++j) {
        int col = n0 + wn * (FN * 16) + j * 16 + lc;
        float c1 = cv[col];
        float c2 = b2v[col];
        #pragma unroll
        for (int i = 0; i < FM; ++i)
            #pragma unroll
            for (int r = 0; r < 4; ++r) {
                float v1 = acc0[i][j][r] + c1;
                float v2 = acc1[i][j][r] + c2;
                acc0[i][j][r] = v1;
                float dd = v1 - v2;
                dsum += dd * dd;
            }
    }

    float* red = (float*)lds;
    red[tid] = dsum;
    __syncthreads();
    for (int o = 128; o > 0; o >>= 1) {
        if (tid < o) red[tid] += red[tid + o];
        __syncthreads();
    }
    if (tid == 0) partial_out[my * 2 + nx] = red[0];

    long baseT = (long)(m0 / NN) * ((long)N * NN) + (long)n0 * NN + (m0 % NN);
    write_tileT<BM, BN, FM, FN>(lds, acc0, C1T, baseT, NN, tid);
}

// ---------------------------------------------------------------------------
// gmix5_k: 5-phase pipelined (8 steps: 4xT1x@Wg1, Radj@WrwWg1, T0@Wg0p,
// Rbf@Wcomb -> acc0; Rbf@Wrg1 -> acc1) + rank-1 epilogue.
// ---------------------------------------------------------------------------
template<int BM, int BN, int FM, int FN>
__global__ __launch_bounds__(256) void gmix5_k(
    const __hip_bfloat16* __restrict__ A0, const __hip_bfloat16* __restrict__ B0, int K0,
    const __hip_bfloat16* __restrict__ A1, const __hip_bfloat16* __restrict__ B1, int K1,
    const __hip_bfloat16* __restrict__ A2, const __hip_bfloat16* __restrict__ B2, int K2,
    const __hip_bfloat16* __restrict__ A3, const __hip_bfloat16* __restrict__ B3, int K3,
    const __hip_bfloat16* __restrict__ A4, const __hip_bfloat16* __restrict__ B4, int K4,
    const float* __restrict__ bv1, const float* __restrict__ b2v,
    const float* __restrict__ ars, const float* __restrict__ bw1s,
    __hip_bfloat16* __restrict__ C1, float* __restrict__ partial_out, int M, int N)
{
    __shared__ __attribute__((aligned(128))) char lds[2 * (BM + BN) * 128];

    const int d  = blockIdx.x;
    const int q  = d >> 3;
    const int nx = q & 1;
    const int my = (d & 7) + ((q >> 1) << 3);
    const int m0 = my * BM;
    const int n0 = nx * BN;

    const int tid  = threadIdx.x;
    const int wave = tid >> 6;
    const int lane = tid & 63;
    const int wm = wave >> 1, wn = wave & 1;

    f32x4 acc0[FM][FN], acc1[FM][FN];
    #pragma unroll
    for (int i = 0; i < FM; ++i)
        #pragma unroll
        for (int j = 0; j < FN; ++j) {
            acc0[i][j] = (f32x4){0.f, 0.f, 0.f, 0.f};
            acc1[i][j] = (f32x4){0.f, 0.f, 0.f, 0.f};
        }

    const __hip_bfloat16* pA[8] = {A0, A0, A0, A0, A1, A2, A3, A4};
    const __hip_bfloat16* pB[8] = {B0, B0, B0, B0, B1, B2, B3, B4};
    int pK[8]  = {K0, K0, K0, K0, K1, K2, K3, K4};
    int pk0[8] = {0, 64, 128, 192, 0, 0, 0, 0};
    pipe_run<BM, BN, FM, FN, 8, 7>(pA, pB, pK, pk0,
                                   lds, lds + (BM + BN) * 128,
                                   acc0, acc1, m0, n0, wave, lane);

    const int lc  = lane & 15;
    const int lr4 = (lane >> 4) << 2;
    const int node0 = m0 & (NN - 1);
    float dsum = 0.f;
    #pragma unroll
    for (int j = 0; j < FN; ++j) {
        int col = n0 + wn * (FN * 16) + j * 16 + lc;
        float c1 = bv1[col];
        float c2 = b2v[col];
        float bw = bw1s[col];
        #pragma unroll
        for (int i = 0; i < FM; ++i) {
            int rowl = wm * (FM * 16) + i * 16 + lr4;
            #pragma unroll
            for (int r = 0; r < 4; ++r) {
                float av = ars[node0 + rowl + r];
                float v1 = acc0[i][j][r] + c1 + av * bw;
                float v2 = acc1[i][j][r] + c2;
                acc0[i][j][r] = v1;
                float dd = v1 - v2;
                dsum += dd * dd;
            }
        }
    }

    float* red = (float*)lds;
    red[tid] = dsum;
    __syncthreads();
    for (int o = 128; o > 0; o >>= 1) {
        if (tid < o) red[tid] += red[tid + o];
        __syncthreads();
    }
    if (tid == 0) partial_out[my * 2 + nx] = red[0];

    write_tile<BM, BN, FM, FN>(lds, acc0, C1, (long)m0 * N + n0, N, tid);
}

// ---------------------------------------------------------------------------
// wave2_k (F): 6 pipelined steps (4+1 -> acc0, 1 -> acc1), plain grid.
// ---------------------------------------------------------------------------
template<int BM, int BN, int FM, int FN>
__global__ __launch_bounds__(256) void wave2_k(
    const __hip_bfloat16* __restrict__ A0, const __hip_bfloat16* __restrict__ B0, int K0,
    const __hip_bfloat16* __restrict__ A1, const __hip_bfloat16* __restrict__ B1, int K1,
    const __hip_bfloat16* __restrict__ A2, const __hip_bfloat16* __restrict__ B2, int K2,
    const float* __restrict__ cv, const float* __restrict__ b2v,
    __hip_bfloat16* __restrict__ C1, __hip_bfloat16* __restrict__ C2,
    float* __restrict__ partial_out, int M, int N)
{
    __shared__ __attribute__((aligned(128))) char lds[2 * (BM + BN) * 128];

    const int m0 = blockIdx.y * BM;
    const int n0 = blockIdx.x * BN;
    const int pidx = blockIdx.y * gridDim.x + blockIdx.x;

    const int tid  = threadIdx.x;
    const int wave = tid >> 6;
    const int lane = tid & 63;
    const int wn = wave & 1;

    f32x4 acc0[FM][FN], acc1[FM][FN];
    #pragma unroll
    for (int i = 0; i < FM; ++i)
        #pragma unroll
        for (int j = 0; j < FN; ++j) {
            acc0[i][j] = (f32x4){0.f, 0.f, 0.f, 0.f};
            acc1[i][j] = (f32x4){0.f, 0.f, 0.f, 0.f};
        }

    const __hip_bfloat16* pA[6] = {A0, A0, A0, A0, A1, A2};
    const __hip_bfloat16* pB[6] = {B0, B0, B0, B0, B1, B2};
    int pK[6]  = {K0, K0, K0, K0, K1, K2};
    int pk0[6] = {0, 64, 128, 192, 0, 0};
    pipe_run<BM, BN, FM, FN, 6, 5>(pA, pB, pK, pk0,
                                   lds, lds + (BM + BN) * 128,
                                   acc0, acc1, m0, n0, wave, lane);

    const int lc = lane & 15;
    float dsum = 0.f;
    #pragma unroll
    for (int j = 0; j < FN; ++j) {
        int col = n0 + wn * (FN * 16) + j * 16 + lc;
        float c1 = cv[col];
        float c2 = b2v[col];
        #pragma unroll
        for (int i = 0; i < FM; ++i)
            #pragma unroll
            for (int r = 0; r < 4; ++r) {
                float v1 = acc0[i][j][r] + c1;
                float v2 = acc1[i][j][r] + c2;
                acc0[i][j][r] = v1;
                acc1[i][j][r] = v2;
                float dd = v1 - v2;
                dsum += dd * dd;
            }
    }

    float* red = (float*)lds;
    red[tid] = dsum;
    __syncthreads();
    for (int o = 128; o > 0; o >>= 1) {
        if (tid < o) red[tid] += red[tid + o];
        __syncthreads();
    }
    if (tid == 0) partial_out[pidx] = red[0];

    write_tile<BM, BN, FM, FN>(lds, acc0, C1, (long)m0 * N + n0, N, tid);
    write_tile<BM, BN, FM, FN>(lds, acc1, C2, (long)m0 * N + n0, N, tid);
}

// ---------------------------------------------------------------------------
// final mix (th in-kernel): out = th*h + (1-th)*r, fp32 out
// ---------------------------------------------------------------------------
__global__ __launch_bounds__(256) void mixfinal_k(
    const unsigned short* __restrict__ h, const unsigned short* __restrict__ r,
    const float* __restrict__ partial_in, int np_in, float inv_in,
    float* __restrict__ out, long n4)
{
    __shared__ float sm[256];
    const float th = block_th(partial_in, np_in, inv_in, sm, (int)threadIdx.x);
    const float om = 1.f - th;
    long gid = (long)blockIdx.x * 256 + threadIdx.x;
    long stride = (long)gridDim.x * 256;
    for (long i = gid; i < n4; i += stride) {
        ushort4 hv = reinterpret_cast<const ushort4*>(h)[i];
        ushort4 rv = reinterpret_cast<const ushort4*>(r)[i];
        float4 o;
        o.x = th * bf2f(hv.x) + om * bf2f(rv.x);
        o.y = th * bf2f(hv.y) + om * bf2f(rv.y);
        o.z = th * bf2f(hv.z) + om * bf2f(rv.z);
        o.w = th * bf2f(hv.w) + om * bf2f(rv.w);
        reinterpret_cast<float4*>(out)[i] = o;
    }
}

// ---------------------------------------------------------------------------
extern "C" void kernel_launch(void* const* d_in, const int* in_sizes, int n_in,
                              void* d_out, int out_size, void* d_ws, size_t ws_size,
                              hipStream_t stream)
{
    const float* x       = (const float*)d_in[0];
    const float* adj     = (const float*)d_in[1];
    const float* Wres    = (const float*)d_in[2];
    const float* bres    = (const float*)d_in[3];
    const float* Wg0     = (const float*)d_in[4];
    const float* bg0     = (const float*)d_in[5];
    const float* Wrg0    = (const float*)d_in[6];
    const float* brg0    = (const float*)d_in[7];
    const float* logits0 = (const float*)d_in[8];
    const float* gumb0   = (const float*)d_in[9];
    const float* Wnl0    = (const float*)d_in[10];
    const float* bnl0    = (const float*)d_in[11];
    const float* Wwo0    = (const float*)d_in[12];
    const float* bwo0    = (const float*)d_in[13];
    const float* Wrw0    = (const float*)d_in[14];
    const float* brw0    = (const float*)d_in[15];
    const float* Wg1     = (const float*)d_in[16];
    const float* bg1     = (const float*)d_in[17];
    const float* Wrg1    = (const float*)d_in[18];
    const float* brg1    = (const float*)d_in[19];
    const float* logits1 = (const float*)d_in[20];
    const float* gumb1   = (const float*)d_in[21];
    const float* Wnl1    = (const float*)d_in[22];
    const float* bnl1    = (const float*)d_in[23];
    const float* Wwo1    = (const float*)d_in[24];
    const float* bwo1    = (const float*)d_in[25];
    const float* Wrw1    = (const float*)d_in[26];
    const float* brw1    = (const float*)d_in[27];

    float* out = (float*)d_out;

    // ---- workspace ----
    char* w = (char*)d_ws;
    auto alloc = [&](long bytes) { char* p = w; w += (bytes + 255) & ~255L; return p; };
    const long SLOT = (long)BNR * HH * 2;                 // 32 MB
    char* pool = alloc(5 * SLOT);                         // 160 MB
    __hip_bfloat16* Rbf  = (__hip_bfloat16*)alloc((long)BNR * DOUT * 2); // 8 MB
    __hip_bfloat16* adjb = (__hip_bfloat16*)alloc((long)NN * NN * 2);
    __hip_bfloat16* WT   = (__hip_bfloat16*)alloc(225280L * 2);
    float* partial0 = (float*)alloc(2048 * 4);
    float* partial1 = (float*)alloc(2048 * 4);
    float* partial2 = (float*)alloc(2048 * 4);
    float* partial3 = (float*)alloc(2048 * 4);
    float* c0      = (float*)alloc(256 * 4);
    float* c1      = (float*)alloc(256 * 4);
    float* bg0p    = (float*)alloc(256 * 4);
    float* brg0p   = (float*)alloc(256 * 4);
    float* crow0   = (float*)alloc(256 * 4);
    float* brgc1   = (float*)alloc(64 * 4);
    float* crow1   = (float*)alloc(64 * 4);
    float* cv0     = (float*)alloc(256 * 4);
    float* bv1g    = (float*)alloc(256 * 4);
    float* cv2     = (float*)alloc(64 * 4);
    float* ars     = (float*)alloc(512 * 4);
    float* bw1v    = (float*)alloc(256 * 4);
    float* bw1s    = (float*)alloc(256 * 4);

    auto S = [&](int i) { return pool + (long)i * SLOT; };
    __hip_bfloat16* xwrT = (__hip_bfloat16*)S(0);
    __hip_bfloat16* orw  = (__hip_bfloat16*)S(1);
    __hip_bfloat16* rw1  = (__hip_bfloat16*)(S(1) + (long)BNR * DOUT * 2);
    __hip_bfloat16* Radj = (__hip_bfloat16*)(S(1) + 2L * BNR * DOUT * 2);
    __hip_bfloat16* xg1  = (__hip_bfloat16*)S(2);
    __hip_bfloat16* T1x  = (__hip_bfloat16*)S(3);
    __hip_bfloat16* xbf  = (__hip_bfloat16*)S(4);
    __hip_bfloat16* xT   = (__hip_bfloat16*)(S(4) + (long)BNR * DIN * 2);
    __hip_bfloat16* T0   = (__hip_bfloat16*)(S(4) + 2L * BNR * DIN * 2);
    __hip_bfloat16* RbfT = (__hip_bfloat16*)(S(4) + 3L * BNR * DIN * 2);

    // transposed weights inside WT (element offsets)
    __hip_bfloat16* WresT   = WT;             // 64x64
    __hip_bfloat16* Wg0T    = WT + 4096;      // 256x64
    __hip_bfloat16* Wrg0T   = WT + 20480;     // 256x64  (NEGATED at prep)
    __hip_bfloat16* Wrw0T   = WT + 36864;     // 256x64
    __hip_bfloat16* Wg1T    = WT + 53248;     // 256x256 (th1 by sc1)
    __hip_bfloat16* Wrg1T   = WT + 118784;    // 256x64
    __hip_bfloat16* Wc1T    = WT + 135168;    // 64x256 (c1-scaled Wwo1^T; th2 by sc2)
    __hip_bfloat16* Wrw1T   = WT + 151552;    // 64x64
    __hip_bfloat16* Wg0pT   = WT + 155648;    // 256x64 (Wg0@(I+Wc0))^T; th0 sc0; th1 sc1
    __hip_bfloat16* Wrg0pT  = WT + 172032;    // 256x64 (Wrg0@(I+Wc0))^T; om0 sc0
    __hip_bfloat16* Wrgc1T  = WT + 188416;    // 64x64  (Wrg1@Wc1)^T; om2 sc2
    __hip_bfloat16* WcombT  = WT + 192512;    // 256x64 (th1*om0*Wrg0p + om1*Wrw0)^T by sc1
    __hip_bfloat16* WrwWg1T = WT + 208896;    // 256x64 (Wrw0@Wg1)^T; om1 by sc1

    const dim3 blk(256);
    const float invH = 1.0f / ((float)BNR * HH);
    const float invD = 1.0f / ((float)BNR * DOUT);

    // ---- prep ----
    hipLaunchKernelGGL(coeff2_k, dim3(2), dim3(256), 0, stream,
                       logits0, gumb0, Wnl0, c0, logits1, gumb1, Wnl1, c1);
    hipLaunchKernelGGL(cvta_k, dim3(NN), blk, 0, stream, adj, (unsigned int*)adjb, ars);
    hipLaunchKernelGGL(cvtx_k, dim3(1, 8, BB), blk, 0, stream, x,
                       (unsigned short*)xbf, (unsigned short*)xT);

    WTArgs wa;
    wa.src[0] = Wres; wa.dst[0] = (unsigned short*)WresT; wa.cs[0] = nullptr; wa.sgn[0] = 1.f;  wa.R[0] = 64;  wa.C[0] = 64;
    wa.src[1] = Wg0;  wa.dst[1] = (unsigned short*)Wg0T;  wa.cs[1] = nullptr; wa.sgn[1] = 1.f;  wa.R[1] = 64;  wa.C[1] = 256;
    wa.src[2] = Wrg0; wa.dst[2] = (unsigned short*)Wrg0T; wa.cs[2] = nullptr; wa.sgn[2] = -1.f; wa.R[2] = 64;  wa.C[2] = 256;
    wa.src[3] = Wrw0; wa.dst[3] = (unsigned short*)Wrw0T; wa.cs[3] = nullptr; wa.sgn[3] = 1.f;  wa.R[3] = 64;  wa.C[3] = 256;
    wa.src[4] = Wg1;  wa.dst[4] = (unsigned short*)Wg1T;  wa.cs[4] = nullptr; wa.sgn[4] = 1.f;  wa.R[4] = 256; wa.C[4] = 256;
    wa.src[5] = Wrg1; wa.dst[5] = (unsigned short*)Wrg1T; wa.cs[5] = nullptr; wa.sgn[5] = 1.f;  wa.R[5] = 64;  wa.C[5] = 256;
    wa.src[6] = Wwo1; wa.dst[6] = (unsigned short*)Wc1T;  wa.cs[6] = c1;      wa.sgn[6] = 1.f;  wa.R[6] = 256; wa.C[6] = 64;
    wa.src[7] = Wrw1; wa.dst[7] = (unsigned short*)Wrw1T; wa.cs[7] = nullptr; wa.sgn[7] = 1.f;  wa.R[7] = 64;  wa.C[7] = 64;
    hipLaunchKernelGGL(tcvt_w_k, dim3(16, 8), blk, 0, stream, wa);

    WFArgs wf;
    wf.Wsrc[0] = Wg0;  wf.Wbig[0] = Wwo0; wf.c[0] = c0;      wf.incl[0] = 1; wf.N[0] = 256;
    wf.dst[0] = (unsigned short*)Wg0pT;
    wf.Wsrc[1] = Wrg0; wf.Wbig[1] = Wwo0; wf.c[1] = c0;      wf.incl[1] = 1; wf.N[1] = 256;
    wf.dst[1] = (unsigned short*)Wrg0pT;
    wf.Wsrc[2] = Wrg1; wf.Wbig[2] = Wwo1; wf.c[2] = c1;      wf.incl[2] = 0; wf.N[2] = 64;
    wf.dst[2] = (unsigned short*)Wrgc1T;
    wf.Wsrc[3] = Wrw0; wf.Wbig[3] = Wg1;  wf.c[3] = nullptr; wf.incl[3] = 0; wf.N[3] = 256;
    wf.dst[3] = (unsigned short*)WrwWg1T;
    hipLaunchKernelGGL(wfold_k, dim3(64, 4), blk, 0, stream, wf);

    FVArgs fv;
    fv.W[0] = Wwo0; fv.c[0] = c0;      fv.v[0] = bg0;  fv.base[0] = bg0;     fv.out[0] = bg0p;  fv.K[0] = 256; fv.N[0] = 256;
    fv.W[1] = Wwo0; fv.c[1] = c0;      fv.v[1] = brg0; fv.base[1] = brg0;    fv.out[1] = brg0p; fv.K[1] = 256; fv.N[1] = 256;
    fv.W[2] = Wwo0; fv.c[2] = nullptr; fv.v[2] = bnl0; fv.base[2] = bwo0;    fv.out[2] = crow0; fv.K[2] = 256; fv.N[2] = 256;
    fv.W[3] = Wwo1; fv.c[3] = c1;      fv.v[3] = brg1; fv.base[3] = nullptr; fv.out[3] = brgc1; fv.K[3] = 256; fv.N[3] = 64;
    fv.W[4] = Wwo1; fv.c[4] = nullptr; fv.v[4] = bnl1; fv.base[4] = bwo1;    fv.out[4] = crow1; fv.K[4] = 256; fv.N[4] = 64;
    fv.W[5] = Wg1;  fv.c[5] = nullptr; fv.v[5] = brw0; fv.base[5] = nullptr; fv.out[5] = bw1v;  fv.K[5] = 256; fv.N[5] = 256;
    hipLaunchKernelGGL(foldvec_k, dim3(256, 6), blk, 0, stream, fv);

    // res = x @ Wres + bres -> Rbf + RbfT
    hipLaunchKernelGGL((gemm_res_k<128, 64, 4, 2>), dim3(1, BNR / 128, 1), blk, 0, stream,
                       xbf, WresT, bres, Rbf, RbfT, BNR, DOUT, DIN);

    // T0 = adj @ x (batched, XCD-grouped, pipelined)
    hipLaunchKernelGGL((gemm_bt_swz_k<128, 64, 4, 2, 1, 4, 8>), dim3(BB * 4), blk, 0, stream,
                       adjb, xT, T0, NN, DIN, NN, 0, (long)DIN * NN, (long)NN * DIN);

    // Radj = adj @ Rbf (batched, XCD-grouped, pipelined)
    hipLaunchKernelGGL((gemm_bt_swz_k<128, 64, 4, 2, 1, 4, 8>), dim3(BB * 4), blk, 0, stream,
                       adjb, RbfT, Radj, NN, DOUT, NN, 0, (long)DOUT * NN, (long)NN * DOUT);

    // D0: diff0 partials only (pipelined)
    hipLaunchKernelGGL((dual1_k<64, 128, 2, 4>), dim3(2 * BNR / 64), blk, 0, stream,
                       T0, Wg0T, DIN, Rbf, Wrg0T, DOUT, bg0, brg0, partial0, BNR, HH);

    // sc0
    hipLaunchKernelGGL(sc0_k, dim3(64), blk, 0, stream, partial0, 2048, invH,
                       (unsigned short*)Wg0pT, (unsigned short*)Wrg0pT,
                       bg0p, brg0p, crow0, cv0);

    // W0: xwrT = [T0@(th0*Wg0p) + Rbf@(om0*Wrg0p) + cv0]^T ; diff vs Rbf@Wrw0+brw0
    hipLaunchKernelGGL((wave2T_k<64, 128, 2, 4>), dim3(2 * BNR / 64), blk, 0, stream,
                       T0, Wg0pT, DIN, Rbf, Wrg0pT, DOUT, Rbf, Wrw0T, DOUT,
                       cv0, brw0, xwrT, partial1, BNR, HH);

    // sc1 (builds Wcomb; th1-scales Wg1T, Wg0pT; om1-scales WrwWg1T)
    hipLaunchKernelGGL(sc1_k, dim3(256), blk, 0, stream, partial1, 2048, invH,
                       (unsigned short*)Wg1T,
                       (const unsigned short*)Wrw0T, (const unsigned short*)Wrg0pT,
                       (unsigned short*)WcombT,
                       (unsigned short*)Wg0pT,
                       (unsigned short*)WrwWg1T,
                       bg1, brw0, cv0, bw1v, bv1g, bw1s);

    // T1x = adj @ xwr (batched, XCD-grouped, pipelined; 128x64 tiles)
    hipLaunchKernelGGL((gemm_bt_swz_k<128, 64, 4, 2, 4, 16, 8>), dim3(BB * 16), blk, 0, stream,
                       adjb, xwrT, T1x, NN, HH, NN, 0, (long)HH * NN, (long)NN * HH);

    // gmix5: xg1 (5 MFMA phases pipelined + rank-1), diff2 partials
    hipLaunchKernelGGL((gmix5_k<64, 128, 2, 4>), dim3(2 * BNR / 64), blk, 0, stream,
                       T1x, Wg1T, HH,
                       Radj, WrwWg1T, DOUT,
                       T0, Wg0pT, DIN,
                       Rbf, WcombT, DOUT,
                       Rbf, Wrg1T, DOUT,
                       bv1g, brg1, ars, bw1s, xg1, partial2, BNR, HH);

    // sc2
    hipLaunchKernelGGL(sc2_k, dim3(64), blk, 0, stream, partial2, 2048, invH,
                       (unsigned short*)Wc1T, (unsigned short*)Wrgc1T,
                       brgc1, crow1, cv2);

    // F: orw = xg1@(th2*Wc1) + Rbf@(om2*Wrgc1) + cv2 ; rw1 = Rbf@Wrw1 + brw1
    hipLaunchKernelGGL((wave2_k<64, 64, 2, 2>), dim3(1, BNR / 64), blk, 0, stream,
                       xg1, Wc1T, HH, Rbf, Wrgc1T, DOUT, Rbf, Wrw1T, DIN,
                       cv2, brw1, orw, rw1, partial3, BNR, DOUT);

    // final mix -> fp32 out
    hipLaunchKernelGGL(mixfinal_k, dim3(2048), blk, 0, stream,
                       (const unsigned short*)orw, (const unsigned short*)rw1,
                       partial3, 1024, invD, out, (long)BNR * DOUT / 4);
}

// Round 14
// 161.404 us; speedup vs baseline: 1.4002x; 1.1042x over previous
//
#include <hip/hip_runtime.h>
#include <hip/hip_bf16.h>
#include <math.h>

#define BB   128
#define NN   512
#define DIN  64
#define HH   256
#define DOUT 64
#define BNR  (BB * NN)          // 65536 rows

typedef float  f32x4  __attribute__((ext_vector_type(4)));
typedef __bf16 bf16x8 __attribute__((ext_vector_type(8)));

#define GLP(p)  ((const __attribute__((address_space(1))) void*)(p))
#define LDSP(p) ((__attribute__((address_space(3))) void*)(p))

// Haar/db1 'zero' DWT patterns, levels 1..3, FULL_LEN=8
__constant__ float PAT[3][8] = {
    {0.70710678f, 0.70710678f, 0.f, 0.f, 0.f, 0.f, 0.f, 0.f},
    {0.5f,        0.70710678f, 0.f, 0.5f, 0.f, 0.f, 0.f, 0.f},
    {0.35355339f, 0.70710678f, 0.f, 0.f, 0.f, 0.5f, 0.f, 0.35355339f}
};

__device__ __forceinline__ unsigned short f2bfu(float x) {
    __hip_bfloat16 b = __float2bfloat16(x);
    unsigned short u;
    __builtin_memcpy(&u, &b, 2);
    return u;
}
__device__ __forceinline__ float bf2f(unsigned short u) {
    unsigned int v = ((unsigned int)u) << 16;
    float f;
    __builtin_memcpy(&f, &v, 4);
    return f;
}

// ---------------------------------------------------------------------------
// In-kernel th = sigmoid(mean diff) — same tree order everywhere.
// ---------------------------------------------------------------------------
__device__ __forceinline__ float block_th(const float* __restrict__ partial, int np,
                                          float inv_n, float* red, int tid)
{
    float s = 0.f;
    for (int i = tid; i < np; i += 256) s += partial[i];
    red[tid] = s;
    __syncthreads();
    for (int o = 128; o > 0; o >>= 1) {
        if (tid < o) red[tid] += red[tid + o];
        __syncthreads();
    }
    float th = 1.f / (1.f + expf(-red[0] * inv_n));
    __syncthreads();
    return th;
}

// ---------------------------------------------------------------------------
// Coalesced bf16 tile write via LDS staging (proven round 4). Row-major.
// ---------------------------------------------------------------------------
template<int BM, int BN, int FM, int FN>
__device__ __forceinline__ void write_tile(char* lds, f32x4 (&a)[FM][FN],
                                           __hip_bfloat16* __restrict__ C,
                                           long base, int N, int tid)
{
    const int wave = tid >> 6;
    const int lane = tid & 63;
    const int wm = wave >> 1, wn = wave & 1;
    const int lc = lane & 15;
    const int lr4 = (lane >> 4) << 2;
    __syncthreads();
    #pragma unroll
    for (int j = 0; j < FN; ++j) {
        int colb = (wn * (FN * 16) + j * 16 + lc) * 2;
        #pragma unroll
        for (int i = 0; i < FM; ++i) {
            int row0 = wm * (FM * 16) + i * 16 + lr4;
            #pragma unroll
            for (int r = 0; r < 4; ++r) {
                int row = row0 + r;
                *reinterpret_cast<unsigned short*>(
                    lds + row * (BN * 2) + (colb ^ (((row >> 2) & 3) << 5))) =
                    f2bfu(a[i][j][r]);
            }
        }
    }
    __syncthreads();
    const int TPR = BN / 8;
    const int RPP = 256 / TPR;
    #pragma unroll
    for (int p = 0; p < BM / RPP; ++p) {
        int row = p * RPP + tid / TPR;
        int cb = (tid % TPR) * 16;
        int pb = cb ^ (((row >> 2) & 3) << 5);
        uint4 v = *reinterpret_cast<const uint4*>(lds + row * (BN * 2) + pb);
        *reinterpret_cast<uint4*>(reinterpret_cast<char*>(C + base + (long)row * N) + cb) = v;
    }
}

// ---------------------------------------------------------------------------
// Transposed tile write (proven round 11).
// ---------------------------------------------------------------------------
template<int BM, int BN, int FM, int FN>
__device__ __forceinline__ void write_tileT(char* lds, f32x4 (&a)[FM][FN],
                                            __hip_bfloat16* __restrict__ CT,
                                            long baseT, int ldT, int tid)
{
    const int wave = tid >> 6;
    const int lane = tid & 63;
    const int wm = wave >> 1, wn = wave & 1;
    const int lc = lane & 15;
    const int lr4 = (lane >> 4) << 2;
    __syncthreads();
    #pragma unroll
    for (int j = 0; j < FN; ++j) {
        int c = wn * (FN * 16) + j * 16 + lc;
        int cbase = c * (BM * 2);
        int swz = ((c >> 2) & 3) << 5;
        #pragma unroll
        for (int i = 0; i < FM; ++i) {
            int m0 = wm * (FM * 16) + i * 16 + lr4;
            #pragma unroll
            for (int r = 0; r < 4; ++r) {
                int m = m0 + r;
                *reinterpret_cast<unsigned short*>(lds + cbase + ((m * 2) ^ swz)) =
                    f2bfu(a[i][j][r]);
            }
        }
    }
    __syncthreads();
    const int TPR = BM / 8;
    const int RPP = 256 / TPR;
    #pragma unroll
    for (int p = 0; p < BN / RPP; ++p) {
        int c = p * RPP + tid / TPR;
        int tb = (tid % TPR) * 16;
        int pb = tb ^ (((c >> 2) & 3) << 5);
        uint4 v = *reinterpret_cast<const uint4*>(lds + c * (BM * 2) + pb);
        *reinterpret_cast<uint4*>(reinterpret_cast<char*>(CT + baseT + (long)c * ldT) + tb) = v;
    }
}

// ---------------------------------------------------------------------------
// staging of one K=64 slab of A(BM rows) + B(BN rows) into swizzled LDS
// ---------------------------------------------------------------------------
template<int BM, int BN>
__device__ __forceinline__ void stage_tiles(const __hip_bfloat16* __restrict__ Ab,
                                            const __hip_bfloat16* __restrict__ Bb,
                                            char* AsB, char* BsB,
                                            int m0, int n0, int k0, int KA, int KB,
                                            int wave, int lane)
{
    const int NCH = (BM + BN) / 32;
    const int lr = lane >> 3;
    const int ls = lane & 7;
    #pragma unroll
    for (int cc = 0; cc < NCH; ++cc) {
        int c = wave * NCH + cc;
        const __hip_bfloat16* src;
        char* ldsb;
        if (c < BM / 8) {
            int r = c * 8 + lr;
            ldsb = AsB + c * 1024;
            src = Ab + ((long)(m0 + r) * KA + k0 + ((ls ^ (r & 7)) << 3));
        } else {
            int c2 = c - BM / 8;
            int r = c2 * 8 + lr;
            ldsb = BsB + c2 * 1024;
            src = Bb + ((long)(n0 + r) * KB + k0 + ((ls ^ (r & 7)) << 3));
        }
        __builtin_amdgcn_global_load_lds(GLP(src), LDSP(ldsb), 16, 0, 0);
    }
}

template<int BM, int BN, int FM, int FN>
__device__ __forceinline__ void mfma_tiles(char* AsB, char* BsB,
                                           f32x4 (&acc)[FM][FN], int wave, int lane)
{
    const int wm = wave >> 1, wn = wave & 1;
    #pragma unroll
    for (int ksl = 0; ksl < 2; ++ksl) {
        bf16x8 af[FM], bfr[FN];
        #pragma unroll
        for (int i = 0; i < FM; ++i) {
            int row = wm * (FM * 16) + i * 16 + (lane & 15);
            int off = (ksl * 64 + ((lane >> 4) << 4)) ^ ((row & 7) << 4);
            af[i] = *reinterpret_cast<const bf16x8*>(AsB + row * 128 + off);
        }
        #pragma unroll
        for (int j = 0; j < FN; ++j) {
            int row = wn * (FN * 16) + j * 16 + (lane & 15);
            int off = (ksl * 64 + ((lane >> 4) << 4)) ^ ((row & 7) << 4);
            bfr[j] = *reinterpret_cast<const bf16x8*>(BsB + row * 128 + off);
        }
        #pragma unroll
        for (int i = 0; i < FM; ++i)
            #pragma unroll
            for (int j = 0; j < FN; ++j)
                acc[i][j] = __builtin_amdgcn_mfma_f32_16x16x32_bf16(
                    af[i], bfr[j], acc[i][j], 0, 0, 0);
    }
}

// ---------------------------------------------------------------------------
// Pipelined multi-step runner (round-13 proven: __syncthreads only).
// ---------------------------------------------------------------------------
template<int BM, int BN, int FM, int FN, int NS, int NA>
__device__ __forceinline__ void pipe_run(
    const __hip_bfloat16* const (&sA)[NS], const __hip_bfloat16* const (&sB)[NS],
    const int (&sK)[NS], const int (&sk0)[NS],
    char* buf0, char* buf1,
    f32x4 (&acc0)[FM][FN], f32x4 (&acc1)[FM][FN],
    int m0, int n0, int wave, int lane)
{
    constexpr int BOFF = BM * 128;
    stage_tiles<BM, BN>(sA[0], sB[0], buf0, buf0 + BOFF, m0, n0, sk0[0],
                        sK[0], sK[0], wave, lane);
    __syncthreads();
    #pragma unroll
    for (int t = 0; t < NS; ++t) {
        char* bc = (t & 1) ? buf1 : buf0;
        if (t + 1 < NS) {
            char* bn = (t & 1) ? buf0 : buf1;
            stage_tiles<BM, BN>(sA[t + 1], sB[t + 1], bn, bn + BOFF, m0, n0,
                                sk0[t + 1], sK[t + 1], sK[t + 1], wave, lane);
        }
        if (t < NA) mfma_tiles<BM, BN, FM, FN>(bc, bc + BOFF, acc0, wave, lane);
        else        mfma_tiles<BM, BN, FM, FN>(bc, bc + BOFF, acc1, wave, lane);
        __syncthreads();
    }
}

// ---------------------------------------------------------------------------
// transpose-convert fp32 (R,C) -> bf16 (C,R), optional per-src-row scale + sign
// ---------------------------------------------------------------------------
__device__ __forceinline__ void tcvt_body(const float* __restrict__ in,
                                          unsigned short* __restrict__ out,
                                          const float* __restrict__ cs, float us,
                                          int R, int C, int r0, int c0)
{
    __shared__ float t[64][65];
    int tr = threadIdx.x >> 6;
    int tc = threadIdx.x & 63;
    #pragma unroll
    for (int i = 0; i < 16; ++i) {
        int r = i * 4 + tr;
        t[r][tc] = in[(long)(r0 + r) * C + c0 + tc];
    }
    __syncthreads();
    float sc = (cs ? cs[r0 + tc] : 1.0f) * us;
    #pragma unroll
    for (int i = 0; i < 16; ++i) {
        int r = i * 4 + tr;
        out[(long)(c0 + r) * R + r0 + tc] = f2bfu(t[tc][r] * sc);
    }
}

struct WTArgs {
    const float* src[8];
    unsigned short* dst[8];
    const float* cs[8];
    float sgn[8];
    int R[8], C[8];
};
struct WFArgs {
    const float* Wsrc[4];
    const float* Wbig[4];
    const float* c[4];
    int incl[4], N[4];
    unsigned short* dst[4];
};
struct FVArgs {
    const float* W[6];
    const float* c[6];
    const float* v[6];
    const float* base[6];
    float* out[6];
    int K[6], N[6];
};

// ---------------------------------------------------------------------------
// prep1: flat-grid fused { coeff x2 | adj cvt+rowsum x512 | x cvt+T x1024 }
// ---------------------------------------------------------------------------
__global__ __launch_bounds__(256) void prep1_k(
    const float* __restrict__ logits0, const float* __restrict__ gumb0,
    const float* __restrict__ Wnl0, float* __restrict__ c0,
    const float* __restrict__ logits1, const float* __restrict__ gumb1,
    const float* __restrict__ Wnl1, float* __restrict__ c1,
    const float* __restrict__ adj, unsigned int* __restrict__ adjb,
    float* __restrict__ ars,
    const float* __restrict__ x, unsigned short* __restrict__ xbf,
    unsigned short* __restrict__ xT)
{
    __shared__ float shm[64 * 65];
    const int b = blockIdx.x;
    const int t = threadIdx.x;
    if (b < 2) {
        const float* lg = b ? logits1 : logits0;
        const float* gb = b ? gumb1 : gumb0;
        const float* Wn = b ? Wnl1 : Wnl0;
        float* cc = b ? c1 : c0;
        float l0 = lg[0] + gb[t * 3 + 0];
        float l1 = lg[1] + gb[t * 3 + 1];
        float l2 = lg[2] + gb[t * 3 + 2];
        int bl = 0;
        float bv = l0;
        if (l1 > bv) { bv = l1; bl = 1; }
        if (l2 > bv) { bv = l2; bl = 2; }
        float s = 0.f;
        #pragma unroll
        for (int q = 0; q < 8; ++q) s += Wn[t * 8 + q] * PAT[bl][q];
        cc[t] = s;
    } else if (b < 2 + NN) {
        int n = b - 2;
        float2 v = reinterpret_cast<const float2*>(adj)[n * 256 + t];
        adjb[n * 256 + t] = (unsigned int)f2bfu(v.x) | ((unsigned int)f2bfu(v.y) << 16);
        shm[t] = v.x + v.y;
        __syncthreads();
        for (int o = 128; o > 0; o >>= 1) {
            if (t < o) shm[t] += shm[t + o];
            __syncthreads();
        }
        if (t == 0) ars[n] = shm[0];
    } else {
        int tt = b - 2 - NN;
        int bz = tt >> 3;
        int r0 = (tt & 7) * 64;
        float (*tl)[65] = (float(*)[65])shm;
        const long base = (long)bz * NN * DIN;
        const int tr4 = t >> 6;
        const int tc  = t & 63;
        #pragma unroll
        for (int i = 0; i < 16; ++i) {
            int r = i * 4 + tr4;
            float v = x[base + (long)(r0 + r) * DIN + tc];
            tl[r][tc] = v;
            xbf[base + (long)(r0 + r) * DIN + tc] = f2bfu(v);
        }
        __syncthreads();
        #pragma unroll
        for (int i = 0; i < 16; ++i) {
            int d = i * 4 + tr4;
            xT[base + (long)d * NN + r0 + tc] = f2bfu(tl[tc][d]);
        }
    }
}

// ---------------------------------------------------------------------------
// prep2: grid (256,3): y=0 weight transposes; y=1 weight folds; y=2 vec folds
// ---------------------------------------------------------------------------
__global__ __launch_bounds__(256) void prep2_k(WTArgs wa, WFArgs wf, FVArgs fv)
{
    __shared__ float aux[256];
    if (blockIdx.y == 0) {
        int xg = blockIdx.x;
        int wgt = xg >> 4;
        if (wgt >= 8) return;
        int t = xg & 15;
        int R = wa.R[wgt], C = wa.C[wgt];
        int tilesX = C >> 6;
        int tiles = (R >> 6) * tilesX;
        if (t >= tiles) return;
        tcvt_body(wa.src[wgt], wa.dst[wgt], wa.cs[wgt], wa.sgn[wgt], R, C,
                  (t / tilesX) * 64, (t % tilesX) * 64);
    } else if (blockIdx.y == 1) {
        int xg = blockIdx.x;
        int cs = xg >> 6;
        int m = xg & 63;
        const float* c = wf.c[cs];
        aux[threadIdx.x] = wf.Wsrc[cs][m * 256 + threadIdx.x] * (c ? c[threadIdx.x] : 1.0f);
        __syncthreads();
        int n = threadIdx.x;
        int N = wf.N[cs];
        if (n >= N) return;
        float s = wf.incl[cs] ? wf.Wsrc[cs][m * 256 + n] : 0.f;
        const float* Wb = wf.Wbig[cs];
        #pragma unroll 8
        for (int k = 0; k < 256; ++k)
            s += aux[k] * Wb[(long)k * N + n];
        wf.dst[cs][n * 64 + m] = f2bfu(s);
    } else {
        int n = blockIdx.x;
        for (int cs = 0; cs < 6; ++cs) {
            __syncthreads();
            if (n >= fv.N[cs]) continue;
            int k = threadIdx.x;
            float s = 0.f;
            if (k < fv.K[cs]) {
                float cc = fv.c[cs] ? fv.c[cs][k] : 1.0f;
                s = fv.v[cs][k] * cc * fv.W[cs][(long)k * fv.N[cs] + n];
            }
            aux[threadIdx.x] = s;
            __syncthreads();
            for (int o = 128; o > 0; o >>= 1) {
                if (threadIdx.x < o) aux[threadIdx.x] += aux[threadIdx.x + o];
                __syncthreads();
            }
            if (threadIdx.x == 0)
                fv.out[cs][n] = (fv.base[cs] ? fv.base[cs][n] : 0.f) + aux[0];
        }
    }
}

// ---------------------------------------------------------------------------
// sc kernels (unchanged round 13)
// ---------------------------------------------------------------------------
__global__ __launch_bounds__(256) void sc0_k(
    const float* __restrict__ partial, int np, float inv_n,
    unsigned short* __restrict__ Wa, unsigned short* __restrict__ Wb,
    const float* __restrict__ bg0p, const float* __restrict__ brg0p,
    const float* __restrict__ crow0, float* __restrict__ cv0)
{
    __shared__ float red[256];
    float th = block_th(partial, np, inv_n, red, threadIdx.x);
    float om = 1.f - th;
    int g = blockIdx.x * 256 + threadIdx.x;
    Wa[g] = f2bfu(th * bf2f(Wa[g]));
    Wb[g] = f2bfu(om * bf2f(Wb[g]));
    if (g < 256) cv0[g] = th * bg0p[g] + om * brg0p[g] + crow0[g];
}

__global__ __launch_bounds__(256) void sc1_k(
    const float* __restrict__ partial, int np, float inv_n,
    unsigned short* __restrict__ Wg1T,
    const unsigned short* __restrict__ Wrw0T, const unsigned short* __restrict__ Wrg0pT,
    unsigned short* __restrict__ WcombT,
    unsigned short* __restrict__ Wg0pT,
    unsigned short* __restrict__ WrwWg1T,
    const float* __restrict__ bg1, const float* __restrict__ brw0,
    const float* __restrict__ cv0, const float* __restrict__ bw1v,
    float* __restrict__ bv1g, float* __restrict__ bw1s)
{
    __shared__ float red[256];
    float th = block_th(partial, np, inv_n, red, threadIdx.x);
    float om = 1.f - th;
    int g = blockIdx.x * 256 + threadIdx.x;
    Wg1T[g] = f2bfu(th * bf2f(Wg1T[g]));
    if (g < 16384) {
        WcombT[g]  = f2bfu(th * bf2f(Wrg0pT[g]) + om * bf2f(Wrw0T[g]));
        Wg0pT[g]   = f2bfu(th * bf2f(Wg0pT[g]));
        WrwWg1T[g] = f2bfu(om * bf2f(WrwWg1T[g]));
    }
    if (g < 256) {
        bv1g[g] = bg1[g] + om * brw0[g] + th * cv0[g];
        bw1s[g] = om * bw1v[g];
    }
}

__global__ __launch_bounds__(256) void sc2_k(
    const float* __restrict__ partial, int np, float inv_n,
    unsigned short* __restrict__ Wc1T, unsigned short* __restrict__ Wrgc1T,
    const float* __restrict__ brgc1, const float* __restrict__ crow1,
    float* __restrict__ cv2)
{
    __shared__ float red[256];
    float th = block_th(partial, np, inv_n, red, threadIdx.x);
    float om = 1.f - th;
    int g = blockIdx.x * 256 + threadIdx.x;
    Wc1T[g] = f2bfu(th * bf2f(Wc1T[g]));
    if (g < 4096) Wrgc1T[g] = f2bfu(om * bf2f(Wrgc1T[g]));
    if (g < 64) cv2[g] = om * brgc1[g] + crow1[g];
}

// ---------------------------------------------------------------------------
// Rbf producer: C = A@B + bias, row-major AND per-batch transposed.
// ---------------------------------------------------------------------------
template<int BM, int BN, int FM, int FN>
__global__ __launch_bounds__(256) void gemm_res_k(
    const __hip_bfloat16* __restrict__ A, const __hip_bfloat16* __restrict__ Bt,
    const float* __restrict__ bias,
    __hip_bfloat16* __restrict__ Cb, __hip_bfloat16* __restrict__ CbT,
    int M, int N, int K)
{
    __shared__ __attribute__((aligned(128))) char lds[(BM + BN) * 128];
    char* AsB = lds;
    char* BsB = lds + BM * 128;

    const int m0 = blockIdx.y * BM;
    const int tid  = threadIdx.x;
    const int wave = tid >> 6;
    const int lane = tid & 63;
    const int wn = wave & 1;

    f32x4 acc[FM][FN];
    #pragma unroll
    for (int i = 0; i < FM; ++i)
        #pragma unroll
        for (int j = 0; j < FN; ++j)
            acc[i][j] = (f32x4){0.f, 0.f, 0.f, 0.f};

    for (int k0 = 0; k0 < K; k0 += 64) {
        stage_tiles<BM, BN>(A, Bt, AsB, BsB, m0, 0, k0, K, K, wave, lane);
        __syncthreads();
        mfma_tiles<BM, BN, FM, FN>(AsB, BsB, acc, wave, lane);
        __syncthreads();
    }

    const int lc = lane & 15;
    #pragma unroll
    for (int j = 0; j < FN; ++j) {
        float bv = bias[wn * (FN * 16) + j * 16 + lc];
        #pragma unroll
        for (int i = 0; i < FM; ++i)
            #pragma unroll
            for (int r = 0; r < 4; ++r)
                acc[i][j][r] += bv;
    }
    write_tile<BM, BN, FM, FN>(lds, acc, Cb, (long)m0 * N, N, tid);
    long baseT = (long)(m0 / NN) * ((long)N * NN) + (m0 % NN);
    write_tileT<BM, BN, FM, FN>(lds, acc, CbT, baseT, NN, tid);
}

// ---------------------------------------------------------------------------
// t0radj_k: fused adj@[x | Rbf] — shared A staging, two accumulators,
// 8-step round-13 pipeline. XCD-grouped (nwg=512, bijective).
// ---------------------------------------------------------------------------
__global__ __launch_bounds__(256) void t0radj_k(
    const __hip_bfloat16* __restrict__ adjb,
    const __hip_bfloat16* __restrict__ xT,    // (b, 64, 512)
    const __hip_bfloat16* __restrict__ RbfT,  // (b, 64, 512)
    __hip_bfloat16* __restrict__ T0,          // (b, 512, 64)
    __hip_bfloat16* __restrict__ Radj)        // (b, 512, 64)
{
    constexpr int BM = 128, BN = 64;
    constexpr int ABYTES = BM * 128;          // 16KB
    constexpr int BBYTES = BN * 128;          // 8KB
    constexpr int BUF = ABYTES + 2 * BBYTES;  // 32KB
    __shared__ __attribute__((aligned(128))) char lds[2 * BUF];

    const int d   = blockIdx.x;
    const int xcd = d & 7;
    const int q   = d >> 3;
    const int t   = q & 3;
    const int bz  = xcd + ((q >> 2) << 3);
    const int m0  = t * BM;

    const __hip_bfloat16* B1 = xT + (long)bz * (64L * NN);
    const __hip_bfloat16* B2 = RbfT + (long)bz * (64L * NN);

    const int tid  = threadIdx.x;
    const int wave = tid >> 6;
    const int lane = tid & 63;
    const int lr = lane >> 3;
    const int ls = lane & 7;

    f32x4 accA[4][2], accB[4][2];
    #pragma unroll
    for (int i = 0; i < 4; ++i)
        #pragma unroll
        for (int j = 0; j < 2; ++j) {
            accA[i][j] = (f32x4){0.f, 0.f, 0.f, 0.f};
            accB[i][j] = (f32x4){0.f, 0.f, 0.f, 0.f};
        }

    auto stage2 = [&](char* buf, int k0) {
        #pragma unroll
        for (int cc = 0; cc < 8; ++cc) {
            int c = wave * 8 + cc;
            const __hip_bfloat16* src;
            char* ldsb;
            if (c < 16) {
                int r = c * 8 + lr;
                ldsb = buf + c * 1024;
                src = adjb + ((long)(m0 + r) * NN + k0 + ((ls ^ (r & 7)) << 3));
            } else if (c < 24) {
                int r = (c - 16) * 8 + lr;
                ldsb = buf + ABYTES + (c - 16) * 1024;
                src = B1 + ((long)r * NN + k0 + ((ls ^ (r & 7)) << 3));
            } else {
                int r = (c - 24) * 8 + lr;
                ldsb = buf + ABYTES + BBYTES + (c - 24) * 1024;
                src = B2 + ((long)r * NN + k0 + ((ls ^ (r & 7)) << 3));
            }
            __builtin_amdgcn_global_load_lds(GLP(src), LDSP(ldsb), 16, 0, 0);
        }
    };

    stage2(lds, 0);
    __syncthreads();
    #pragma unroll
    for (int s = 0; s < 8; ++s) {
        char* bc = lds + (s & 1) * BUF;
        if (s + 1 < 8) stage2(lds + ((s + 1) & 1) * BUF, (s + 1) * 64);
        mfma_tiles<BM, BN, 4, 2>(bc, bc + ABYTES, accA, wave, lane);
        mfma_tiles<BM, BN, 4, 2>(bc, bc + ABYTES + BBYTES, accB, wave, lane);
        __syncthreads();
    }

    long base = (long)bz * ((long)NN * BN) + (long)m0 * BN;
    write_tile<BM, BN, 4, 2>(lds, accA, T0, base, BN, tid);
    write_tile<BM, BN, 4, 2>(lds, accB, Radj, base, BN, tid);
}

// ---------------------------------------------------------------------------
// Batched pipelined GEMM with XCD-grouped block swizzle (round 13).
// ---------------------------------------------------------------------------
template<int BM, int BN, int FM, int FN, int GX, int NB, int NS>
__global__ __launch_bounds__(256) void gemm_bt_swz_k(
    const __hip_bfloat16* __restrict__ A, const __hip_bfloat16* __restrict__ Bt,
    __hip_bfloat16* __restrict__ Cb,
    int M, int N, int K, long sA, long sB, long sC)
{
    __shared__ __attribute__((aligned(128))) char lds[2 * (BM + BN) * 128];

    const int d   = blockIdx.x;
    const int xcd = d & 7;
    const int q   = d >> 3;
    const int t   = q % NB;
    const int bz  = xcd + ((q / NB) << 3);
    const int n0  = (t % GX) * BN;
    const int m0  = (t / GX) * BM;

    const __hip_bfloat16* Ab = A + (long)bz * sA;
    const __hip_bfloat16* Bb = Bt + (long)bz * sB;

    const int tid  = threadIdx.x;
    const int wave = tid >> 6;
    const int lane = tid & 63;

    f32x4 acc[FM][FN];
    #pragma unroll
    for (int i = 0; i < FM; ++i)
        #pragma unroll
        for (int j = 0; j < FN; ++j)
            acc[i][j] = (f32x4){0.f, 0.f, 0.f, 0.f};

    const __hip_bfloat16* pA[NS];
    const __hip_bfloat16* pB[NS];
    int pK[NS], pk0[NS];
    #pragma unroll
    for (int s = 0; s < NS; ++s) { pA[s] = Ab; pB[s] = Bb; pK[s] = K; pk0[s] = s * 64; }

    pipe_run<BM, BN, FM, FN, NS, NS>(pA, pB, pK, pk0,
                                     lds, lds + (BM + BN) * 128,
                                     acc, acc, m0, n0, wave, lane);

    write_tile<BM, BN, FM, FN>(lds, acc, Cb, (long)bz * sC + (long)m0 * N + n0, N, tid);
}

// ---------------------------------------------------------------------------
// dual1_k (D0): ONE accumulator, pair-swizzled, pipelined (2 steps).
// ---------------------------------------------------------------------------
template<int BM, int BN, int FM, int FN>
__global__ __launch_bounds__(256) void dual1_k(
    const __hip_bfloat16* __restrict__ A0, const __hip_bfloat16* __restrict__ B0, int K0,
    const __hip_bfloat16* __restrict__ A1, const __hip_bfloat16* __restrict__ B1, int K1,
    const float* __restrict__ b1, const float* __restrict__ b2,
    float* __restrict__ partial, int M, int N)
{
    __shared__ __attribute__((aligned(128))) char lds[2 * (BM + BN) * 128];

    const int d   = blockIdx.x;
    const int q   = d >> 3;
    const int nx  = q & 1;
    const int my  = (d & 7) + ((q >> 1) << 3);
    const int m0  = my * BM;
    const int n0  = nx * BN;

    const int tid  = threadIdx.x;
    const int wave = tid >> 6;
    const int lane = tid & 63;
    const int wn = wave & 1;

    f32x4 acc[FM][FN];
    #pragma unroll
    for (int i = 0; i < FM; ++i)
        #pragma unroll
        for (int j = 0; j < FN; ++j)
            acc[i][j] = (f32x4){0.f, 0.f, 0.f, 0.f};

    const __hip_bfloat16* pA[2] = {A0, A1};
    const __hip_bfloat16* pB[2] = {B0, B1};
    int pK[2] = {K0, K1};
    int pk0[2] = {0, 0};
    pipe_run<BM, BN, FM, FN, 2, 2>(pA, pB, pK, pk0,
                                   lds, lds + (BM + BN) * 128,
                                   acc, acc, m0, n0, wave, lane);

    const int lc = lane & 15;
    float dsum = 0.f;
    #pragma unroll
    for (int j = 0; j < FN; ++j) {
        int col = n0 + wn * (FN * 16) + j * 16 + lc;
        float bd = b1[col] - b2[col];
        #pragma unroll
        for (int i = 0; i < FM; ++i)
            #pragma unroll
            for (int r = 0; r < 4; ++r) {
                float dd = acc[i][j][r] + bd;
                dsum += dd * dd;
            }
    }

    float* red = (float*)lds;
    red[tid] = dsum;
    __syncthreads();
    for (int o = 128; o > 0; o >>= 1) {
        if (tid < o) red[tid] += red[tid + o];
        __syncthreads();
    }
    if (tid == 0) partial[my * 2 + nx] = red[0];
}

// ---------------------------------------------------------------------------
// wave2T_k (W0): 3 pipelined steps {acc0,acc0,acc1}; writes C1 transposed.
// ---------------------------------------------------------------------------
template<int BM, int BN, int FM, int FN>
__global__ __launch_bounds__(256) void wave2T_k(
    const __hip_bfloat16* __restrict__ A0, const __hip_bfloat16* __restrict__ B0, int K0,
    const __hip_bfloat16* __restrict__ A1, const __hip_bfloat16* __restrict__ B1, int K1,
    const __hip_bfloat16* __restrict__ A2, const __hip_bfloat16* __restrict__ B2, int K2,
    const float* __restrict__ cv, const float* __restrict__ b2v,
    __hip_bfloat16* __restrict__ C1T, float* __restrict__ partial_out, int M, int N)
{
    __shared__ __attribute__((aligned(128))) char lds[2 * (BM + BN) * 128];

    const int d   = blockIdx.x;
    const int q   = d >> 3;
    const int nx  = q & 1;
    const int my  = (d & 7) + ((q >> 1) << 3);
    const int m0  = my * BM;
    const int n0  = nx * BN;

    const int tid  = threadIdx.x;
    const int wave = tid >> 6;
    const int lane = tid & 63;
    const int wn = wave & 1;

    f32x4 acc0[FM][FN], acc1[FM][FN];
    #pragma unroll
    for (int i = 0; i < FM; ++i)
        #pragma unroll
        for (int j = 0; j < FN; ++j) {
            acc0[i][j] = (f32x4){0.f, 0.f, 0.f, 0.f};
            acc1[i][j] = (f32x4){0.f, 0.f, 0.f, 0.f};
        }

    const __hip_bfloat16* pA[3] = {A0, A1, A2};
    const __hip_bfloat16* pB[3] = {B0, B1, B2};
    int pK[3] = {K0, K1, K2};
    int pk0[3] = {0, 0, 0};
    pipe_run<BM, BN, FM, FN, 3, 2>(pA, pB, pK, pk0,
                                   lds, lds + (BM + BN) * 128,
                                   acc0, acc1, m0, n0, wave, lane);

    const int lc = lane & 15;
    float dsum = 0.f;
    #pragma unroll
    for (int j = 0; j < FN; ++j) {
        int col = n0 + wn * (FN * 16) + j * 16 + lc;
        float c1 = cv[col];
        float c2 = b2v[col];
        #pragma unroll
        for (int i = 0; i < FM; ++i)
            #pragma unroll
            for (int r = 0; r < 4; ++r) {
                float v1 = acc0[i][j][r] + c1;
                float v2 = acc1[i][j][r] + c2;
                acc0[i][j][r] = v1;
                float dd = v1 - v2;
                dsum += dd * dd;
            }
    }

    float* red = (float*)lds;
    red[tid] = dsum;
    __syncthreads();
    for (int o = 128; o > 0; o >>= 1) {
        if (tid < o) red[tid] += red[tid + o];
        __syncthreads();
    }
    if (tid == 0) partial_out[my * 2 + nx] = red[0];

    long baseT = (long)(m0 / NN) * ((long)N * NN) + (long)n0 * NN + (m0 % NN);
    write_tileT<BM, BN, FM, FN>(lds, acc0, C1T, baseT, NN, tid);
}

// ---------------------------------------------------------------------------
// gmix5_k: 5-phase pipelined (8 steps) + rank-1 epilogue (round 13).
// ---------------------------------------------------------------------------
template<int BM, int BN, int FM, int FN>
__global__ __launch_bounds__(256) void gmix5_k(
    const __hip_bfloat16* __restrict__ A0, const __hip_bfloat16* __restrict__ B0, int K0,
    const __hip_bfloat16* __restrict__ A1, const __hip_bfloat16* __restrict__ B1, int K1,
    const __hip_bfloat16* __restrict__ A2, const __hip_bfloat16* __restrict__ B2, int K2,
    const __hip_bfloat16* __restrict__ A3, const __hip_bfloat16* __restrict__ B3, int K3,
    const __hip_bfloat16* __restrict__ A4, const __hip_bfloat16* __restrict__ B4, int K4,
    const float* __restrict__ bv1, const float* __restrict__ b2v,
    const float* __restrict__ ars, const float* __restrict__ bw1s,
    __hip_bfloat16* __restrict__ C1, float* __restrict__ partial_out, int M, int N)
{
    __shared__ __attribute__((aligned(128))) char lds[2 * (BM + BN) * 128];

    const int d  = blockIdx.x;
    const int q  = d >> 3;
    const int nx = q & 1;
    const int my = (d & 7) + ((q >> 1) << 3);
    const int m0 = my * BM;
    const int n0 = nx * BN;

    const int tid  = threadIdx.x;
    const int wave = tid >> 6;
    const int lane = tid & 63;
    const int wm = wave >> 1, wn = wave & 1;

    f32x4 acc0[FM][FN], acc1[FM][FN];
    #pragma unroll
    for (int i = 0; i < FM; ++i)
        #pragma unroll
        for (int j = 0; j < FN; ++j) {
            acc0[i][j] = (f32x4){0.f, 0.f, 0.f, 0.f};
            acc1[i][j] = (f32x4){0.f, 0.f, 0.f, 0.f};
        }

    const __hip_bfloat16* pA[8] = {A0, A0, A0, A0, A1, A2, A3, A4};
    const __hip_bfloat16* pB[8] = {B0, B0, B0, B0, B1, B2, B3, B4};
    int pK[8]  = {K0, K0, K0, K0, K1, K2, K3, K4};
    int pk0[8] = {0, 64, 128, 192, 0, 0, 0, 0};
    pipe_run<BM, BN, FM, FN, 8, 7>(pA, pB, pK, pk0,
                                   lds, lds + (BM + BN) * 128,
                                   acc0, acc1, m0, n0, wave, lane);

    const int lc  = lane & 15;
    const int lr4 = (lane >> 4) << 2;
    const int node0 = m0 & (NN - 1);
    float dsum = 0.f;
    #pragma unroll
    for (int j = 0; j < FN; ++j) {
        int col = n0 + wn * (FN * 16) + j * 16 + lc;
        float c1 = bv1[col];
        float c2 = b2v[col];
        float bw = bw1s[col];
        #pragma unroll
        for (int i = 0; i < FM; ++i) {
            int rowl = wm * (FM * 16) + i * 16 + lr4;
            #pragma unroll
            for (int r = 0; r < 4; ++r) {
                float av = ars[node0 + rowl + r];
                float v1 = acc0[i][j][r] + c1 + av * bw;
                float v2 = acc1[i][j][r] + c2;
                acc0[i][j][r] = v1;
                float dd = v1 - v2;
                dsum += dd * dd;
            }
        }
    }

    float* red = (float*)lds;
    red[tid] = dsum;
    __syncthreads();
    for (int o = 128; o > 0; o >>= 1) {
        if (tid < o) red[tid] += red[tid + o];
        __syncthreads();
    }
    if (tid == 0) partial_out[my * 2 + nx] = red[0];

    write_tile<BM, BN, FM, FN>(lds, acc0, C1, (long)m0 * N + n0, N, tid);
}

// ---------------------------------------------------------------------------
// wave2_k (F): 6 pipelined steps (5 -> acc0, 1 -> acc1), plain grid.
// ---------------------------------------------------------------------------
template<int BM, int BN, int FM, int FN>
__global__ __launch_bounds__(256) void wave2_k(
    const __hip_bfloat16* __restrict__ A0, const __hip_bfloat16* __restrict__ B0, int K0,
    const __hip_bfloat16* __restrict__ A1, const __hip_bfloat16* __restrict__ B1, int K1,
    const __hip_bfloat16* __restrict__ A2, const __hip_bfloat16* __restrict__ B2, int K2,
    const float* __restrict__ cv, const float* __restrict__ b2v,
    __hip_bfloat16* __restrict__ C1, __hip_bfloat16* __restrict__ C2,
    float* __restrict__ partial_out, int M, int N)
{
    __shared__ __attribute__((aligned(128))) char lds[2 * (BM + BN) * 128];

    const int m0 = blockIdx.y * BM;
    const int n0 = blockIdx.x * BN;
    const int pidx = blockIdx.y * gridDim.x + blockIdx.x;

    const int tid  = threadIdx.x;
    const int wave = tid >> 6;
    const int lane = tid & 63;
    const int wn = wave & 1;

    f32x4 acc0[FM][FN], acc1[FM][FN];
    #pragma unroll
    for (int i = 0; i < FM; ++i)
        #pragma unroll
        for (int j = 0; j < FN; ++j) {
            acc0[i][j] = (f32x4){0.f, 0.f, 0.f, 0.f};
            acc1[i][j] = (f32x4){0.f, 0.f, 0.f, 0.f};
        }

    const __hip_bfloat16* pA[6] = {A0, A0, A0, A0, A1, A2};
    const __hip_bfloat16* pB[6] = {B0, B0, B0, B0, B1, B2};
    int pK[6]  = {K0, K0, K0, K0, K1, K2};
    int pk0[6] = {0, 64, 128, 192, 0, 0};
    pipe_run<BM, BN, FM, FN, 6, 5>(pA, pB, pK, pk0,
                                   lds, lds + (BM + BN) * 128,
                                   acc0, acc1, m0, n0, wave, lane);

    const int lc = lane & 15;
    float dsum = 0.f;
    #pragma unroll
    for (int j = 0; j < FN; ++j) {
        int col = n0 + wn * (FN * 16) + j * 16 + lc;
        float c1 = cv[col];
        float c2 = b2v[col];
        #pragma unroll
        for (int i = 0; i < FM; ++i)
            #pragma unroll
            for (int r = 0; r < 4; ++r) {
                float v1 = acc0[i][j][r] + c1;
                float v2 = acc1[i][j][r] + c2;
                acc0[i][j][r] = v1;
                acc1[i][j][r] = v2;
                float dd = v1 - v2;
                dsum += dd * dd;
            }
    }

    float* red = (float*)lds;
    red[tid] = dsum;
    __syncthreads();
    for (int o = 128; o > 0; o >>= 1) {
        if (tid < o) red[tid] += red[tid + o];
        __syncthreads();
    }
    if (tid == 0) partial_out[pidx] = red[0];

    write_tile<BM, BN, FM, FN>(lds, acc0, C1, (long)m0 * N + n0, N, tid);
    write_tile<BM, BN, FM, FN>(lds, acc1, C2, (long)m0 * N + n0, N, tid);
}

// ---------------------------------------------------------------------------
// final mix (th in-kernel): out = th*h + (1-th)*r, fp32 out
// ---------------------------------------------------------------------------
__global__ __launch_bounds__(256) void mixfinal_k(
    const unsigned short* __restrict__ h, const unsigned short* __restrict__ r,
    const float* __restrict__ partial_in, int np_in, float inv_in,
    float* __restrict__ out, long n4)
{
    __shared__ float sm[256];
    const float th = block_th(partial_in, np_in, inv_in, sm, (int)threadIdx.x);
    const float om = 1.f - th;
    long gid = (long)blockIdx.x * 256 + threadIdx.x;
    long stride = (long)gridDim.x * 256;
    for (long i = gid; i < n4; i += stride) {
        ushort4 hv = reinterpret_cast<const ushort4*>(h)[i];
        ushort4 rv = reinterpret_cast<const ushort4*>(r)[i];
        float4 o;
        o.x = th * bf2f(hv.x) + om * bf2f(rv.x);
        o.y = th * bf2f(hv.y) + om * bf2f(rv.y);
        o.z = th * bf2f(hv.z) + om * bf2f(rv.z);
        o.w = th * bf2f(hv.w) + om * bf2f(rv.w);
        reinterpret_cast<float4*>(out)[i] = o;
    }
}

// ---------------------------------------------------------------------------
extern "C" void kernel_launch(void* const* d_in, const int* in_sizes, int n_in,
                              void* d_out, int out_size, void* d_ws, size_t ws_size,
                              hipStream_t stream)
{
    const float* x       = (const float*)d_in[0];
    const float* adj     = (const float*)d_in[1];
    const float* Wres    = (const float*)d_in[2];
    const float* bres    = (const float*)d_in[3];
    const float* Wg0     = (const float*)d_in[4];
    const float* bg0     = (const float*)d_in[5];
    const float* Wrg0    = (const float*)d_in[6];
    const float* brg0    = (const float*)d_in[7];
    const float* logits0 = (const float*)d_in[8];
    const float* gumb0   = (const float*)d_in[9];
    const float* Wnl0    = (const float*)d_in[10];
    const float* bnl0    = (const float*)d_in[11];
    const float* Wwo0    = (const float*)d_in[12];
    const float* bwo0    = (const float*)d_in[13];
    const float* Wrw0    = (const float*)d_in[14];
    const float* brw0    = (const float*)d_in[15];
    const float* Wg1     = (const float*)d_in[16];
    const float* bg1     = (const float*)d_in[17];
    const float* Wrg1    = (const float*)d_in[18];
    const float* brg1    = (const float*)d_in[19];
    const float* logits1 = (const float*)d_in[20];
    const float* gumb1   = (const float*)d_in[21];
    const float* Wnl1    = (const float*)d_in[22];
    const float* bnl1    = (const float*)d_in[23];
    const float* Wwo1    = (const float*)d_in[24];
    const float* bwo1    = (const float*)d_in[25];
    const float* Wrw1    = (const float*)d_in[26];
    const float* brw1    = (const float*)d_in[27];

    float* out = (float*)d_out;

    // ---- workspace ----
    char* w = (char*)d_ws;
    auto alloc = [&](long bytes) { char* p = w; w += (bytes + 255) & ~255L; return p; };
    const long SLOT = (long)BNR * HH * 2;                 // 32 MB
    char* pool = alloc(5 * SLOT);                         // 160 MB
    __hip_bfloat16* Rbf  = (__hip_bfloat16*)alloc((long)BNR * DOUT * 2); // 8 MB
    __hip_bfloat16* adjb = (__hip_bfloat16*)alloc((long)NN * NN * 2);
    __hip_bfloat16* WT   = (__hip_bfloat16*)alloc(225280L * 2);
    float* partial0 = (float*)alloc(2048 * 4);
    float* partial1 = (float*)alloc(2048 * 4);
    float* partial2 = (float*)alloc(2048 * 4);
    float* partial3 = (float*)alloc(2048 * 4);
    float* c0      = (float*)alloc(256 * 4);
    float* c1      = (float*)alloc(256 * 4);
    float* bg0p    = (float*)alloc(256 * 4);
    float* brg0p   = (float*)alloc(256 * 4);
    float* crow0   = (float*)alloc(256 * 4);
    float* brgc1   = (float*)alloc(64 * 4);
    float* crow1   = (float*)alloc(64 * 4);
    float* cv0     = (float*)alloc(256 * 4);
    float* bv1g    = (float*)alloc(256 * 4);
    float* cv2     = (float*)alloc(64 * 4);
    float* ars     = (float*)alloc(512 * 4);
    float* bw1v    = (float*)alloc(256 * 4);
    float* bw1s    = (float*)alloc(256 * 4);

    auto S = [&](int i) { return pool + (long)i * SLOT; };
    __hip_bfloat16* xwrT = (__hip_bfloat16*)S(0);
    __hip_bfloat16* orw  = (__hip_bfloat16*)S(1);
    __hip_bfloat16* rw1  = (__hip_bfloat16*)(S(1) + (long)BNR * DOUT * 2);
    __hip_bfloat16* Radj = (__hip_bfloat16*)(S(1) + 2L * BNR * DOUT * 2);
    __hip_bfloat16* xg1  = (__hip_bfloat16*)S(2);
    __hip_bfloat16* T1x  = (__hip_bfloat16*)S(3);
    __hip_bfloat16* xbf  = (__hip_bfloat16*)S(4);
    __hip_bfloat16* xT   = (__hip_bfloat16*)(S(4) + (long)BNR * DIN * 2);
    __hip_bfloat16* T0   = (__hip_bfloat16*)(S(4) + 2L * BNR * DIN * 2);
    __hip_bfloat16* RbfT = (__hip_bfloat16*)(S(4) + 3L * BNR * DIN * 2);

    // transposed weights inside WT (element offsets)
    __hip_bfloat16* WresT   = WT;             // 64x64
    __hip_bfloat16* Wg0T    = WT + 4096;      // 256x64
    __hip_bfloat16* Wrg0T   = WT + 20480;     // 256x64  (NEGATED at prep)
    __hip_bfloat16* Wrw0T   = WT + 36864;     // 256x64
    __hip_bfloat16* Wg1T    = WT + 53248;     // 256x256 (th1 by sc1)
    __hip_bfloat16* Wrg1T   = WT + 118784;    // 256x64
    __hip_bfloat16* Wc1T    = WT + 135168;    // 64x256 (c1-scaled Wwo1^T; th2 by sc2)
    __hip_bfloat16* Wrw1T   = WT + 151552;    // 64x64
    __hip_bfloat16* Wg0pT   = WT + 155648;    // 256x64 (Wg0@(I+Wc0))^T; th0 sc0; th1 sc1
    __hip_bfloat16* Wrg0pT  = WT + 172032;    // 256x64 (Wrg0@(I+Wc0))^T; om0 sc0
    __hip_bfloat16* Wrgc1T  = WT + 188416;    // 64x64  (Wrg1@Wc1)^T; om2 sc2
    __hip_bfloat16* WcombT  = WT + 192512;    // 256x64 (th1*om0*Wrg0p + om1*Wrw0)^T by sc1
    __hip_bfloat16* WrwWg1T = WT + 208896;    // 256x64 (Wrw0@Wg1)^T; om1 by sc1

    const dim3 blk(256);
    const float invH = 1.0f / ((float)BNR * HH);
    const float invD = 1.0f / ((float)BNR * DOUT);

    // ---- prep1: coeffs + adj cvt/rowsum + x cvt/transpose (one launch) ----
    hipLaunchKernelGGL(prep1_k, dim3(2 + NN + 8 * BB), blk, 0, stream,
                       logits0, gumb0, Wnl0, c0, logits1, gumb1, Wnl1, c1,
                       adj, (unsigned int*)adjb, ars,
                       x, (unsigned short*)xbf, (unsigned short*)xT);

    // ---- prep2: weight transposes + weight folds + vector folds ----
    WTArgs wa;
    wa.src[0] = Wres; wa.dst[0] = (unsigned short*)WresT; wa.cs[0] = nullptr; wa.sgn[0] = 1.f;  wa.R[0] = 64;  wa.C[0] = 64;
    wa.src[1] = Wg0;  wa.dst[1] = (unsigned short*)Wg0T;  wa.cs[1] = nullptr; wa.sgn[1] = 1.f;  wa.R[1] = 64;  wa.C[1] = 256;
    wa.src[2] = Wrg0; wa.dst[2] = (unsigned short*)Wrg0T; wa.cs[2] = nullptr; wa.sgn[2] = -1.f; wa.R[2] = 64;  wa.C[2] = 256;
    wa.src[3] = Wrw0; wa.dst[3] = (unsigned short*)Wrw0T; wa.cs[3] = nullptr; wa.sgn[3] = 1.f;  wa.R[3] = 64;  wa.C[3] = 256;
    wa.src[4] = Wg1;  wa.dst[4] = (unsigned short*)Wg1T;  wa.cs[4] = nullptr; wa.sgn[4] = 1.f;  wa.R[4] = 256; wa.C[4] = 256;
    wa.src[5] = Wrg1; wa.dst[5] = (unsigned short*)Wrg1T; wa.cs[5] = nullptr; wa.sgn[5] = 1.f;  wa.R[5] = 64;  wa.C[5] = 256;
    wa.src[6] = Wwo1; wa.dst[6] = (unsigned short*)Wc1T;  wa.cs[6] = c1;      wa.sgn[6] = 1.f;  wa.R[6] = 256; wa.C[6] = 64;
    wa.src[7] = Wrw1; wa.dst[7] = (unsigned short*)Wrw1T; wa.cs[7] = nullptr; wa.sgn[7] = 1.f;  wa.R[7] = 64;  wa.C[7] = 64;

    WFArgs wf;
    wf.Wsrc[0] = Wg0;  wf.Wbig[0] = Wwo0; wf.c[0] = c0;      wf.incl[0] = 1; wf.N[0] = 256;
    wf.dst[0] = (unsigned short*)Wg0pT;
    wf.Wsrc[1] = Wrg0; wf.Wbig[1] = Wwo0; wf.c[1] = c0;      wf.incl[1] = 1; wf.N[1] = 256;
    wf.dst[1] = (unsigned short*)Wrg0pT;
    wf.Wsrc[2] = Wrg1; wf.Wbig[2] = Wwo1; wf.c[2] = c1;      wf.incl[2] = 0; wf.N[2] = 64;
    wf.dst[2] = (unsigned short*)Wrgc1T;
    wf.Wsrc[3] = Wrw0; wf.Wbig[3] = Wg1;  wf.c[3] = nullptr; wf.incl[3] = 0; wf.N[3] = 256;
    wf.dst[3] = (unsigned short*)WrwWg1T;

    FVArgs fv;
    fv.W[0] = Wwo0; fv.c[0] = c0;      fv.v[0] = bg0;  fv.base[0] = bg0;     fv.out[0] = bg0p;  fv.K[0] = 256; fv.N[0] = 256;
    fv.W[1] = Wwo0; fv.c[1] = c0;      fv.v[1] = brg0; fv.base[1] = brg0;    fv.out[1] = brg0p; fv.K[1] = 256; fv.N[1] = 256;
    fv.W[2] = Wwo0; fv.c[2] = nullptr; fv.v[2] = bnl0; fv.base[2] = bwo0;    fv.out[2] = crow0; fv.K[2] = 256; fv.N[2] = 256;
    fv.W[3] = Wwo1; fv.c[3] = c1;      fv.v[3] = brg1; fv.base[3] = nullptr; fv.out[3] = brgc1; fv.K[3] = 256; fv.N[3] = 64;
    fv.W[4] = Wwo1; fv.c[4] = nullptr; fv.v[4] = bnl1; fv.base[4] = bwo1;    fv.out[4] = crow1; fv.K[4] = 256; fv.N[4] = 64;
    fv.W[5] = Wg1;  fv.c[5] = nullptr; fv.v[5] = brw0; fv.base[5] = nullptr; fv.out[5] = bw1v;  fv.K[5] = 256; fv.N[5] = 256;
    hipLaunchKernelGGL(prep2_k, dim3(256, 3), blk, 0, stream, wa, wf, fv);

    // res = x @ Wres + bres -> Rbf + RbfT
    hipLaunchKernelGGL((gemm_res_k<128, 64, 4, 2>), dim3(1, BNR / 128, 1), blk, 0, stream,
                       xbf, WresT, bres, Rbf, RbfT, BNR, DOUT, DIN);

    // T0 = adj@x AND Radj = adj@Rbf (fused, shared A staging, pipelined)
    hipLaunchKernelGGL(t0radj_k, dim3(BB * 4), blk, 0, stream,
                       adjb, xT, RbfT, T0, Radj);

    // D0: diff0 partials only (pipelined)
    hipLaunchKernelGGL((dual1_k<64, 128, 2, 4>), dim3(2 * BNR / 64), blk, 0, stream,
                       T0, Wg0T, DIN, Rbf, Wrg0T, DOUT, bg0, brg0, partial0, BNR, HH);

    // sc0
    hipLaunchKernelGGL(sc0_k, dim3(64), blk, 0, stream, partial0, 2048, invH,
                       (unsigned short*)Wg0pT, (unsigned short*)Wrg0pT,
                       bg0p, brg0p, crow0, cv0);

    // W0: xwrT = [T0@(th0*Wg0p) + Rbf@(om0*Wrg0p) + cv0]^T ; diff vs Rbf@Wrw0+brw0
    hipLaunchKernelGGL((wave2T_k<64, 128, 2, 4>), dim3(2 * BNR / 64), blk, 0, stream,
                       T0, Wg0pT, DIN, Rbf, Wrg0pT, DOUT, Rbf, Wrw0T, DOUT,
                       cv0, brw0, xwrT, partial1, BNR, HH);

    // sc1
    hipLaunchKernelGGL(sc1_k, dim3(256), blk, 0, stream, partial1, 2048, invH,
                       (unsigned short*)Wg1T,
                       (const unsigned short*)Wrw0T, (const unsigned short*)Wrg0pT,
                       (unsigned short*)WcombT,
                       (unsigned short*)Wg0pT,
                       (unsigned short*)WrwWg1T,
                       bg1, brw0, cv0, bw1v, bv1g, bw1s);

    // T1x = adj @ xwr (batched, XCD-grouped, pipelined; 128x64 tiles)
    hipLaunchKernelGGL((gemm_bt_swz_k<128, 64, 4, 2, 4, 16, 8>), dim3(BB * 16), blk, 0, stream,
                       adjb, xwrT, T1x, NN, HH, NN, 0, (long)HH * NN, (long)NN * HH);

    // gmix5: xg1 (5 MFMA phases pipelined + rank-1), diff2 partials
    hipLaunchKernelGGL((gmix5_k<64, 128, 2, 4>), dim3(2 * BNR / 64), blk, 0, stream,
                       T1x, Wg1T, HH,
                       Radj, WrwWg1T, DOUT,
                       T0, Wg0pT, DIN,
                       Rbf, WcombT, DOUT,
                       Rbf, Wrg1T, DOUT,
                       bv1g, brg1, ars, bw1s, xg1, partial2, BNR, HH);

    // sc2
    hipLaunchKernelGGL(sc2_k, dim3(64), blk, 0, stream, partial2, 2048, invH,
                       (unsigned short*)Wc1T, (unsigned short*)Wrgc1T,
                       brgc1, crow1, cv2);

    // F: orw = xg1@(th2*Wc1) + Rbf@(om2*Wrgc1) + cv2 ; rw1 = Rbf@Wrw1 + brw1
    hipLaunchKernelGGL((wave2_k<64, 64, 2, 2>), dim3(1, BNR / 64), blk, 0, stream,
                       xg1, Wc1T, HH, Rbf, Wrgc1T, DOUT, Rbf, Wrw1T, DIN,
                       cv2, brw1, orw, rw1, partial3, BNR, DOUT);

    // final mix -> fp32 out
    hipLaunchKernelGGL(mixfinal_k, dim3(2048), blk, 0, stream,
                       (const unsigned short*)orw, (const unsigned short*)rw1,
                       partial3, 1024, invD, out, (long)BNR * DOUT / 4);
}